// Round 1
// baseline (2936.770 us; speedup 1.0000x reference)
//
#include <hip/hip_runtime.h>
#include <math.h>

#define N_SUB   50000
#define NEDGE   500000
#define NBATCH  5000
#define DD      100
#define TDIM    100
#define MSGD    100
#define KATTR   200     // TDIM + MSGD
#define CPH     50      // channels per head
#define SATTR   205     // LDS row stride for attr tile (odd -> conflict-free)

// ---------------- zero scratch ----------------
__global__ void k_zero(float* __restrict__ p, int n){
  int i = blockIdx.x*blockDim.x + threadIdx.x;
  int stride = gridDim.x*blockDim.x;
  for (; i < n; i += stride) p[i] = 0.f;
}

// ---------------- lu_sub = last_update[n_id] ----------------
__global__ void k_lusub(const int* __restrict__ last_update, const int* __restrict__ nid,
                        int* __restrict__ lu_sub){
  int i = blockIdx.x*blockDim.x + threadIdx.x;
  if (i < N_SUB) lu_sub[i] = last_update[nid[i]];
}

// ---------------- node GEMMs: q,k,v,skip = z @ W + b ----------------
__global__ __launch_bounds__(256) void k_node(
    const float* __restrict__ mem, const int* __restrict__ nid,
    const float* __restrict__ Wq, const float* __restrict__ bq,
    const float* __restrict__ Wk, const float* __restrict__ bk,
    const float* __restrict__ Wv, const float* __restrict__ bv,
    const float* __restrict__ Ws, const float* __restrict__ bs,
    float* __restrict__ qs, float* __restrict__ ks,
    float* __restrict__ vs, float* __restrict__ ss)
{
  __shared__ float zt[64][101];   // odd-ish stride -> conflict-free
  const int tid = threadIdx.x;
  const int which = blockIdx.y;
  const float* W    = (which==0)?Wq:(which==1)?Wk:(which==2)?Wv:Ws;
  const float* bias = (which==0)?bq:(which==1)?bk:(which==2)?bv:bs;
  float* outp       = (which==0)?qs:(which==1)?ks:(which==2)?vs:ss;
  const int node0 = blockIdx.x*64;

  for (int idx = tid; idx < 64*DD; idx += 256){
    int r = idx/DD, j = idx - r*DD;
    int node = node0 + r;
    zt[r][j] = (node < N_SUB) ? mem[(size_t)nid[node]*DD + j] : 0.f;
  }
  __syncthreads();

  const int e  = tid & 63;                                    // node within tile
  const int cg = __builtin_amdgcn_readfirstlane(tid >> 6);    // wave-uniform channel group
  const int c0 = cg*25;

  float acc[25];
  #pragma unroll
  for (int i=0;i<25;i++) acc[i] = 0.f;
  for (int k=0;k<DD;k++){
    float a = zt[e][k];
    const float* wr = W + k*DD + c0;   // wave-uniform -> scalar loads
    #pragma unroll
    for (int i=0;i<25;i++) acc[i] = fmaf(a, wr[i], acc[i]);
  }
  const int node = node0 + e;
  if (node < N_SUB){
    float* op = outp + (size_t)node*DD + c0;
    #pragma unroll
    for (int i=0;i<25;i++) op[i] = acc[i] + bias[c0+i];
  }
}

// ---------------- fused edge kernel ----------------
// per edge: ct=cos(rel*w+b); e = [ct,msg] @ We; key=k[src]+e; val=v[src]+e;
// alpha = q[dst].key/sqrt(C); aexp=exp(alpha); denom[dst,h]+=aexp (atomic);
// agg[dst,c] += aexp*val[c] (atomic).  (segment-max dropped: shift-invariant,
// alpha bounded ~O(1) for these inputs)
__global__ __launch_bounds__(256) void k_edge(
    const int* __restrict__ ei, const int* __restrict__ tt,
    const float* __restrict__ msg, const int* __restrict__ lusub,
    const float* __restrict__ wtime, const float* __restrict__ btime,
    const float* __restrict__ We,
    const float* __restrict__ qs, const float* __restrict__ ks, const float* __restrict__ vs,
    float* __restrict__ denom, float* __restrict__ agg)
{
  __shared__ float attr[64][SATTR];
  __shared__ float relv[64];
  __shared__ int   srcs[64];
  __shared__ int   dsts[64];
  __shared__ float part[64][4];
  __shared__ float aexp_s[64][2];
  __shared__ float wt_s[TDIM];
  __shared__ float bt_s[TDIM];

  const int tid = threadIdx.x;
  const long e0 = (long)blockIdx.x*64;

  if (tid < TDIM){ wt_s[tid] = wtime[tid]; bt_s[tid] = btime[tid]; }
  else if (tid >= 128 && tid < 192){
    int l = tid - 128;
    long eid = e0 + l;
    int s = 0, d = -1; float rl = 0.f;
    if (eid < NEDGE){
      s = ei[eid]; d = ei[NEDGE + eid];
      rl = (float)(lusub[s] - tt[eid]);
    }
    srcs[l]=s; dsts[l]=d; relv[l]=rl;
  }
  __syncthreads();

  // ---- time-encoding part of attr (cols 0..99) ----
  {
    const int e = tid & 63;
    const float rl = relv[e];
    #pragma unroll
    for (int it=0; it<25; ++it){
      int j = (tid >> 6) + it*4;
      // match XLA's non-contracted mul-then-add rounding exactly
      float arg = __fadd_rn(__fmul_rn(rl, wt_s[j]), bt_s[j]);
      attr[e][j] = cosf(arg);
    }
  }
  // ---- msg part of attr (cols 100..199), coalesced float4 ----
  {
    const float4* m4 = (const float4*)(msg + (size_t)e0*MSGD);
    for (int idx = tid; idx < 64*MSGD/4; idx += 256){
      int flat = idx*4;
      int e = flat/100;
      int j = flat - e*100;
      float4 mv = (e0 + e < NEDGE) ? m4[idx] : make_float4(0.f,0.f,0.f,0.f);
      attr[e][TDIM+j]   = mv.x;
      attr[e][TDIM+j+1] = mv.y;
      attr[e][TDIM+j+2] = mv.z;
      attr[e][TDIM+j+3] = mv.w;
    }
  }
  __syncthreads();

  const int e  = tid & 63;
  const int cg = __builtin_amdgcn_readfirstlane(tid >> 6);
  const int c0 = cg*25;

  // ---- e = attr @ We for 25 channels of one edge ----
  float acc[25];
  #pragma unroll
  for (int i=0;i<25;i++) acc[i] = 0.f;
  for (int k=0;k<KATTR;k++){
    float a = attr[e][k];
    const float* wr = We + k*DD + c0;   // wave-uniform -> scalar loads
    #pragma unroll
    for (int i=0;i<25;i++) acc[i] = fmaf(a, wr[i], acc[i]);
  }

  const int s = srcs[e];
  const int d = dsts[e];

  // ---- partial alpha over this thread's 25 channels ----
  float pal = 0.f;
  if (d >= 0){
    const float* krow = ks + (size_t)s*DD + c0;
    const float* qrow = qs + (size_t)d*DD + c0;
    #pragma unroll
    for (int i=0;i<25;i++) pal = fmaf(qrow[i], krow[i] + acc[i], pal);
  }
  part[e][cg] = pal;
  __syncthreads();

  // ---- per-edge per-head: alpha -> exp -> denom atomic ----
  if (tid < 128){
    int ee = tid & 63, hh = tid >> 6;
    int dd2 = dsts[ee];
    float ax = 0.f;
    if (dd2 >= 0){
      float al = (part[ee][hh*2] + part[ee][hh*2+1]) * 0.14142135623730951f; // 1/sqrt(50)
      ax = expf(al);
      atomicAdd(&denom[dd2*2 + hh], ax);
    }
    aexp_s[ee][hh] = ax;
  }
  __syncthreads();

  // ---- scatter: agg[dst][c] += aexp * (v[src][c] + e[c]) ----
  if (d >= 0){
    const float ax = aexp_s[e][cg >> 1];
    const float* vrow = vs + (size_t)s*DD + c0;
    float* ap = agg + (size_t)d*DD + c0;
    #pragma unroll
    for (int i=0;i<25;i++) atomicAdd(&ap[i], ax*(vrow[i] + acc[i]));
  }
}

// ---------------- finalize: out = agg/denom + skip ----------------
__global__ void k_final(const float* __restrict__ agg, const float* __restrict__ denom,
                        const float* __restrict__ ss, float* __restrict__ oute){
  int i = blockIdx.x*blockDim.x + threadIdx.x;
  if (i >= N_SUB*DD) return;
  int n = i/DD, c = i - n*DD;
  int hh = (c >= CPH) ? 1 : 0;
  oute[i] = agg[i]/(denom[n*2+hh] + 1e-16f) + ss[i];
}

// ---------------- predictor ----------------
__global__ __launch_bounds__(256) void k_pred1(
    const float* __restrict__ oute, const int* __restrict__ srci, const int* __restrict__ dsti,
    const float* __restrict__ Wps, const float* __restrict__ bps,
    const float* __restrict__ Wpd, const float* __restrict__ bpd,
    float* __restrict__ hbuf)
{
  int i = blockIdx.x*256 + threadIdx.x;
  if (i >= NBATCH*DD) return;
  int b = i/DD, c = i - b*DD;
  const float* r1 = oute + (size_t)srci[b]*DD;
  const float* r2 = oute + (size_t)dsti[b]*DD;
  float a = bps[c] + bpd[c];
  for (int k=0;k<DD;k++){
    a = fmaf(r1[k], Wps[k*DD+c], a);
    a = fmaf(r2[k], Wpd[k*DD+c], a);
  }
  hbuf[i] = fmaxf(a, 0.f);
}

__global__ __launch_bounds__(256) void k_pred2(
    const float* __restrict__ hbuf, const float* __restrict__ Wpf, const float* __restrict__ bpf,
    float* __restrict__ outp)
{
  int i = blockIdx.x*256 + threadIdx.x;
  if (i >= NBATCH*DD) return;
  int b = i/DD, c = i - b*DD;
  const float* hr = hbuf + (size_t)b*DD;
  float a = bpf[c];
  for (int k=0;k<DD;k++) a = fmaf(hr[k], Wpf[k*DD+c], a);
  outp[i] = a;
}

extern "C" void kernel_launch(void* const* d_in, const int* in_sizes, int n_in,
                              void* d_out, int out_size, void* d_ws, size_t ws_size,
                              hipStream_t stream)
{
  const float* mem   = (const float*)d_in[0];
  const int*   lastu = (const int*)  d_in[1];
  const int*   nid   = (const int*)  d_in[2];
  const int*   ei    = (const int*)  d_in[3];
  const int*   tt    = (const int*)  d_in[4];
  const float* msg   = (const float*)d_in[5];
  const int*   srci  = (const int*)  d_in[6];
  const int*   dsti  = (const int*)  d_in[7];
  const float* wtime = (const float*)d_in[8];
  const float* btime = (const float*)d_in[9];
  const float* Wq = (const float*)d_in[10]; const float* bq = (const float*)d_in[11];
  const float* Wk = (const float*)d_in[12]; const float* bk = (const float*)d_in[13];
  const float* Wv = (const float*)d_in[14]; const float* bv = (const float*)d_in[15];
  const float* We = (const float*)d_in[16];
  const float* Ws = (const float*)d_in[17]; const float* bs = (const float*)d_in[18];
  const float* Wps= (const float*)d_in[19]; const float* bps= (const float*)d_in[20];
  const float* Wpd= (const float*)d_in[21]; const float* bpd= (const float*)d_in[22];
  const float* Wpf= (const float*)d_in[23]; const float* bpf= (const float*)d_in[24];

  float* agg   = (float*)d_ws;                       // N_SUB*DD
  float* denom = agg + (size_t)N_SUB*DD;             // N_SUB*2
  float* qs    = denom + (size_t)N_SUB*2;            // N_SUB*DD
  float* ks    = qs    + (size_t)N_SUB*DD;
  float* vs    = ks    + (size_t)N_SUB*DD;
  float* ss    = vs    + (size_t)N_SUB*DD;
  int*   lusub = (int*)(ss + (size_t)N_SUB*DD);      // N_SUB ints
  float* hbuf  = (float*)(lusub + N_SUB);            // NBATCH*DD
  float* oute  = qs;  // reuse: q dead after k_edge

  // zero agg+denom (contiguous)
  k_zero<<<2048, 256, 0, stream>>>(agg, N_SUB*DD + N_SUB*2);
  k_lusub<<<(N_SUB+255)/256, 256, 0, stream>>>(lastu, nid, lusub);

  dim3 gn((N_SUB+63)/64, 4);
  k_node<<<gn, 256, 0, stream>>>(mem, nid, Wq,bq, Wk,bk, Wv,bv, Ws,bs, qs,ks,vs,ss);

  k_edge<<<(NEDGE+63)/64, 256, 0, stream>>>(ei, tt, msg, lusub, wtime, btime, We,
                                            qs, ks, vs, denom, agg);

  k_final<<<(N_SUB*DD+255)/256, 256, 0, stream>>>(agg, denom, ss, oute);

  k_pred1<<<(NBATCH*DD+255)/256, 256, 0, stream>>>(oute, srci, dsti, Wps,bps, Wpd,bpd, hbuf);
  k_pred2<<<(NBATCH*DD+255)/256, 256, 0, stream>>>(hbuf, Wpf, bpf, (float*)d_out);
}

// Round 2
// 691.802 us; speedup vs baseline: 4.2451x; 4.2451x over previous
//
#include <hip/hip_runtime.h>
#include <math.h>

#define N_SUBN  50000
#define NE      500000
#define NB      5000
#define DDIM    100
#define TDIM    100
#define KATTR   200
#define SROW    232     // attr LDS row stride in bf16 elems (29x16B, bank-uniform)

typedef __attribute__((ext_vector_type(8))) short short8;
typedef __attribute__((ext_vector_type(4))) float f32x4;

__device__ inline unsigned short f2bf(float f){
  union{float f; unsigned int u;} v; v.f = f;
  unsigned int r = (v.u + 0x7fffu + ((v.u >> 16) & 1u)) >> 16;   // RNE
  return (unsigned short)r;
}
__device__ inline float bf2f(unsigned short u){
  union{unsigned int u; float f;} v; v.u = ((unsigned int)u) << 16;
  return v.f;
}

// ---------------- zero scratch (bit-zero, works for int too) ----------------
__global__ void k_zero(float* __restrict__ p, int n){
  int i = blockIdx.x*blockDim.x + threadIdx.x;
  int stride = gridDim.x*blockDim.x;
  for (; i < n; i += stride) p[i] = 0.f;
}

// ---------------- lu_sub = last_update[n_id] ----------------
__global__ void k_lusub(const int* __restrict__ last_update, const int* __restrict__ nid,
                        int* __restrict__ lu_sub){
  int i = blockIdx.x*blockDim.x + threadIdx.x;
  if (i < N_SUBN) lu_sub[i] = last_update[nid[i]];
}

// ---------------- CSR: histogram over dst ----------------
__global__ void k_hist(const int* __restrict__ ei, int* __restrict__ cnt){
  int i = blockIdx.x*blockDim.x + threadIdx.x;
  if (i < NE) atomicAdd(&cnt[ei[NE + i]], 1);
}

// ---------------- CSR: single-block scan ----------------
__global__ __launch_bounds__(1024) void k_scan(const int* __restrict__ cnt,
                                               int* __restrict__ rowptr, int* __restrict__ ofs){
  __shared__ int sd[1024];
  __shared__ int carry;
  int tid = threadIdx.x;
  if (tid == 0){ carry = 0; rowptr[0] = 0; }
  __syncthreads();
  for (int base = 0; base < N_SUBN; base += 1024){
    int v = (base + tid < N_SUBN) ? cnt[base + tid] : 0;
    sd[tid] = v; __syncthreads();
    for (int off = 1; off < 1024; off <<= 1){
      int tv = (tid >= off) ? sd[tid - off] : 0;
      __syncthreads();
      sd[tid] += tv;
      __syncthreads();
    }
    int incl = sd[tid];
    int tot  = sd[1023];
    int c    = carry;
    __syncthreads();
    if (base + tid < N_SUBN){
      rowptr[base + tid + 1] = c + incl;
      ofs[base + tid]        = c + incl - v;   // exclusive start
    }
    if (tid == 0) carry = c + tot;
    __syncthreads();
  }
}

// ---------------- CSR: permute edges by dst ----------------
__global__ void k_perm(const int* __restrict__ ei, const int* __restrict__ tt,
                       int* __restrict__ ofs, int* __restrict__ perm,
                       int* __restrict__ ssort, int* __restrict__ tsort){
  int i = blockIdx.x*blockDim.x + threadIdx.x;
  if (i < NE){
    int d = ei[NE + i];
    int pos = atomicAdd(&ofs[d], 1);
    perm[pos]  = i;
    ssort[pos] = ei[i];
    tsort[pos] = tt[i];
  }
}

// ---------------- pack We into B-fragment layout (bf16) ----------------
// Web[(kt*7+nt)*64 + lane] (short8): B[k = kt*32 + (lane>>4)*8 + j][col = nt*16 + (lane&15)]
__global__ void k_web(const float* __restrict__ We, unsigned short* __restrict__ Web){
  int idx = blockIdx.x*blockDim.x + threadIdx.x;
  if (idx >= 49*64) return;
  int l = idx & 63; int t = idx >> 6; int kt = t / 7; int nt = t - kt*7;
  int col = nt*16 + (l & 15);
  int kbase = kt*32 + ((l >> 4) << 3);
  short8 pack;
  #pragma unroll
  for (int j = 0; j < 8; ++j){
    int k = kbase + j;
    float v = (k < KATTR && col < DDIM) ? We[k*DDIM + col] : 0.f;
    pack[j] = (short)f2bf(v);
  }
  *((short8*)Web + idx) = pack;
}

// ---------------- node GEMMs: q,k,v,skip = z @ W + b ----------------
__global__ __launch_bounds__(256) void k_node(
    const float* __restrict__ mem, const int* __restrict__ nid,
    const float* __restrict__ Wq, const float* __restrict__ bq,
    const float* __restrict__ Wk, const float* __restrict__ bk,
    const float* __restrict__ Wv, const float* __restrict__ bv,
    const float* __restrict__ Ws, const float* __restrict__ bs,
    float* __restrict__ qs, float* __restrict__ ks,
    float* __restrict__ vs, float* __restrict__ ss)
{
  __shared__ float zt[64][101];
  const int tid = threadIdx.x;
  const int which = blockIdx.y;
  const float* W    = (which==0)?Wq:(which==1)?Wk:(which==2)?Wv:Ws;
  const float* bias = (which==0)?bq:(which==1)?bk:(which==2)?bv:bs;
  float* outp       = (which==0)?qs:(which==1)?ks:(which==2)?vs:ss;
  const int node0 = blockIdx.x*64;

  for (int idx = tid; idx < 64*DDIM; idx += 256){
    int r = idx/DDIM, j = idx - r*DDIM;
    int node = node0 + r;
    zt[r][j] = (node < N_SUBN) ? mem[(size_t)nid[node]*DDIM + j] : 0.f;
  }
  __syncthreads();

  const int e  = tid & 63;
  const int cg = __builtin_amdgcn_readfirstlane(tid >> 6);
  const int c0 = cg*25;

  float acc[25];
  #pragma unroll
  for (int i=0;i<25;i++) acc[i] = 0.f;
  for (int k=0;k<DDIM;k++){
    float a = zt[e][k];
    const float* wr = W + k*DDIM + c0;
    #pragma unroll
    for (int i=0;i<25;i++) acc[i] = fmaf(a, wr[i], acc[i]);
  }
  const int node = node0 + e;
  if (node < N_SUBN){
    float* op = outp + (size_t)node*DDIM + c0;
    #pragma unroll
    for (int i=0;i<25;i++) op[i] = acc[i] + bias[c0+i];
  }
}

// ---------------- MFMA edge GEMM: evals[p] = [cos_enc, msg] @ We (bf16) ----------------
__global__ __launch_bounds__(256) void k_gemm(
    const int* __restrict__ perm, const int* __restrict__ ssort, const int* __restrict__ tsort,
    const int* __restrict__ lusub, const float* __restrict__ msg,
    const float* __restrict__ wt, const float* __restrict__ bt,
    const unsigned short* __restrict__ Web, unsigned short* __restrict__ evals)
{
  __shared__ unsigned short attr[64][SROW];
  const int tid = threadIdx.x;
  const long p0 = (long)blockIdx.x * 64;

  // K-pad zero (cols 200..231)
  {
    int e = tid & 63; int g = tid >> 6;
    #pragma unroll
    for (int i = 0; i < 8; ++i) attr[e][KATTR + g*8 + i] = 0;
  }
  // cos region (cols 0..99)
  {
    int e = tid & 63; int g = tid >> 6; int c0 = g*25;
    long p = p0 + e;
    bool valid = p < NE;
    long pc = valid ? p : (NE-1);
    int s = ssort[pc];
    float rel = valid ? (float)(lusub[s] - tsort[pc]) : 0.f;
    for (int i = 0; i < 25; ++i){
      int j = c0 + i;
      float arg = __fadd_rn(__fmul_rn(rel, wt[j]), bt[j]);
      attr[e][j] = valid ? f2bf(cosf(arg)) : (unsigned short)0;
    }
  }
  // msg region (cols 100..199)
  {
    int e = tid >> 2; int part = tid & 3; int j0 = part*25;
    long p = p0 + e;
    bool valid = p < NE;
    long eid = valid ? (long)perm[p] : 0;
    const float* mrow = msg + eid*DDIM + j0;
    for (int i = 0; i < 25; ++i)
      attr[e][TDIM + j0 + i] = valid ? f2bf(mrow[i]) : (unsigned short)0;
  }
  __syncthreads();

  const int lane = tid & 63;
  const int w = tid >> 6;
  const int arow = w*16 + (lane & 15);
  const int koff = (lane >> 4) * 8;

  f32x4 acc[7];
  #pragma unroll
  for (int nt=0; nt<7; ++nt) acc[nt] = (f32x4){0.f,0.f,0.f,0.f};

  for (int kt=0; kt<7; ++kt){
    short8 a = *(const short8*)&attr[arow][kt*32 + koff];
    const short8* wb = (const short8*)Web + (size_t)(kt*7)*64 + lane;
    #pragma unroll
    for (int nt=0; nt<7; ++nt){
      short8 b = wb[(size_t)nt*64];
      acc[nt] = __builtin_amdgcn_mfma_f32_16x16x32_bf16(a, b, acc[nt], 0, 0, 0);
    }
  }

  // epilogue: D row=(lane>>4)*4+r (+16w), col=nt*16+(lane&15)
  const int colb = lane & 15;
  const int rbase = w*16 + ((lane >> 4) << 2);
  #pragma unroll
  for (int nt=0; nt<7; ++nt){
    int col = nt*16 + colb;
    if (col >= DDIM) continue;
    #pragma unroll
    for (int r=0; r<4; ++r){
      long p = p0 + rbase + r;
      if (p < NE) evals[p*DDIM + col] = f2bf(acc[nt][r]);
    }
  }
}

// ---------------- per-dst aggregation (one wave per node, no atomics) ----------------
__global__ __launch_bounds__(256) void k_agg(
    const int* __restrict__ rowptr, const int* __restrict__ ssort,
    const unsigned short* __restrict__ evals,
    const float* __restrict__ qs, const float* __restrict__ ks, const float* __restrict__ vs,
    const float* __restrict__ ssb, float* __restrict__ oute)
{
  const int w = threadIdx.x >> 6;
  const int lane = threadIdx.x & 63;
  const int node = blockIdx.x*4 + w;
  if (node >= N_SUBN) return;

  const int c1 = lane;            // 0..63
  const int c2 = 64 + lane;       // 64..99 valid when lane<36
  const bool has2 = lane < 36;
  const bool h0_1 = c1 < 50;      // head of channel c1

  const float q1 = qs[(size_t)node*DDIM + c1];
  const float q2 = has2 ? qs[(size_t)node*DDIM + c2] : 0.f;

  float num1 = 0.f, num2 = 0.f, den0 = 0.f, den1 = 0.f;
  const int b0 = rowptr[node], b1 = rowptr[node+1];

  for (int p = b0; p < b1; ++p){
    int s = ssort[p];
    float e1 = bf2f(evals[(size_t)p*DDIM + c1]);
    float e2 = has2 ? bf2f(evals[(size_t)p*DDIM + c2]) : 0.f;
    float k1 = ks[(size_t)s*DDIM + c1] + e1;
    float k2 = has2 ? (ks[(size_t)s*DDIM + c2] + e2) : 0.f;
    float v1 = vs[(size_t)s*DDIM + c1] + e1;
    float v2 = has2 ? (vs[(size_t)s*DDIM + c2] + e2) : 0.f;

    float ph0 = h0_1 ? q1*k1 : 0.f;
    float ph1 = (h0_1 ? 0.f : q1*k1) + q2*k2;   // c2 always head1; q2,k2==0 if !has2

    #pragma unroll
    for (int m = 32; m; m >>= 1){
      ph0 += __shfl_xor(ph0, m);
      ph1 += __shfl_xor(ph1, m);
    }
    float a0 = expf(ph0 * 0.14142135623730951f);
    float a1 = expf(ph1 * 0.14142135623730951f);
    den0 += a0; den1 += a1;
    num1 += (h0_1 ? a0 : a1) * v1;
    num2 += a1 * v2;
  }

  float o1 = num1 / ((h0_1 ? den0 : den1) + 1e-16f) + ssb[(size_t)node*DDIM + c1];
  oute[(size_t)node*DDIM + c1] = o1;
  if (has2)
    oute[(size_t)node*DDIM + c2] = num2 / (den1 + 1e-16f) + ssb[(size_t)node*DDIM + c2];
}

// ---------------- predictor ----------------
__global__ __launch_bounds__(256) void k_pred1(
    const float* __restrict__ oute, const int* __restrict__ srci, const int* __restrict__ dsti,
    const float* __restrict__ Wps, const float* __restrict__ bps,
    const float* __restrict__ Wpd, const float* __restrict__ bpd,
    float* __restrict__ hbuf)
{
  int i = blockIdx.x*256 + threadIdx.x;
  if (i >= NB*DDIM) return;
  int b = i/DDIM, c = i - b*DDIM;
  const float* r1 = oute + (size_t)srci[b]*DDIM;
  const float* r2 = oute + (size_t)dsti[b]*DDIM;
  float a = bps[c] + bpd[c];
  for (int k=0;k<DDIM;k++){
    a = fmaf(r1[k], Wps[k*DDIM+c], a);
    a = fmaf(r2[k], Wpd[k*DDIM+c], a);
  }
  hbuf[i] = fmaxf(a, 0.f);
}

__global__ __launch_bounds__(256) void k_pred2(
    const float* __restrict__ hbuf, const float* __restrict__ Wpf, const float* __restrict__ bpf,
    float* __restrict__ outp)
{
  int i = blockIdx.x*256 + threadIdx.x;
  if (i >= NB*DDIM) return;
  int b = i/DDIM, c = i - b*DDIM;
  const float* hr = hbuf + (size_t)b*DDIM;
  float a = bpf[c];
  for (int k=0;k<DDIM;k++) a = fmaf(hr[k], Wpf[k*DDIM+c], a);
  outp[i] = a;
}

extern "C" void kernel_launch(void* const* d_in, const int* in_sizes, int n_in,
                              void* d_out, int out_size, void* d_ws, size_t ws_size,
                              hipStream_t stream)
{
  const float* mem   = (const float*)d_in[0];
  const int*   lastu = (const int*)  d_in[1];
  const int*   nid   = (const int*)  d_in[2];
  const int*   ei    = (const int*)  d_in[3];
  const int*   tt    = (const int*)  d_in[4];
  const float* msg   = (const float*)d_in[5];
  const int*   srci  = (const int*)  d_in[6];
  const int*   dsti  = (const int*)  d_in[7];
  const float* wtime = (const float*)d_in[8];
  const float* btime = (const float*)d_in[9];
  const float* Wq = (const float*)d_in[10]; const float* bq = (const float*)d_in[11];
  const float* Wk = (const float*)d_in[12]; const float* bk = (const float*)d_in[13];
  const float* Wv = (const float*)d_in[14]; const float* bv = (const float*)d_in[15];
  const float* We = (const float*)d_in[16];
  const float* Ws = (const float*)d_in[17]; const float* bs = (const float*)d_in[18];
  const float* Wps= (const float*)d_in[19]; const float* bps= (const float*)d_in[20];
  const float* Wpd= (const float*)d_in[21]; const float* bpd= (const float*)d_in[22];
  const float* Wpf= (const float*)d_in[23]; const float* bpf= (const float*)d_in[24];

  char* wsp = (char*)d_ws;
  auto alloc = [&](size_t bytes)->void*{
    void* p = (void*)wsp;
    wsp += (bytes + 255) & ~(size_t)255;
    return p;
  };
  unsigned short* evals = (unsigned short*)alloc((size_t)NE*DDIM*2);   // 100 MB
  float* qs   = (float*)alloc((size_t)N_SUBN*DDIM*4);
  float* ks   = (float*)alloc((size_t)N_SUBN*DDIM*4);
  float* vs   = (float*)alloc((size_t)N_SUBN*DDIM*4);
  float* ssb  = (float*)alloc((size_t)N_SUBN*DDIM*4);
  float* oute = (float*)alloc((size_t)N_SUBN*DDIM*4);
  int* cnt    = (int*)alloc((size_t)N_SUBN*4);
  int* rowptr = (int*)alloc((size_t)(N_SUBN+1)*4);
  int* ofs    = (int*)alloc((size_t)N_SUBN*4);
  int* perm   = (int*)alloc((size_t)NE*4);
  int* ssort  = (int*)alloc((size_t)NE*4);
  int* tsort  = (int*)alloc((size_t)NE*4);
  int* lusub  = (int*)alloc((size_t)N_SUBN*4);
  float* hbuf = (float*)alloc((size_t)NB*DDIM*4);
  unsigned short* Web = (unsigned short*)alloc((size_t)49*64*8*2);

  k_zero<<<196, 256, 0, stream>>>((float*)cnt, N_SUBN);
  k_lusub<<<(N_SUBN+255)/256, 256, 0, stream>>>(lastu, nid, lusub);
  k_hist<<<(NE+255)/256, 256, 0, stream>>>(ei, cnt);
  k_scan<<<1, 1024, 0, stream>>>(cnt, rowptr, ofs);
  k_perm<<<(NE+255)/256, 256, 0, stream>>>(ei, tt, ofs, perm, ssort, tsort);
  k_web<<<(49*64+255)/256, 256, 0, stream>>>(We, Web);

  dim3 gn((N_SUBN+63)/64, 4);
  k_node<<<gn, 256, 0, stream>>>(mem, nid, Wq,bq, Wk,bk, Wv,bv, Ws,bs, qs,ks,vs,ssb);

  k_gemm<<<(NE+63)/64, 256, 0, stream>>>(perm, ssort, tsort, lusub, msg,
                                         wtime, btime, Web, evals);

  k_agg<<<(N_SUBN+3)/4, 256, 0, stream>>>(rowptr, ssort, evals, qs, ks, vs, ssb, oute);

  k_pred1<<<(NB*DDIM+255)/256, 256, 0, stream>>>(oute, srci, dsti, Wps,bps, Wpd,bpd, hbuf);
  k_pred2<<<(NB*DDIM+255)/256, 256, 0, stream>>>(hbuf, Wpf, bpf, (float*)d_out);
}

// Round 3
// 528.332 us; speedup vs baseline: 5.5586x; 1.3094x over previous
//
#include <hip/hip_runtime.h>
#include <math.h>

#define N_SUBN  50000
#define NE      500000
#define NB      5000
#define DDIM    100
#define TDIM    100
#define KATTR   200
#define NCHUNK  49        // ceil(N_SUBN/1024)

typedef __attribute__((ext_vector_type(8))) short short8;
typedef __attribute__((ext_vector_type(4))) float f32x4;

__device__ inline unsigned short f2bf(float f){
  union{float f; unsigned int u;} v; v.f = f;
  unsigned int r = (v.u + 0x7fffu + ((v.u >> 16) & 1u)) >> 16;   // RNE
  return (unsigned short)r;
}
__device__ inline float bf2f(unsigned short u){
  union{unsigned int u; float f;} v; v.u = ((unsigned int)u) << 16;
  return v.f;
}

// ---------------- zero scratch ----------------
__global__ void k_zero(int* __restrict__ p, int n){
  int i = blockIdx.x*blockDim.x + threadIdx.x;
  int stride = gridDim.x*blockDim.x;
  for (; i < n; i += stride) p[i] = 0;
}

// ---------------- lu_sub = last_update[n_id] ----------------
__global__ void k_lusub(const int* __restrict__ last_update, const int* __restrict__ nid,
                        int* __restrict__ lu_sub){
  int i = blockIdx.x*blockDim.x + threadIdx.x;
  if (i < N_SUBN) lu_sub[i] = last_update[nid[i]];
}

// ---------------- CSR: histogram over dst ----------------
__global__ void k_hist(const int* __restrict__ ei, int* __restrict__ cnt){
  int i = blockIdx.x*blockDim.x + threadIdx.x;
  if (i < NE) atomicAdd(&cnt[ei[NE + i]], 1);
}

// ---------------- CSR scan phase 1: per-1024-chunk sums ----------------
__global__ __launch_bounds__(256) void k_bsum(const int* __restrict__ cnt, int* __restrict__ bsum){
  __shared__ int wsum[4];
  int b = blockIdx.x, tid = threadIdx.x;
  int base = b*1024 + tid*4;
  int s = 0;
  #pragma unroll
  for (int i=0;i<4;i++){ int idx = base+i; if (idx < N_SUBN) s += cnt[idx]; }
  #pragma unroll
  for (int m=1;m<64;m<<=1) s += __shfl_xor(s, m);
  if ((tid&63)==0) wsum[tid>>6] = s;
  __syncthreads();
  if (tid==0) bsum[b] = wsum[0]+wsum[1]+wsum[2]+wsum[3];
}

// ---------------- CSR scan phase 2: exclusive scan of chunk sums (1 wave) ----------------
__global__ void k_bscan(const int* __restrict__ bsum, int* __restrict__ bbase){
  int l = threadIdx.x;
  int v = (l < NCHUNK) ? bsum[l] : 0;
  int orig = v;
  for (int off=1; off<64; off<<=1){
    int t = __shfl_up(v, off);
    if (l >= off) v += t;
  }
  if (l < NCHUNK) bbase[l] = v - orig;   // exclusive
}

// ---------------- CSR scan phase 3: per-chunk inclusive scan + base ----------------
__global__ __launch_bounds__(1024) void k_off(const int* __restrict__ cnt, const int* __restrict__ bbase,
                                              int* __restrict__ rowptr, int* __restrict__ ofs){
  __shared__ int sd[1024];
  int b = blockIdx.x, tid = threadIdx.x;
  int i = b*1024 + tid;
  int v = (i < N_SUBN) ? cnt[i] : 0;
  sd[tid] = v; __syncthreads();
  for (int off=1; off<1024; off<<=1){
    int t = (tid >= off) ? sd[tid-off] : 0;
    __syncthreads();
    sd[tid] += t;
    __syncthreads();
  }
  int incl = sd[tid] + bbase[b];
  if (i < N_SUBN){ rowptr[i+1] = incl; ofs[i] = incl - v; }
  if (i == 0) rowptr[0] = 0;
}

// ---------------- CSR: bucket edges by dst ----------------
__global__ void k_perm(const int* __restrict__ ei, int* __restrict__ ofs,
                       int* __restrict__ perm, int* __restrict__ ssort){
  int i = blockIdx.x*blockDim.x + threadIdx.x;
  if (i < NE){
    int d = ei[NE + i];
    int pos = atomicAdd(&ofs[d], 1);
    perm[pos]  = i;
    ssort[pos] = ei[i];
  }
}

// ---------------- pack We into B-fragment layout (bf16) ----------------
__global__ void k_web(const float* __restrict__ We, unsigned short* __restrict__ Web){
  int idx = blockIdx.x*blockDim.x + threadIdx.x;
  if (idx >= 49*64) return;
  int l = idx & 63; int t = idx >> 6; int kt = t / 7; int nt = t - kt*7;
  int col = nt*16 + (l & 15);
  int kbase = kt*32 + ((l >> 4) << 3);
  short8 pack;
  #pragma unroll
  for (int j = 0; j < 8; ++j){
    int k = kbase + j;
    float v = (k < KATTR && col < DDIM) ? We[k*DDIM + col] : 0.f;
    pack[j] = (short)f2bf(v);
  }
  *((short8*)Web + idx) = pack;
}

// ---------------- node GEMMs fused: q,k,v,skip = z @ W + b (z staged once) ----------------
__global__ __launch_bounds__(256) void k_node(
    const float* __restrict__ mem, const int* __restrict__ nid,
    const float* __restrict__ Wq, const float* __restrict__ bq,
    const float* __restrict__ Wk, const float* __restrict__ bk,
    const float* __restrict__ Wv, const float* __restrict__ bv,
    const float* __restrict__ Ws, const float* __restrict__ bs,
    float* __restrict__ qs, float* __restrict__ ks,
    float* __restrict__ vs, float* __restrict__ ss)
{
  __shared__ float zt[64][101];
  const int tid = threadIdx.x;
  const int node0 = blockIdx.x*64;

  for (int idx = tid; idx < 64*DDIM; idx += 256){
    int r = idx/DDIM, j = idx - r*DDIM;
    int node = node0 + r;
    zt[r][j] = (node < N_SUBN) ? mem[(size_t)nid[node]*DDIM + j] : 0.f;
  }
  __syncthreads();

  const int e  = tid & 63;
  const int cg = __builtin_amdgcn_readfirstlane(tid >> 6);
  const int c0 = cg*25;
  const int node = node0 + e;

  #pragma unroll
  for (int which = 0; which < 4; ++which){
    const float* W    = (which==0)?Wq:(which==1)?Wk:(which==2)?Wv:Ws;
    const float* bias = (which==0)?bq:(which==1)?bk:(which==2)?bv:bs;
    float* outp       = (which==0)?qs:(which==1)?ks:(which==2)?vs:ss;
    float acc[25];
    #pragma unroll
    for (int i=0;i<25;i++) acc[i] = 0.f;
    for (int k=0;k<DDIM;k++){
      float a = zt[e][k];
      const float* wr = W + k*DDIM + c0;   // wave-uniform -> scalar loads
      #pragma unroll
      for (int i=0;i<25;i++) acc[i] = fmaf(a, wr[i], acc[i]);
    }
    if (node < N_SUBN){
      float* op = outp + (size_t)node*DDIM + c0;
      #pragma unroll
      for (int i=0;i<25;i++) op[i] = acc[i] + bias[c0+i];
    }
  }
}

// ---------------- MFMA edge GEMM (original edge order, coalesced msg) ----------------
// attr LDS: 64 rows x 512B, XOR-swizzled: phys = row*512 + (byteoff ^ ((row&7)<<4))
__global__ __launch_bounds__(256) void k_gemm(
    const int* __restrict__ ei, const int* __restrict__ tt,
    const int* __restrict__ lusub, const float* __restrict__ msg,
    const float* __restrict__ wt, const float* __restrict__ bt,
    const unsigned short* __restrict__ Web, unsigned short* __restrict__ evals)
{
  __shared__ char attrb[64*512];
  __shared__ float relv[64];
  const int tid = threadIdx.x;
  const long p0 = (long)blockIdx.x * 64;

  if (tid < 64){
    long p = p0 + tid;
    float rl = 0.f;
    if (p < NE) rl = (float)(lusub[ei[p]] - tt[p]);
    relv[tid] = rl;
  }
  // zero K-pad (logical bytes 400..463 per row = cols 200..231)
  {
    int r = tid >> 2, g = tid & 3;
    int lb = 400 + g*16;
    *(uint4*)(attrb + r*512 + (lb ^ ((r&7)<<4))) = make_uint4(0,0,0,0);
  }
  __syncthreads();

  // cos region: cols 0..99, 4 cols per slot
  for (int idx = tid; idx < 1600; idx += 256){
    int r = idx/25, pp = idx - r*25;
    float rl = relv[r];
    float4 w4 = ((const float4*)wt)[pp];
    float4 b4 = ((const float4*)bt)[pp];
    bool val = (p0 + r) < NE;
    ushort4 o;
    o.x = val ? f2bf(cosf(__fadd_rn(__fmul_rn(rl, w4.x), b4.x))) : (unsigned short)0;
    o.y = val ? f2bf(cosf(__fadd_rn(__fmul_rn(rl, w4.y), b4.y))) : (unsigned short)0;
    o.z = val ? f2bf(cosf(__fadd_rn(__fmul_rn(rl, w4.z), b4.z))) : (unsigned short)0;
    o.w = val ? f2bf(cosf(__fadd_rn(__fmul_rn(rl, w4.w), b4.w))) : (unsigned short)0;
    *(ushort4*)(attrb + r*512 + ((pp*8) ^ ((r&7)<<4))) = o;
  }
  // msg region: cols 100..199, perfectly coalesced float4 stream
  {
    const float4* m4 = (const float4*)msg;
    for (int idx = tid; idx < 1600; idx += 256){
      int r = idx/25, pp = idx - r*25;
      bool val = (p0 + r) < NE;
      float4 mv = val ? m4[p0*25 + idx] : make_float4(0.f,0.f,0.f,0.f);
      ushort4 o;
      o.x = f2bf(mv.x); o.y = f2bf(mv.y); o.z = f2bf(mv.z); o.w = f2bf(mv.w);
      *(ushort4*)(attrb + r*512 + ((200 + pp*8) ^ ((r&7)<<4))) = o;
    }
  }
  __syncthreads();

  const int lane = tid & 63;
  const int w = tid >> 6;
  const int arow = w*16 + (lane & 15);
  const int kbyte0 = (lane >> 4) << 4;
  const int aswz = (arow & 7) << 4;

  f32x4 acc[7];
  #pragma unroll
  for (int nt=0; nt<7; ++nt) acc[nt] = (f32x4){0.f,0.f,0.f,0.f};

  #pragma unroll
  for (int kt=0; kt<7; ++kt){
    short8 a = *(const short8*)(attrb + arow*512 + ((kt*64 + kbyte0) ^ aswz));
    const short8* wb = (const short8*)Web + (size_t)(kt*7)*64 + lane;
    #pragma unroll
    for (int nt=0; nt<7; ++nt){
      short8 b = wb[(size_t)nt*64];
      acc[nt] = __builtin_amdgcn_mfma_f32_16x16x32_bf16(a, b, acc[nt], 0, 0, 0);
    }
  }

  const int colb = lane & 15;
  const int rbase = w*16 + ((lane >> 4) << 2);
  #pragma unroll
  for (int nt=0; nt<7; ++nt){
    int col = nt*16 + colb;
    if (col >= DDIM) continue;
    #pragma unroll
    for (int r=0; r<4; ++r){
      long p = p0 + rbase + r;
      if (p < NE) evals[p*DDIM + col] = f2bf(acc[nt][r]);
    }
  }
}

// ---------------- per-dst aggregation: head0 -> lanes 0..24, head1 -> lanes 32..56 ----------------
__global__ __launch_bounds__(256) void k_agg(
    const int* __restrict__ rowptr, const int* __restrict__ ssort, const int* __restrict__ perm,
    const unsigned short* __restrict__ evals,
    const float* __restrict__ qs, const float* __restrict__ ks, const float* __restrict__ vs,
    const float* __restrict__ ssb, float* __restrict__ oute)
{
  const int w = threadIdx.x >> 6;
  const int lane = threadIdx.x & 63;
  const int node = blockIdx.x*4 + w;
  if (node >= N_SUBN) return;

  const int half = lane >> 5;               // 0: head0, 1: head1
  const int lh = lane & 31;
  const bool act = lh < 25;
  const int c = half*50 + lh*2;             // col pair (c, c+1)

  float q0 = 0.f, q1 = 0.f;
  if (act){
    float2 qq = *(const float2*)(qs + (size_t)node*DDIM + c);
    q0 = qq.x; q1 = qq.y;
  }
  const int b0 = rowptr[node], b1 = rowptr[node+1];
  float num0 = 0.f, num1 = 0.f, den = 0.f;
  const float INV = 0.14142135623730951f;   // 1/sqrt(50)

  int p = b0;
  for (; p+1 < b1; p += 2){
    int sA = ssort[p],  sB = ssort[p+1];
    int eA = perm[p],   eB = perm[p+1];
    float eA0=0,eA1=0,kA0=0,kA1=0,vA0=0,vA1=0;
    float eB0=0,eB1=0,kB0=0,kB1=0,vB0=0,vB1=0;
    if (act){
      unsigned ea = *(const unsigned*)(evals + (size_t)eA*DDIM + c);
      unsigned eb = *(const unsigned*)(evals + (size_t)eB*DDIM + c);
      float2 ka = *(const float2*)(ks + (size_t)sA*DDIM + c);
      float2 kb = *(const float2*)(ks + (size_t)sB*DDIM + c);
      float2 va = *(const float2*)(vs + (size_t)sA*DDIM + c);
      float2 vb = *(const float2*)(vs + (size_t)sB*DDIM + c);
      eA0 = bf2f((unsigned short)(ea & 0xffff)); eA1 = bf2f((unsigned short)(ea >> 16));
      eB0 = bf2f((unsigned short)(eb & 0xffff)); eB1 = bf2f((unsigned short)(eb >> 16));
      kA0 = ka.x; kA1 = ka.y; kB0 = kb.x; kB1 = kb.y;
      vA0 = va.x; vA1 = va.y; vB0 = vb.x; vB1 = vb.y;
    }
    float phA = fmaf(q0, kA0+eA0, q1*(kA1+eA1));
    float phB = fmaf(q0, kB0+eB0, q1*(kB1+eB1));
    #pragma unroll
    for (int m=1; m<32; m<<=1){
      phA += __shfl_xor(phA, m);
      phB += __shfl_xor(phB, m);
    }
    float aA = expf(phA * INV), aB = expf(phB * INV);
    den += aA + aB;
    num0 = fmaf(aA, vA0+eA0, num0); num0 = fmaf(aB, vB0+eB0, num0);
    num1 = fmaf(aA, vA1+eA1, num1); num1 = fmaf(aB, vB1+eB1, num1);
  }
  if (p < b1){
    int sA = ssort[p]; int eA = perm[p];
    float eA0=0,eA1=0,kA0=0,kA1=0,vA0=0,vA1=0;
    if (act){
      unsigned ea = *(const unsigned*)(evals + (size_t)eA*DDIM + c);
      float2 ka = *(const float2*)(ks + (size_t)sA*DDIM + c);
      float2 va = *(const float2*)(vs + (size_t)sA*DDIM + c);
      eA0 = bf2f((unsigned short)(ea & 0xffff)); eA1 = bf2f((unsigned short)(ea >> 16));
      kA0 = ka.x; kA1 = ka.y; vA0 = va.x; vA1 = va.y;
    }
    float phA = fmaf(q0, kA0+eA0, q1*(kA1+eA1));
    #pragma unroll
    for (int m=1; m<32; m<<=1) phA += __shfl_xor(phA, m);
    float aA = expf(phA * INV);
    den += aA;
    num0 = fmaf(aA, vA0+eA0, num0);
    num1 = fmaf(aA, vA1+eA1, num1);
  }

  if (act){
    float inv_d = 1.f / (den + 1e-16f);
    const float* sp = ssb + (size_t)node*DDIM + c;
    float* op = oute + (size_t)node*DDIM + c;
    op[0] = num0*inv_d + sp[0];
    op[1] = num1*inv_d + sp[1];
  }
}

// ---------------- predictor ----------------
__global__ __launch_bounds__(256) void k_pred1(
    const float* __restrict__ oute, const int* __restrict__ srci, const int* __restrict__ dsti,
    const float* __restrict__ Wps, const float* __restrict__ bps,
    const float* __restrict__ Wpd, const float* __restrict__ bpd,
    float* __restrict__ hbuf)
{
  int i = blockIdx.x*256 + threadIdx.x;
  if (i >= NB*DDIM) return;
  int b = i/DDIM, c = i - b*DDIM;
  const float* r1 = oute + (size_t)srci[b]*DDIM;
  const float* r2 = oute + (size_t)dsti[b]*DDIM;
  float a = bps[c] + bpd[c];
  for (int k=0;k<DDIM;k++){
    a = fmaf(r1[k], Wps[k*DDIM+c], a);
    a = fmaf(r2[k], Wpd[k*DDIM+c], a);
  }
  hbuf[i] = fmaxf(a, 0.f);
}

__global__ __launch_bounds__(256) void k_pred2(
    const float* __restrict__ hbuf, const float* __restrict__ Wpf, const float* __restrict__ bpf,
    float* __restrict__ outp)
{
  int i = blockIdx.x*256 + threadIdx.x;
  if (i >= NB*DDIM) return;
  int b = i/DDIM, c = i - b*DDIM;
  const float* hr = hbuf + (size_t)b*DDIM;
  float a = bpf[c];
  for (int k=0;k<DDIM;k++) a = fmaf(hr[k], Wpf[k*DDIM+c], a);
  outp[i] = a;
}

extern "C" void kernel_launch(void* const* d_in, const int* in_sizes, int n_in,
                              void* d_out, int out_size, void* d_ws, size_t ws_size,
                              hipStream_t stream)
{
  const float* mem   = (const float*)d_in[0];
  const int*   lastu = (const int*)  d_in[1];
  const int*   nid   = (const int*)  d_in[2];
  const int*   ei    = (const int*)  d_in[3];
  const int*   tt    = (const int*)  d_in[4];
  const float* msg   = (const float*)d_in[5];
  const int*   srci  = (const int*)  d_in[6];
  const int*   dsti  = (const int*)  d_in[7];
  const float* wtime = (const float*)d_in[8];
  const float* btime = (const float*)d_in[9];
  const float* Wq = (const float*)d_in[10]; const float* bq = (const float*)d_in[11];
  const float* Wk = (const float*)d_in[12]; const float* bk = (const float*)d_in[13];
  const float* Wv = (const float*)d_in[14]; const float* bv = (const float*)d_in[15];
  const float* We = (const float*)d_in[16];
  const float* Ws = (const float*)d_in[17]; const float* bs = (const float*)d_in[18];
  const float* Wps= (const float*)d_in[19]; const float* bps= (const float*)d_in[20];
  const float* Wpd= (const float*)d_in[21]; const float* bpd= (const float*)d_in[22];
  const float* Wpf= (const float*)d_in[23]; const float* bpf= (const float*)d_in[24];

  char* wsp = (char*)d_ws;
  auto alloc = [&](size_t bytes)->void*{
    void* p = (void*)wsp;
    wsp += (bytes + 255) & ~(size_t)255;
    return p;
  };
  unsigned short* evals = (unsigned short*)alloc((size_t)NE*DDIM*2);   // 100 MB
  float* qs   = (float*)alloc((size_t)N_SUBN*DDIM*4);
  float* ks   = (float*)alloc((size_t)N_SUBN*DDIM*4);
  float* vs   = (float*)alloc((size_t)N_SUBN*DDIM*4);
  float* ssb  = (float*)alloc((size_t)N_SUBN*DDIM*4);
  float* oute = (float*)alloc((size_t)N_SUBN*DDIM*4);
  int* cnt    = (int*)alloc((size_t)N_SUBN*4);
  int* rowptr = (int*)alloc((size_t)(N_SUBN+1)*4);
  int* ofs    = (int*)alloc((size_t)N_SUBN*4);
  int* bsum   = (int*)alloc((size_t)NCHUNK*4);
  int* bbase  = (int*)alloc((size_t)NCHUNK*4);
  int* perm   = (int*)alloc((size_t)NE*4);
  int* ssort  = (int*)alloc((size_t)NE*4);
  int* lusub  = (int*)alloc((size_t)N_SUBN*4);
  float* hbuf = (float*)alloc((size_t)NB*DDIM*4);
  unsigned short* Web = (unsigned short*)alloc((size_t)49*64*8*2);

  k_zero<<<64, 256, 0, stream>>>(cnt, N_SUBN);
  k_lusub<<<(N_SUBN+255)/256, 256, 0, stream>>>(lastu, nid, lusub);
  k_hist<<<(NE+255)/256, 256, 0, stream>>>(ei, cnt);
  k_bsum<<<NCHUNK, 256, 0, stream>>>(cnt, bsum);
  k_bscan<<<1, 64, 0, stream>>>(bsum, bbase);
  k_off<<<NCHUNK, 1024, 0, stream>>>(cnt, bbase, rowptr, ofs);
  k_perm<<<(NE+255)/256, 256, 0, stream>>>(ei, ofs, perm, ssort);
  k_web<<<(49*64+255)/256, 256, 0, stream>>>(We, Web);

  k_node<<<(N_SUBN+63)/64, 256, 0, stream>>>(mem, nid, Wq,bq, Wk,bk, Wv,bv, Ws,bs,
                                             qs, ks, vs, ssb);

  k_gemm<<<(NE+63)/64, 256, 0, stream>>>(ei, tt, lusub, msg, wtime, btime, Web, evals);

  k_agg<<<(N_SUBN+3)/4, 256, 0, stream>>>(rowptr, ssort, perm, evals, qs, ks, vs, ssb, oute);

  k_pred1<<<(NB*DDIM+255)/256, 256, 0, stream>>>(oute, srci, dsti, Wps,bps, Wpd,bpd, hbuf);
  k_pred2<<<(NB*DDIM+255)/256, 256, 0, stream>>>(hbuf, Wpf, bpf, (float*)d_out);
}

// Round 4
// 482.117 us; speedup vs baseline: 6.0914x; 1.0959x over previous
//
#include <hip/hip_runtime.h>
#include <math.h>

#define N_SUBN  50000
#define NE      500000
#define NB      5000
#define DDIM    100
#define TDIM    100
#define KATTR   200
#define NCHUNK  49        // ceil(N_SUBN/1024)

typedef __attribute__((ext_vector_type(8))) short short8;
typedef __attribute__((ext_vector_type(4))) float f32x4;

__device__ inline unsigned short f2bf(float f){
  union{float f; unsigned int u;} v; v.f = f;
  unsigned int r = (v.u + 0x7fffu + ((v.u >> 16) & 1u)) >> 16;   // RNE
  return (unsigned short)r;
}
__device__ inline float bf2f(unsigned short u){
  union{unsigned int u; float f;} v; v.u = ((unsigned int)u) << 16;
  return v.f;
}

// ---------------- fused: zero cnt + lusub gather + We B-fragment pack ----------------
__global__ __launch_bounds__(256) void k_misc(
    const int* __restrict__ lastu, const int* __restrict__ nid,
    int* __restrict__ cnt, int* __restrict__ lusub,
    const float* __restrict__ We, unsigned short* __restrict__ Web)
{
  int i = blockIdx.x*256 + threadIdx.x;
  if (i < N_SUBN){
    cnt[i] = 0;
    lusub[i] = lastu[nid[i]];
  }
  if (i < 49*64){
    int l = i & 63; int t = i >> 6; int kt = t / 7; int nt = t - kt*7;
    int col = nt*16 + (l & 15);
    int kbase = kt*32 + ((l >> 4) << 3);
    short8 pack;
    #pragma unroll
    for (int j = 0; j < 8; ++j){
      int k = kbase + j;
      float v = (k < KATTR && col < DDIM) ? We[k*DDIM + col] : 0.f;
      pack[j] = (short)f2bf(v);
    }
    *((short8*)Web + i) = pack;
  }
}

// ---------------- CSR: histogram over dst ----------------
__global__ void k_hist(const int* __restrict__ ei, int* __restrict__ cnt){
  int i = blockIdx.x*blockDim.x + threadIdx.x;
  if (i < NE) atomicAdd(&cnt[ei[NE + i]], 1);
}

// ---------------- CSR scan phase 1: per-1024-chunk sums ----------------
__global__ __launch_bounds__(256) void k_bsum(const int* __restrict__ cnt, int* __restrict__ bsum){
  __shared__ int wsum[4];
  int b = blockIdx.x, tid = threadIdx.x;
  int base = b*1024 + tid*4;
  int s = 0;
  #pragma unroll
  for (int i=0;i<4;i++){ int idx = base+i; if (idx < N_SUBN) s += cnt[idx]; }
  #pragma unroll
  for (int m=1;m<64;m<<=1) s += __shfl_xor(s, m);
  if ((tid&63)==0) wsum[tid>>6] = s;
  __syncthreads();
  if (tid==0) bsum[b] = wsum[0]+wsum[1]+wsum[2]+wsum[3];
}

// ---------------- CSR scan phase 2: exclusive scan of chunk sums (1 wave) ----------------
__global__ void k_bscan(const int* __restrict__ bsum, int* __restrict__ bbase){
  int l = threadIdx.x;
  int v = (l < NCHUNK) ? bsum[l] : 0;
  int orig = v;
  for (int off=1; off<64; off<<=1){
    int t = __shfl_up(v, off);
    if (l >= off) v += t;
  }
  if (l < NCHUNK) bbase[l] = v - orig;   // exclusive
}

// ---------------- CSR scan phase 3: per-chunk inclusive scan + base ----------------
__global__ __launch_bounds__(1024) void k_off(const int* __restrict__ cnt, const int* __restrict__ bbase,
                                              int* __restrict__ rowptr, int* __restrict__ ofs){
  __shared__ int sd[1024];
  int b = blockIdx.x, tid = threadIdx.x;
  int i = b*1024 + tid;
  int v = (i < N_SUBN) ? cnt[i] : 0;
  sd[tid] = v; __syncthreads();
  for (int off=1; off<1024; off<<=1){
    int t = (tid >= off) ? sd[tid-off] : 0;
    __syncthreads();
    sd[tid] += t;
    __syncthreads();
  }
  int incl = sd[tid] + bbase[b];
  if (i < N_SUBN){ rowptr[i+1] = incl; ofs[i] = incl - v; }
  if (i == 0) rowptr[0] = 0;
}

// ---------------- CSR: bucket edges by dst, packed (perm<<32 | src) ----------------
__global__ void k_perm(const int* __restrict__ ei, int* __restrict__ ofs,
                       unsigned long long* __restrict__ sp64){
  int i = blockIdx.x*blockDim.x + threadIdx.x;
  if (i < NE){
    int d = ei[NE + i];
    int pos = atomicAdd(&ofs[d], 1);
    sp64[pos] = ((unsigned long long)(unsigned)i << 32) | (unsigned)ei[i];
  }
}

// ---------------- node GEMMs fused: q,k,v,skip = z @ W + b (z staged once) ----------------
__global__ __launch_bounds__(256) void k_node(
    const float* __restrict__ mem, const int* __restrict__ nid,
    const float* __restrict__ Wq, const float* __restrict__ bq,
    const float* __restrict__ Wk, const float* __restrict__ bk,
    const float* __restrict__ Wv, const float* __restrict__ bv,
    const float* __restrict__ Ws, const float* __restrict__ bs,
    float* __restrict__ qs, float* __restrict__ ks,
    float* __restrict__ vs, float* __restrict__ ss)
{
  __shared__ float zt[64][101];
  const int tid = threadIdx.x;
  const int node0 = blockIdx.x*64;

  for (int idx = tid; idx < 64*DDIM; idx += 256){
    int r = idx/DDIM, j = idx - r*DDIM;
    int node = node0 + r;
    zt[r][j] = (node < N_SUBN) ? mem[(size_t)nid[node]*DDIM + j] : 0.f;
  }
  __syncthreads();

  const int e  = tid & 63;
  const int cg = __builtin_amdgcn_readfirstlane(tid >> 6);
  const int c0 = cg*25;
  const int node = node0 + e;

  #pragma unroll
  for (int which = 0; which < 4; ++which){
    const float* W    = (which==0)?Wq:(which==1)?Wk:(which==2)?Wv:Ws;
    const float* bias = (which==0)?bq:(which==1)?bk:(which==2)?bv:bs;
    float* outp       = (which==0)?qs:(which==1)?ks:(which==2)?vs:ss;
    float acc[25];
    #pragma unroll
    for (int i=0;i<25;i++) acc[i] = 0.f;
    for (int k=0;k<DDIM;k++){
      float a = zt[e][k];
      const float* wr = W + k*DDIM + c0;   // wave-uniform -> scalar loads
      #pragma unroll
      for (int i=0;i<25;i++) acc[i] = fmaf(a, wr[i], acc[i]);
    }
    if (node < N_SUBN){
      float* op = outp + (size_t)node*DDIM + c0;
      #pragma unroll
      for (int i=0;i<25;i++) op[i] = acc[i] + bias[c0+i];
    }
  }
}

// ---------------- MFMA edge GEMM, barrier-free: A-fragments built in registers ----------------
// A layout for mfma_f32_16x16x32_bf16: lane holds row = 16w + (lane&15),
// k = kt*32 + (lane>>4)*8 + j.  Each (row,k) produced by exactly one lane.
__global__ __launch_bounds__(256) void k_gemm(
    const int* __restrict__ ei, const int* __restrict__ tt,
    const int* __restrict__ lusub, const float* __restrict__ msg,
    const float* __restrict__ wt, const float* __restrict__ bt,
    const unsigned short* __restrict__ Web, unsigned short* __restrict__ evals)
{
  const int tid = threadIdx.x;
  const int lane = tid & 63;
  const int w = tid >> 6;
  const long p0 = (long)blockIdx.x * 64;
  const int arow = w*16 + (lane & 15);
  const int koff = (lane >> 4) << 3;           // 0,8,16,24

  long p = p0 + arow;
  long pc = (p < NE) ? p : (NE - 1);
  const float rel = (float)(lusub[ei[pc]] - tt[pc]);
  const float* mrow = msg + pc*DDIM;

  f32x4 acc[7];
  #pragma unroll
  for (int nt=0; nt<7; ++nt) acc[nt] = (f32x4){0.f,0.f,0.f,0.f};

  #pragma unroll
  for (int kt=0; kt<7; ++kt){
    const int k0 = kt*32 + koff;
    short8 a;
    if (k0 + 7 < TDIM){
      // pure cos region
      float4 w0 = *(const float4*)(wt + k0);
      float4 w1 = *(const float4*)(wt + k0 + 4);
      float4 b0 = *(const float4*)(bt + k0);
      float4 b1 = *(const float4*)(bt + k0 + 4);
      a[0] = (short)f2bf(cosf(__fadd_rn(__fmul_rn(rel, w0.x), b0.x)));
      a[1] = (short)f2bf(cosf(__fadd_rn(__fmul_rn(rel, w0.y), b0.y)));
      a[2] = (short)f2bf(cosf(__fadd_rn(__fmul_rn(rel, w0.z), b0.z)));
      a[3] = (short)f2bf(cosf(__fadd_rn(__fmul_rn(rel, w0.w), b0.w)));
      a[4] = (short)f2bf(cosf(__fadd_rn(__fmul_rn(rel, w1.x), b1.x)));
      a[5] = (short)f2bf(cosf(__fadd_rn(__fmul_rn(rel, w1.y), b1.y)));
      a[6] = (short)f2bf(cosf(__fadd_rn(__fmul_rn(rel, w1.z), b1.z)));
      a[7] = (short)f2bf(cosf(__fadd_rn(__fmul_rn(rel, w1.w), b1.w)));
    } else if (k0 >= KATTR){
      #pragma unroll
      for (int j=0;j<8;++j) a[j] = 0;
    } else if (k0 >= TDIM){
      // pure msg region
      float4 m0 = *(const float4*)(mrow + (k0 - TDIM));
      float4 m1 = *(const float4*)(mrow + (k0 - TDIM) + 4);
      a[0] = (short)f2bf(m0.x); a[1] = (short)f2bf(m0.y);
      a[2] = (short)f2bf(m0.z); a[3] = (short)f2bf(m0.w);
      a[4] = (short)f2bf(m1.x); a[5] = (short)f2bf(m1.y);
      a[6] = (short)f2bf(m1.z); a[7] = (short)f2bf(m1.w);
    } else {
      // mixed tile (k0 == 96): j<4 cos, j>=4 msg
      #pragma unroll
      for (int j=0;j<8;++j){
        int k = k0 + j;
        float x = (k < TDIM)
                  ? cosf(__fadd_rn(__fmul_rn(rel, wt[k]), bt[k]))
                  : mrow[k - TDIM];
        a[j] = (short)f2bf(x);
      }
    }
    const short8* wb = (const short8*)Web + (size_t)(kt*7)*64 + lane;
    #pragma unroll
    for (int nt=0; nt<7; ++nt){
      short8 b = wb[(size_t)nt*64];
      acc[nt] = __builtin_amdgcn_mfma_f32_16x16x32_bf16(a, b, acc[nt], 0, 0, 0);
    }
  }

  const int colb = lane & 15;
  const int rbase = w*16 + ((lane >> 4) << 2);
  #pragma unroll
  for (int nt=0; nt<7; ++nt){
    int col = nt*16 + colb;
    if (col >= DDIM) continue;
    #pragma unroll
    for (int r=0; r<4; ++r){
      long pp = p0 + rbase + r;
      if (pp < NE) evals[pp*DDIM + col] = f2bf(acc[nt][r]);
    }
  }
}

// ---------------- per-dst aggregation: head0 -> lanes 0..24, head1 -> lanes 32..56 ----------------
__global__ __launch_bounds__(256) void k_agg(
    const int* __restrict__ rowptr, const unsigned long long* __restrict__ sp64,
    const unsigned short* __restrict__ evals,
    const float* __restrict__ qs, const float* __restrict__ ks, const float* __restrict__ vs,
    const float* __restrict__ ssb, float* __restrict__ oute)
{
  const int w = threadIdx.x >> 6;
  const int lane = threadIdx.x & 63;
  const int node = blockIdx.x*4 + w;
  if (node >= N_SUBN) return;

  const int half = lane >> 5;               // 0: head0, 1: head1
  const int lh = lane & 31;
  const bool act = lh < 25;
  const int c = half*50 + lh*2;             // col pair (c, c+1)

  float q0 = 0.f, q1 = 0.f;
  if (act){
    float2 qq = *(const float2*)(qs + (size_t)node*DDIM + c);
    q0 = qq.x; q1 = qq.y;
  }
  const int b0 = rowptr[node], b1 = rowptr[node+1];
  float num0 = 0.f, num1 = 0.f, den = 0.f;
  const float INV = 0.14142135623730951f;   // 1/sqrt(50)

  int p = b0;
  for (; p+1 < b1; p += 2){
    uint2 seA = ((const uint2*)sp64)[p];
    uint2 seB = ((const uint2*)sp64)[p+1];
    int sA = (int)seA.x, eA = (int)seA.y;
    int sB = (int)seB.x, eB = (int)seB.y;
    float eA0=0,eA1=0,kA0=0,kA1=0,vA0=0,vA1=0;
    float eB0=0,eB1=0,kB0=0,kB1=0,vB0=0,vB1=0;
    if (act){
      unsigned ea = *(const unsigned*)(evals + (size_t)eA*DDIM + c);
      unsigned eb = *(const unsigned*)(evals + (size_t)eB*DDIM + c);
      float2 ka = *(const float2*)(ks + (size_t)sA*DDIM + c);
      float2 kb = *(const float2*)(ks + (size_t)sB*DDIM + c);
      float2 va = *(const float2*)(vs + (size_t)sA*DDIM + c);
      float2 vb = *(const float2*)(vs + (size_t)sB*DDIM + c);
      eA0 = bf2f((unsigned short)(ea & 0xffff)); eA1 = bf2f((unsigned short)(ea >> 16));
      eB0 = bf2f((unsigned short)(eb & 0xffff)); eB1 = bf2f((unsigned short)(eb >> 16));
      kA0 = ka.x; kA1 = ka.y; kB0 = kb.x; kB1 = kb.y;
      vA0 = va.x; vA1 = va.y; vB0 = vb.x; vB1 = vb.y;
    }
    float phA = fmaf(q0, kA0+eA0, q1*(kA1+eA1));
    float phB = fmaf(q0, kB0+eB0, q1*(kB1+eB1));
    #pragma unroll
    for (int m=1; m<32; m<<=1){
      phA += __shfl_xor(phA, m);
      phB += __shfl_xor(phB, m);
    }
    float aA = expf(phA * INV), aB = expf(phB * INV);
    den += aA + aB;
    num0 = fmaf(aA, vA0+eA0, num0); num0 = fmaf(aB, vB0+eB0, num0);
    num1 = fmaf(aA, vA1+eA1, num1); num1 = fmaf(aB, vB1+eB1, num1);
  }
  if (p < b1){
    uint2 seA = ((const uint2*)sp64)[p];
    int sA = (int)seA.x, eA = (int)seA.y;
    float eA0=0,eA1=0,kA0=0,kA1=0,vA0=0,vA1=0;
    if (act){
      unsigned ea = *(const unsigned*)(evals + (size_t)eA*DDIM + c);
      float2 ka = *(const float2*)(ks + (size_t)sA*DDIM + c);
      float2 va = *(const float2*)(vs + (size_t)sA*DDIM + c);
      eA0 = bf2f((unsigned short)(ea & 0xffff)); eA1 = bf2f((unsigned short)(ea >> 16));
      kA0 = ka.x; kA1 = ka.y; vA0 = va.x; vA1 = va.y;
    }
    float phA = fmaf(q0, kA0+eA0, q1*(kA1+eA1));
    #pragma unroll
    for (int m=1; m<32; m<<=1) phA += __shfl_xor(phA, m);
    float aA = expf(phA * INV);
    den += aA;
    num0 = fmaf(aA, vA0+eA0, num0);
    num1 = fmaf(aA, vA1+eA1, num1);
  }

  if (act){
    float inv_d = 1.f / (den + 1e-16f);
    const float* sp = ssb + (size_t)node*DDIM + c;
    float* op = oute + (size_t)node*DDIM + c;
    op[0] = num0*inv_d + sp[0];
    op[1] = num1*inv_d + sp[1];
  }
}

// ---------------- fused predictor: 2 batch rows per block ----------------
__global__ __launch_bounds__(256) void k_pred(
    const float* __restrict__ oute, const int* __restrict__ srci, const int* __restrict__ dsti,
    const float* __restrict__ Wps, const float* __restrict__ bps,
    const float* __restrict__ Wpd, const float* __restrict__ bpd,
    const float* __restrict__ Wpf, const float* __restrict__ bpf,
    float* __restrict__ outp)
{
  __shared__ float hs[2][DDIM];
  const int tid = threadIdx.x;
  const int r = tid / DDIM;          // 0,1 active; 2 idle
  const int c = tid - r*DDIM;
  const int b = blockIdx.x*2 + r;
  const bool on = (r < 2) && (b < NB);

  if (on){
    const float* r1 = oute + (size_t)srci[b]*DDIM;
    const float* r2 = oute + (size_t)dsti[b]*DDIM;
    float a = bps[c] + bpd[c];
    for (int k=0;k<DDIM;k++){
      a = fmaf(r1[k], Wps[k*DDIM+c], a);
      a = fmaf(r2[k], Wpd[k*DDIM+c], a);
    }
    hs[r][c] = fmaxf(a, 0.f);
  }
  __syncthreads();
  if (on){
    float a = bpf[c];
    for (int k=0;k<DDIM;k++) a = fmaf(hs[r][k], Wpf[k*DDIM+c], a);
    outp[(size_t)b*DDIM + c] = a;
  }
}

extern "C" void kernel_launch(void* const* d_in, const int* in_sizes, int n_in,
                              void* d_out, int out_size, void* d_ws, size_t ws_size,
                              hipStream_t stream)
{
  const float* mem   = (const float*)d_in[0];
  const int*   lastu = (const int*)  d_in[1];
  const int*   nid   = (const int*)  d_in[2];
  const int*   ei    = (const int*)  d_in[3];
  const int*   tt    = (const int*)  d_in[4];
  const float* msg   = (const float*)d_in[5];
  const int*   srci  = (const int*)  d_in[6];
  const int*   dsti  = (const int*)  d_in[7];
  const float* wtime = (const float*)d_in[8];
  const float* btime = (const float*)d_in[9];
  const float* Wq = (const float*)d_in[10]; const float* bq = (const float*)d_in[11];
  const float* Wk = (const float*)d_in[12]; const float* bk = (const float*)d_in[13];
  const float* Wv = (const float*)d_in[14]; const float* bv = (const float*)d_in[15];
  const float* We = (const float*)d_in[16];
  const float* Ws = (const float*)d_in[17]; const float* bs = (const float*)d_in[18];
  const float* Wps= (const float*)d_in[19]; const float* bps= (const float*)d_in[20];
  const float* Wpd= (const float*)d_in[21]; const float* bpd= (const float*)d_in[22];
  const float* Wpf= (const float*)d_in[23]; const float* bpf= (const float*)d_in[24];

  char* wsp = (char*)d_ws;
  auto alloc = [&](size_t bytes)->void*{
    void* p = (void*)wsp;
    wsp += (bytes + 255) & ~(size_t)255;
    return p;
  };
  unsigned short* evals = (unsigned short*)alloc((size_t)NE*DDIM*2);   // 100 MB
  float* qs   = (float*)alloc((size_t)N_SUBN*DDIM*4);
  float* ks   = (float*)alloc((size_t)N_SUBN*DDIM*4);
  float* vs   = (float*)alloc((size_t)N_SUBN*DDIM*4);
  float* ssb  = (float*)alloc((size_t)N_SUBN*DDIM*4);
  float* oute = (float*)alloc((size_t)N_SUBN*DDIM*4);
  int* cnt    = (int*)alloc((size_t)N_SUBN*4);
  int* rowptr = (int*)alloc((size_t)(N_SUBN+1)*4);
  int* ofs    = (int*)alloc((size_t)N_SUBN*4);
  int* bsum   = (int*)alloc((size_t)NCHUNK*4);
  int* bbase  = (int*)alloc((size_t)NCHUNK*4);
  unsigned long long* sp64 = (unsigned long long*)alloc((size_t)NE*8);
  int* lusub  = (int*)alloc((size_t)N_SUBN*4);
  unsigned short* Web = (unsigned short*)alloc((size_t)49*64*8*2);

  k_misc<<<(N_SUBN+255)/256, 256, 0, stream>>>(lastu, nid, cnt, lusub, We, Web);
  k_hist<<<(NE+255)/256, 256, 0, stream>>>(ei, cnt);
  k_bsum<<<NCHUNK, 256, 0, stream>>>(cnt, bsum);
  k_bscan<<<1, 64, 0, stream>>>(bsum, bbase);
  k_off<<<NCHUNK, 1024, 0, stream>>>(cnt, bbase, rowptr, ofs);
  k_perm<<<(NE+255)/256, 256, 0, stream>>>(ei, ofs, sp64);

  k_node<<<(N_SUBN+63)/64, 256, 0, stream>>>(mem, nid, Wq,bq, Wk,bk, Wv,bv, Ws,bs,
                                             qs, ks, vs, ssb);

  k_gemm<<<(NE+63)/64, 256, 0, stream>>>(ei, tt, lusub, msg, wtime, btime, Web, evals);

  k_agg<<<(N_SUBN+3)/4, 256, 0, stream>>>(rowptr, sp64, evals, qs, ks, vs, ssb, oute);

  k_pred<<<(NB+1)/2, 256, 0, stream>>>(oute, srci, dsti, Wps,bps, Wpd,bpd, Wpf,bpf,
                                       (float*)d_out);
}

// Round 5
// 478.630 us; speedup vs baseline: 6.1358x; 1.0073x over previous
//
#include <hip/hip_runtime.h>
#include <math.h>

#define N_SUBN  50000
#define NE      500000
#define NB      5000
#define DDIM    100
#define TDIM    100
#define KATTR   200
#define NCHUNK  49        // ceil(N_SUBN/1024)

typedef __attribute__((ext_vector_type(8))) short short8;
typedef __attribute__((ext_vector_type(4))) float f32x4;

__device__ inline unsigned short f2bf(float f){
  union{float f; unsigned int u;} v; v.f = f;
  unsigned int r = (v.u + 0x7fffu + ((v.u >> 16) & 1u)) >> 16;   // RNE
  return (unsigned short)r;
}
__device__ inline float bf2f(unsigned short u){
  union{unsigned int u; float f;} v; v.u = ((unsigned int)u) << 16;
  return v.f;
}

// fast cos for |x| up to ~1e6: Cody-Waite 2-term reduction (fma-exact) + v_cos.
// reduction error ~5e-7 rad, far below downstream bf16 quantization (2e-3).
__device__ inline float fast_cos(float x){
  constexpr double TWO_PI_D = 6.2831853071795864769252867665590;
  constexpr float I2PI = (float)(1.0/TWO_PI_D);
  constexpr float C1 = (float)TWO_PI_D;
  constexpr float C2 = (float)(TWO_PI_D - (double)((float)TWO_PI_D));
  float k = rintf(x * I2PI);
  float r = fmaf(k, -C1, x);
  r = fmaf(k, -C2, r);
  return __cosf(r);            // native v_cos on small residual
}

// ---------------- fused: zero cnt + lusub gather + We B-fragment pack ----------------
__global__ __launch_bounds__(256) void k_misc(
    const int* __restrict__ lastu, const int* __restrict__ nid,
    int* __restrict__ cnt, int* __restrict__ lusub,
    const float* __restrict__ We, unsigned short* __restrict__ Web)
{
  int i = blockIdx.x*256 + threadIdx.x;
  if (i < N_SUBN){
    cnt[i] = 0;
    lusub[i] = lastu[nid[i]];
  }
  if (i < 49*64){
    int l = i & 63; int t = i >> 6; int kt = t / 7; int nt = t - kt*7;
    int col = nt*16 + (l & 15);
    int kbase = kt*32 + ((l >> 4) << 3);
    short8 pack;
    #pragma unroll
    for (int j = 0; j < 8; ++j){
      int k = kbase + j;
      float v = (k < KATTR && col < DDIM) ? We[k*DDIM + col] : 0.f;
      pack[j] = (short)f2bf(v);
    }
    *((short8*)Web + i) = pack;
  }
}

// ---------------- CSR: histogram over dst ----------------
__global__ void k_hist(const int* __restrict__ ei, int* __restrict__ cnt){
  int i = blockIdx.x*blockDim.x + threadIdx.x;
  if (i < NE) atomicAdd(&cnt[ei[NE + i]], 1);
}

// ---------------- CSR scan phase 1: per-1024-chunk sums ----------------
__global__ __launch_bounds__(256) void k_bsum(const int* __restrict__ cnt, int* __restrict__ bsum){
  __shared__ int wsum[4];
  int b = blockIdx.x, tid = threadIdx.x;
  int base = b*1024 + tid*4;
  int s = 0;
  #pragma unroll
  for (int i=0;i<4;i++){ int idx = base+i; if (idx < N_SUBN) s += cnt[idx]; }
  #pragma unroll
  for (int m=1;m<64;m<<=1) s += __shfl_xor(s, m);
  if ((tid&63)==0) wsum[tid>>6] = s;
  __syncthreads();
  if (tid==0) bsum[b] = wsum[0]+wsum[1]+wsum[2]+wsum[3];
}

// ---------------- CSR scan phase 2: exclusive scan of chunk sums (1 wave) ----------------
__global__ void k_bscan(const int* __restrict__ bsum, int* __restrict__ bbase){
  int l = threadIdx.x;
  int v = (l < NCHUNK) ? bsum[l] : 0;
  int orig = v;
  for (int off=1; off<64; off<<=1){
    int t = __shfl_up(v, off);
    if (l >= off) v += t;
  }
  if (l < NCHUNK) bbase[l] = v - orig;   // exclusive
}

// ---------------- CSR scan phase 3: per-chunk inclusive scan + base ----------------
__global__ __launch_bounds__(1024) void k_off(const int* __restrict__ cnt, const int* __restrict__ bbase,
                                              int* __restrict__ rowptr, int* __restrict__ ofs){
  __shared__ int sd[1024];
  int b = blockIdx.x, tid = threadIdx.x;
  int i = b*1024 + tid;
  int v = (i < N_SUBN) ? cnt[i] : 0;
  sd[tid] = v; __syncthreads();
  for (int off=1; off<1024; off<<=1){
    int t = (tid >= off) ? sd[tid-off] : 0;
    __syncthreads();
    sd[tid] += t;
    __syncthreads();
  }
  int incl = sd[tid] + bbase[b];
  if (i < N_SUBN){ rowptr[i+1] = incl; ofs[i] = incl - v; }
  if (i == 0) rowptr[0] = 0;
}

// ---------------- CSR: bucket edges by dst, packed (perm<<32 | src) ----------------
__global__ void k_perm(const int* __restrict__ ei, int* __restrict__ ofs,
                       unsigned long long* __restrict__ sp64){
  int i = blockIdx.x*blockDim.x + threadIdx.x;
  if (i < NE){
    int d = ei[NE + i];
    int pos = atomicAdd(&ofs[d], 1);
    sp64[pos] = ((unsigned long long)(unsigned)i << 32) | (unsigned)ei[i];
  }
}

// ---------------- node GEMMs fused: q,k,v,skip = z @ W + b (z staged once) ----------------
__global__ __launch_bounds__(256) void k_node(
    const float* __restrict__ mem, const int* __restrict__ nid,
    const float* __restrict__ Wq, const float* __restrict__ bq,
    const float* __restrict__ Wk, const float* __restrict__ bk,
    const float* __restrict__ Wv, const float* __restrict__ bv,
    const float* __restrict__ Ws, const float* __restrict__ bs,
    float* __restrict__ qs, float* __restrict__ ks,
    float* __restrict__ vs, float* __restrict__ ss)
{
  __shared__ float zt[64][101];
  const int tid = threadIdx.x;
  const int node0 = blockIdx.x*64;

  for (int idx = tid; idx < 64*DDIM; idx += 256){
    int r = idx/DDIM, j = idx - r*DDIM;
    int node = node0 + r;
    zt[r][j] = (node < N_SUBN) ? mem[(size_t)nid[node]*DDIM + j] : 0.f;
  }
  __syncthreads();

  const int e  = tid & 63;
  const int cg = __builtin_amdgcn_readfirstlane(tid >> 6);
  const int c0 = cg*25;
  const int node = node0 + e;

  #pragma unroll
  for (int which = 0; which < 4; ++which){
    const float* W    = (which==0)?Wq:(which==1)?Wk:(which==2)?Wv:Ws;
    const float* bias = (which==0)?bq:(which==1)?bk:(which==2)?bv:bs;
    float* outp       = (which==0)?qs:(which==1)?ks:(which==2)?vs:ss;
    float acc[25];
    #pragma unroll
    for (int i=0;i<25;i++) acc[i] = 0.f;
    for (int k=0;k<DDIM;k++){
      float a = zt[e][k];
      const float* wr = W + k*DDIM + c0;   // wave-uniform -> scalar loads
      #pragma unroll
      for (int i=0;i<25;i++) acc[i] = fmaf(a, wr[i], acc[i]);
    }
    if (node < N_SUBN){
      float* op = outp + (size_t)node*DDIM + c0;
      #pragma unroll
      for (int i=0;i<25;i++) op[i] = acc[i] + bias[c0+i];
    }
  }
}

// ---------------- MFMA edge GEMM, barrier-free: A-fragments built in registers ----------------
// A layout for mfma_f32_16x16x32_bf16: lane holds row = 16w + (lane&15),
// k = kt*32 + (lane>>4)*8 + j.  Each (row,k) produced by exactly one lane.
__global__ __launch_bounds__(256) void k_gemm(
    const int* __restrict__ ei, const int* __restrict__ tt,
    const int* __restrict__ lusub, const float* __restrict__ msg,
    const float* __restrict__ wt, const float* __restrict__ bt,
    const unsigned short* __restrict__ Web, unsigned short* __restrict__ evals)
{
  const int tid = threadIdx.x;
  const int lane = tid & 63;
  const int w = tid >> 6;
  const long p0 = (long)blockIdx.x * 64;
  const int arow = w*16 + (lane & 15);
  const int koff = (lane >> 4) << 3;           // 0,8,16,24

  long p = p0 + arow;
  long pc = (p < NE) ? p : (NE - 1);
  const float rel = (float)(lusub[ei[pc]] - tt[pc]);
  const float* mrow = msg + pc*DDIM;

  f32x4 acc[7];
  #pragma unroll
  for (int nt=0; nt<7; ++nt) acc[nt] = (f32x4){0.f,0.f,0.f,0.f};

  #pragma unroll
  for (int kt=0; kt<7; ++kt){
    const int k0 = kt*32 + koff;
    short8 a;
    if (k0 + 7 < TDIM){
      // pure cos region
      float4 w0 = *(const float4*)(wt + k0);
      float4 w1 = *(const float4*)(wt + k0 + 4);
      float4 b0 = *(const float4*)(bt + k0);
      float4 b1 = *(const float4*)(bt + k0 + 4);
      a[0] = (short)f2bf(fast_cos(__fadd_rn(__fmul_rn(rel, w0.x), b0.x)));
      a[1] = (short)f2bf(fast_cos(__fadd_rn(__fmul_rn(rel, w0.y), b0.y)));
      a[2] = (short)f2bf(fast_cos(__fadd_rn(__fmul_rn(rel, w0.z), b0.z)));
      a[3] = (short)f2bf(fast_cos(__fadd_rn(__fmul_rn(rel, w0.w), b0.w)));
      a[4] = (short)f2bf(fast_cos(__fadd_rn(__fmul_rn(rel, w1.x), b1.x)));
      a[5] = (short)f2bf(fast_cos(__fadd_rn(__fmul_rn(rel, w1.y), b1.y)));
      a[6] = (short)f2bf(fast_cos(__fadd_rn(__fmul_rn(rel, w1.z), b1.z)));
      a[7] = (short)f2bf(fast_cos(__fadd_rn(__fmul_rn(rel, w1.w), b1.w)));
    } else if (k0 >= KATTR){
      #pragma unroll
      for (int j=0;j<8;++j) a[j] = 0;
    } else if (k0 >= TDIM){
      // pure msg region
      float4 m0 = *(const float4*)(mrow + (k0 - TDIM));
      float4 m1 = *(const float4*)(mrow + (k0 - TDIM) + 4);
      a[0] = (short)f2bf(m0.x); a[1] = (short)f2bf(m0.y);
      a[2] = (short)f2bf(m0.z); a[3] = (short)f2bf(m0.w);
      a[4] = (short)f2bf(m1.x); a[5] = (short)f2bf(m1.y);
      a[6] = (short)f2bf(m1.z); a[7] = (short)f2bf(m1.w);
    } else {
      // mixed tile (k0 == 96): j<4 cos, j>=4 msg
      #pragma unroll
      for (int j=0;j<8;++j){
        int k = k0 + j;
        float x = (k < TDIM)
                  ? fast_cos(__fadd_rn(__fmul_rn(rel, wt[k]), bt[k]))
                  : mrow[k - TDIM];
        a[j] = (short)f2bf(x);
      }
    }
    const short8* wb = (const short8*)Web + (size_t)(kt*7)*64 + lane;
    #pragma unroll
    for (int nt=0; nt<7; ++nt){
      short8 b = wb[(size_t)nt*64];
      acc[nt] = __builtin_amdgcn_mfma_f32_16x16x32_bf16(a, b, acc[nt], 0, 0, 0);
    }
  }

  const int colb = lane & 15;
  const int rbase = w*16 + ((lane >> 4) << 2);
  #pragma unroll
  for (int nt=0; nt<7; ++nt){
    int col = nt*16 + colb;
    if (col >= DDIM) continue;
    #pragma unroll
    for (int r=0; r<4; ++r){
      long pp = p0 + rbase + r;
      if (pp < NE) evals[pp*DDIM + col] = f2bf(acc[nt][r]);
    }
  }
}

// ---------------- per-dst aggregation: head0 -> lanes 0..24, head1 -> lanes 32..56 ----------------
__global__ __launch_bounds__(256) void k_agg(
    const int* __restrict__ rowptr, const unsigned long long* __restrict__ sp64,
    const unsigned short* __restrict__ evals,
    const float* __restrict__ qs, const float* __restrict__ ks, const float* __restrict__ vs,
    const float* __restrict__ ssb, float* __restrict__ oute)
{
  const int w = threadIdx.x >> 6;
  const int lane = threadIdx.x & 63;
  const int node = blockIdx.x*4 + w;
  if (node >= N_SUBN) return;

  const int half = lane >> 5;               // 0: head0, 1: head1
  const int lh = lane & 31;
  const bool act = lh < 25;
  const int c = half*50 + lh*2;             // col pair (c, c+1)

  float q0 = 0.f, q1 = 0.f;
  if (act){
    float2 qq = *(const float2*)(qs + (size_t)node*DDIM + c);
    q0 = qq.x; q1 = qq.y;
  }
  const int b0 = rowptr[node], b1 = rowptr[node+1];
  float num0 = 0.f, num1 = 0.f, den = 0.f;
  const float INV = 0.14142135623730951f;   // 1/sqrt(50)

  int p = b0;
  for (; p+1 < b1; p += 2){
    uint2 seA = ((const uint2*)sp64)[p];
    uint2 seB = ((const uint2*)sp64)[p+1];
    int sA = (int)seA.x, eA = (int)seA.y;
    int sB = (int)seB.x, eB = (int)seB.y;
    float eA0=0,eA1=0,kA0=0,kA1=0,vA0=0,vA1=0;
    float eB0=0,eB1=0,kB0=0,kB1=0,vB0=0,vB1=0;
    if (act){
      unsigned ea = *(const unsigned*)(evals + (size_t)eA*DDIM + c);
      unsigned eb = *(const unsigned*)(evals + (size_t)eB*DDIM + c);
      float2 ka = *(const float2*)(ks + (size_t)sA*DDIM + c);
      float2 kb = *(const float2*)(ks + (size_t)sB*DDIM + c);
      float2 va = *(const float2*)(vs + (size_t)sA*DDIM + c);
      float2 vb = *(const float2*)(vs + (size_t)sB*DDIM + c);
      eA0 = bf2f((unsigned short)(ea & 0xffff)); eA1 = bf2f((unsigned short)(ea >> 16));
      eB0 = bf2f((unsigned short)(eb & 0xffff)); eB1 = bf2f((unsigned short)(eb >> 16));
      kA0 = ka.x; kA1 = ka.y; kB0 = kb.x; kB1 = kb.y;
      vA0 = va.x; vA1 = va.y; vB0 = vb.x; vB1 = vb.y;
    }
    float phA = fmaf(q0, kA0+eA0, q1*(kA1+eA1));
    float phB = fmaf(q0, kB0+eB0, q1*(kB1+eB1));
    #pragma unroll
    for (int m=1; m<32; m<<=1){
      phA += __shfl_xor(phA, m);
      phB += __shfl_xor(phB, m);
    }
    float aA = __expf(phA * INV), aB = __expf(phB * INV);
    den += aA + aB;
    num0 = fmaf(aA, vA0+eA0, num0); num0 = fmaf(aB, vB0+eB0, num0);
    num1 = fmaf(aA, vA1+eA1, num1); num1 = fmaf(aB, vB1+eB1, num1);
  }
  if (p < b1){
    uint2 seA = ((const uint2*)sp64)[p];
    int sA = (int)seA.x, eA = (int)seA.y;
    float eA0=0,eA1=0,kA0=0,kA1=0,vA0=0,vA1=0;
    if (act){
      unsigned ea = *(const unsigned*)(evals + (size_t)eA*DDIM + c);
      float2 ka = *(const float2*)(ks + (size_t)sA*DDIM + c);
      float2 va = *(const float2*)(vs + (size_t)sA*DDIM + c);
      eA0 = bf2f((unsigned short)(ea & 0xffff)); eA1 = bf2f((unsigned short)(ea >> 16));
      kA0 = ka.x; kA1 = ka.y; vA0 = va.x; vA1 = va.y;
    }
    float phA = fmaf(q0, kA0+eA0, q1*(kA1+eA1));
    #pragma unroll
    for (int m=1; m<32; m<<=1) phA += __shfl_xor(phA, m);
    float aA = __expf(phA * INV);
    den += aA;
    num0 = fmaf(aA, vA0+eA0, num0);
    num1 = fmaf(aA, vA1+eA1, num1);
  }

  if (act){
    float inv_d = 1.f / (den + 1e-16f);
    const float* sp = ssb + (size_t)node*DDIM + c;
    float* op = oute + (size_t)node*DDIM + c;
    op[0] = num0*inv_d + sp[0];
    op[1] = num1*inv_d + sp[1];
  }
}

// ---------------- fused predictor: 2 batch rows per block ----------------
__global__ __launch_bounds__(256) void k_pred(
    const float* __restrict__ oute, const int* __restrict__ srci, const int* __restrict__ dsti,
    const float* __restrict__ Wps, const float* __restrict__ bps,
    const float* __restrict__ Wpd, const float* __restrict__ bpd,
    const float* __restrict__ Wpf, const float* __restrict__ bpf,
    float* __restrict__ outp)
{
  __shared__ float hs[2][DDIM];
  const int tid = threadIdx.x;
  const int r = tid / DDIM;          // 0,1 active; 2 idle
  const int c = tid - r*DDIM;
  const int b = blockIdx.x*2 + r;
  const bool on = (r < 2) && (b < NB);

  if (on){
    const float* r1 = oute + (size_t)srci[b]*DDIM;
    const float* r2 = oute + (size_t)dsti[b]*DDIM;
    float a = bps[c] + bpd[c];
    for (int k=0;k<DDIM;k++){
      a = fmaf(r1[k], Wps[k*DDIM+c], a);
      a = fmaf(r2[k], Wpd[k*DDIM+c], a);
    }
    hs[r][c] = fmaxf(a, 0.f);
  }
  __syncthreads();
  if (on){
    float a = bpf[c];
    for (int k=0;k<DDIM;k++) a = fmaf(hs[r][k], Wpf[k*DDIM+c], a);
    outp[(size_t)b*DDIM + c] = a;
  }
}

extern "C" void kernel_launch(void* const* d_in, const int* in_sizes, int n_in,
                              void* d_out, int out_size, void* d_ws, size_t ws_size,
                              hipStream_t stream)
{
  const float* mem   = (const float*)d_in[0];
  const int*   lastu = (const int*)  d_in[1];
  const int*   nid   = (const int*)  d_in[2];
  const int*   ei    = (const int*)  d_in[3];
  const int*   tt    = (const int*)  d_in[4];
  const float* msg   = (const float*)d_in[5];
  const int*   srci  = (const int*)  d_in[6];
  const int*   dsti  = (const int*)  d_in[7];
  const float* wtime = (const float*)d_in[8];
  const float* btime = (const float*)d_in[9];
  const float* Wq = (const float*)d_in[10]; const float* bq = (const float*)d_in[11];
  const float* Wk = (const float*)d_in[12]; const float* bk = (const float*)d_in[13];
  const float* Wv = (const float*)d_in[14]; const float* bv = (const float*)d_in[15];
  const float* We = (const float*)d_in[16];
  const float* Ws = (const float*)d_in[17]; const float* bs = (const float*)d_in[18];
  const float* Wps= (const float*)d_in[19]; const float* bps= (const float*)d_in[20];
  const float* Wpd= (const float*)d_in[21]; const float* bpd= (const float*)d_in[22];
  const float* Wpf= (const float*)d_in[23]; const float* bpf= (const float*)d_in[24];

  char* wsp = (char*)d_ws;
  auto alloc = [&](size_t bytes)->void*{
    void* p = (void*)wsp;
    wsp += (bytes + 255) & ~(size_t)255;
    return p;
  };
  unsigned short* evals = (unsigned short*)alloc((size_t)NE*DDIM*2);   // 100 MB
  float* qs   = (float*)alloc((size_t)N_SUBN*DDIM*4);
  float* ks   = (float*)alloc((size_t)N_SUBN*DDIM*4);
  float* vs   = (float*)alloc((size_t)N_SUBN*DDIM*4);
  float* ssb  = (float*)alloc((size_t)N_SUBN*DDIM*4);
  float* oute = (float*)alloc((size_t)N_SUBN*DDIM*4);
  int* cnt    = (int*)alloc((size_t)N_SUBN*4);
  int* rowptr = (int*)alloc((size_t)(N_SUBN+1)*4);
  int* ofs    = (int*)alloc((size_t)N_SUBN*4);
  int* bsum   = (int*)alloc((size_t)NCHUNK*4);
  int* bbase  = (int*)alloc((size_t)NCHUNK*4);
  unsigned long long* sp64 = (unsigned long long*)alloc((size_t)NE*8);
  int* lusub  = (int*)alloc((size_t)N_SUBN*4);
  unsigned short* Web = (unsigned short*)alloc((size_t)49*64*8*2);

  k_misc<<<(N_SUBN+255)/256, 256, 0, stream>>>(lastu, nid, cnt, lusub, We, Web);
  k_hist<<<(NE+255)/256, 256, 0, stream>>>(ei, cnt);
  k_bsum<<<NCHUNK, 256, 0, stream>>>(cnt, bsum);
  k_bscan<<<1, 64, 0, stream>>>(bsum, bbase);
  k_off<<<NCHUNK, 1024, 0, stream>>>(cnt, bbase, rowptr, ofs);
  k_perm<<<(NE+255)/256, 256, 0, stream>>>(ei, ofs, sp64);

  k_node<<<(N_SUBN+63)/64, 256, 0, stream>>>(mem, nid, Wq,bq, Wk,bk, Wv,bv, Ws,bs,
                                             qs, ks, vs, ssb);

  k_gemm<<<(NE+63)/64, 256, 0, stream>>>(ei, tt, lusub, msg, wtime, btime, Web, evals);

  k_agg<<<(N_SUBN+3)/4, 256, 0, stream>>>(rowptr, sp64, evals, qs, ks, vs, ssb, oute);

  k_pred<<<(NB+1)/2, 256, 0, stream>>>(oute, srci, dsti, Wps,bps, Wpd,bpd, Wpf,bpf,
                                       (float*)d_out);
}

// Round 6
// 392.599 us; speedup vs baseline: 7.4803x; 1.2191x over previous
//
#include <hip/hip_runtime.h>
#include <math.h>

#define N_SUBN  50000
#define NE      500000
#define NB      5000
#define DDIM    100
#define TDIM    100
#define KATTR   200
#define NCHUNK  49        // ceil(N_SUBN/1024)

typedef __attribute__((ext_vector_type(8))) short short8;
typedef __attribute__((ext_vector_type(4))) float f32x4;

__device__ inline unsigned short f2bf(float f){
  union{float f; unsigned int u;} v; v.f = f;
  unsigned int r = (v.u + 0x7fffu + ((v.u >> 16) & 1u)) >> 16;   // RNE
  return (unsigned short)r;
}
__device__ inline float bf2f(unsigned short u){
  union{unsigned int u; float f;} v; v.u = ((unsigned int)u) << 16;
  return v.f;
}

// fast cos for |x| up to ~1e6: Cody-Waite 2-term reduction (fma-exact) + v_cos.
__device__ inline float fast_cos(float x){
  constexpr double TWO_PI_D = 6.2831853071795864769252867665590;
  constexpr float I2PI = (float)(1.0/TWO_PI_D);
  constexpr float C1 = (float)TWO_PI_D;
  constexpr float C2 = (float)(TWO_PI_D - (double)((float)TWO_PI_D));
  float k = rintf(x * I2PI);
  float r = fmaf(k, -C1, x);
  r = fmaf(k, -C2, r);
  return __cosf(r);
}

// A-fragment build for edge GEMM: 8 bf16 at k0..k0+7 of [cos_enc | msg | 0pad]
__device__ inline short8 build_attr(float rel, const float* __restrict__ mrow,
                                    const float* __restrict__ wt,
                                    const float* __restrict__ bt, int k0){
  short8 a;
  if (k0 + 7 < TDIM){
    float4 w0 = *(const float4*)(wt + k0);
    float4 w1 = *(const float4*)(wt + k0 + 4);
    float4 b0 = *(const float4*)(bt + k0);
    float4 b1 = *(const float4*)(bt + k0 + 4);
    // __fmul_rn/__fadd_rn: must match XLA's non-contracted mul-then-add rounding
    a[0] = (short)f2bf(fast_cos(__fadd_rn(__fmul_rn(rel, w0.x), b0.x)));
    a[1] = (short)f2bf(fast_cos(__fadd_rn(__fmul_rn(rel, w0.y), b0.y)));
    a[2] = (short)f2bf(fast_cos(__fadd_rn(__fmul_rn(rel, w0.z), b0.z)));
    a[3] = (short)f2bf(fast_cos(__fadd_rn(__fmul_rn(rel, w0.w), b0.w)));
    a[4] = (short)f2bf(fast_cos(__fadd_rn(__fmul_rn(rel, w1.x), b1.x)));
    a[5] = (short)f2bf(fast_cos(__fadd_rn(__fmul_rn(rel, w1.y), b1.y)));
    a[6] = (short)f2bf(fast_cos(__fadd_rn(__fmul_rn(rel, w1.z), b1.z)));
    a[7] = (short)f2bf(fast_cos(__fadd_rn(__fmul_rn(rel, w1.w), b1.w)));
  } else if (k0 >= KATTR){
    #pragma unroll
    for (int j=0;j<8;++j) a[j] = 0;
  } else if (k0 >= TDIM){
    float4 m0 = *(const float4*)(mrow + (k0 - TDIM));
    float4 m1 = *(const float4*)(mrow + (k0 - TDIM) + 4);
    a[0] = (short)f2bf(m0.x); a[1] = (short)f2bf(m0.y);
    a[2] = (short)f2bf(m0.z); a[3] = (short)f2bf(m0.w);
    a[4] = (short)f2bf(m1.x); a[5] = (short)f2bf(m1.y);
    a[6] = (short)f2bf(m1.z); a[7] = (short)f2bf(m1.w);
  } else {
    #pragma unroll
    for (int j=0;j<8;++j){
      int k = k0 + j;
      float x = (k < TDIM)
                ? fast_cos(__fadd_rn(__fmul_rn(rel, wt[k]), bt[k]))
                : mrow[k - TDIM];
      a[j] = (short)f2bf(x);
    }
  }
  return a;
}

// ---------------- fused: zero cnt + lusub gather + pack Web (edge) + Wnb (node) ----------------
__global__ __launch_bounds__(256) void k_misc(
    const int* __restrict__ lastu, const int* __restrict__ nid,
    int* __restrict__ cnt, int* __restrict__ lusub,
    const float* __restrict__ We, unsigned short* __restrict__ Web,
    const float* __restrict__ Wq, const float* __restrict__ Wk,
    const float* __restrict__ Wv, const float* __restrict__ Ws,
    unsigned short* __restrict__ Wnb)
{
  int i = blockIdx.x*256 + threadIdx.x;
  if (i < N_SUBN){
    cnt[i] = 0;
    lusub[i] = lastu[nid[i]];
  }
  if (i < 49*64){
    int l = i & 63; int t = i >> 6; int kt = t / 7; int nt = t - kt*7;
    int col = nt*16 + (l & 15);
    int kbase = kt*32 + ((l >> 4) << 3);
    short8 pack;
    #pragma unroll
    for (int j = 0; j < 8; ++j){
      int k = kbase + j;
      float v = (k < KATTR && col < DDIM) ? We[k*DDIM + col] : 0.f;
      pack[j] = (short)f2bf(v);
    }
    *((short8*)Web + i) = pack;
  }
  if (i < 4*28*64){
    int l = i & 63; int t = i >> 6;              // 0..111
    int which = t / 28; int t2 = t - which*28;
    int kt = t2 / 7; int nt = t2 - kt*7;
    const float* W = (which==0)?Wq:(which==1)?Wk:(which==2)?Wv:Ws;
    int col = nt*16 + (l & 15);
    int kbase = kt*32 + ((l >> 4) << 3);
    short8 pack;
    #pragma unroll
    for (int j = 0; j < 8; ++j){
      int k = kbase + j;
      float v = (k < DDIM && col < DDIM) ? W[k*DDIM + col] : 0.f;
      pack[j] = (short)f2bf(v);
    }
    *((short8*)Wnb + i) = pack;
  }
}

// ---------------- CSR: histogram over dst ----------------
__global__ void k_hist(const int* __restrict__ ei, int* __restrict__ cnt){
  int i = blockIdx.x*blockDim.x + threadIdx.x;
  if (i < NE) atomicAdd(&cnt[ei[NE + i]], 1);
}

// ---------------- CSR scan phase 1 ----------------
__global__ __launch_bounds__(256) void k_bsum(const int* __restrict__ cnt, int* __restrict__ bsum){
  __shared__ int wsum[4];
  int b = blockIdx.x, tid = threadIdx.x;
  int base = b*1024 + tid*4;
  int s = 0;
  #pragma unroll
  for (int i=0;i<4;i++){ int idx = base+i; if (idx < N_SUBN) s += cnt[idx]; }
  #pragma unroll
  for (int m=1;m<64;m<<=1) s += __shfl_xor(s, m);
  if ((tid&63)==0) wsum[tid>>6] = s;
  __syncthreads();
  if (tid==0) bsum[b] = wsum[0]+wsum[1]+wsum[2]+wsum[3];
}

// ---------------- CSR scan phase 2 ----------------
__global__ void k_bscan(const int* __restrict__ bsum, int* __restrict__ bbase){
  int l = threadIdx.x;
  int v = (l < NCHUNK) ? bsum[l] : 0;
  int orig = v;
  for (int off=1; off<64; off<<=1){
    int t = __shfl_up(v, off);
    if (l >= off) v += t;
  }
  if (l < NCHUNK) bbase[l] = v - orig;
}

// ---------------- CSR scan phase 3 ----------------
__global__ __launch_bounds__(1024) void k_off(const int* __restrict__ cnt, const int* __restrict__ bbase,
                                              int* __restrict__ rowptr, int* __restrict__ ofs){
  __shared__ int sd[1024];
  int b = blockIdx.x, tid = threadIdx.x;
  int i = b*1024 + tid;
  int v = (i < N_SUBN) ? cnt[i] : 0;
  sd[tid] = v; __syncthreads();
  for (int off=1; off<1024; off<<=1){
    int t = (tid >= off) ? sd[tid-off] : 0;
    __syncthreads();
    sd[tid] += t;
    __syncthreads();
  }
  int incl = sd[tid] + bbase[b];
  if (i < N_SUBN){ rowptr[i+1] = incl; ofs[i] = incl - v; }
  if (i == 0) rowptr[0] = 0;
}

// ---------------- CSR: bucket edges by dst, packed (perm<<32 | src) ----------------
__global__ void k_perm(const int* __restrict__ ei, int* __restrict__ ofs,
                       unsigned long long* __restrict__ sp64){
  int i = blockIdx.x*blockDim.x + threadIdx.x;
  if (i < NE){
    int d = ei[NE + i];
    int pos = atomicAdd(&ofs[d], 1);
    sp64[pos] = ((unsigned long long)(unsigned)i << 32) | (unsigned)ei[i];
  }
}

// ---------------- node GEMMs via MFMA: pair 0 -> q,k ; pair 1 -> v,skip ----------------
__global__ __launch_bounds__(256, 4) void k_node(
    const float* __restrict__ mem, const int* __restrict__ nid,
    const unsigned short* __restrict__ Wnb,
    const float* __restrict__ bq, const float* __restrict__ bk,
    const float* __restrict__ bv, const float* __restrict__ bs,
    float* __restrict__ qs, float* __restrict__ ks,
    float* __restrict__ vs, float* __restrict__ ss)
{
  const int tid = threadIdx.x;
  const int lane = tid & 63;
  const int w = tid >> 6;
  const int pair = blockIdx.y;
  const int node0 = blockIdx.x*64;
  const int arow = w*16 + (lane & 15);
  const int koff = (lane >> 4) << 3;

  int node = node0 + arow;
  int nc = (node < N_SUBN) ? node : (N_SUBN-1);
  const float* zrow = mem + (size_t)nid[nc]*DDIM;

  f32x4 acc0[7], acc1[7];
  #pragma unroll
  for (int nt=0; nt<7; ++nt){ acc0[nt] = (f32x4){0,0,0,0}; acc1[nt] = (f32x4){0,0,0,0}; }

  const int wm0 = pair*2, wm1 = pair*2+1;
  #pragma unroll
  for (int kt=0; kt<4; ++kt){
    const int k0 = kt*32 + koff;
    short8 a;
    if (k0 + 7 < DDIM){
      float4 m0 = *(const float4*)(zrow + k0);
      float4 m1 = *(const float4*)(zrow + k0 + 4);
      a[0] = (short)f2bf(m0.x); a[1] = (short)f2bf(m0.y);
      a[2] = (short)f2bf(m0.z); a[3] = (short)f2bf(m0.w);
      a[4] = (short)f2bf(m1.x); a[5] = (short)f2bf(m1.y);
      a[6] = (short)f2bf(m1.z); a[7] = (short)f2bf(m1.w);
    } else if (k0 >= DDIM){
      #pragma unroll
      for (int j=0;j<8;++j) a[j] = 0;
    } else {  // k0 == 96
      float4 m0 = *(const float4*)(zrow + 96);
      a[0] = (short)f2bf(m0.x); a[1] = (short)f2bf(m0.y);
      a[2] = (short)f2bf(m0.z); a[3] = (short)f2bf(m0.w);
      a[4] = 0; a[5] = 0; a[6] = 0; a[7] = 0;
    }
    const short8* wb0 = (const short8*)Wnb + (size_t)((wm0*4 + kt)*7)*64 + lane;
    const short8* wb1 = (const short8*)Wnb + (size_t)((wm1*4 + kt)*7)*64 + lane;
    #pragma unroll
    for (int nt=0; nt<7; ++nt){
      short8 b0 = wb0[(size_t)nt*64];
      short8 b1 = wb1[(size_t)nt*64];
      acc0[nt] = __builtin_amdgcn_mfma_f32_16x16x32_bf16(a, b0, acc0[nt], 0, 0, 0);
      acc1[nt] = __builtin_amdgcn_mfma_f32_16x16x32_bf16(a, b1, acc1[nt], 0, 0, 0);
    }
  }

  const float* bias0 = pair ? bv : bq;
  const float* bias1 = pair ? bs : bk;
  float* out0 = pair ? vs : qs;
  float* out1 = pair ? ss : ks;
  const int colb = lane & 15;
  const int rbase = w*16 + ((lane >> 4) << 2);
  #pragma unroll
  for (int nt=0; nt<7; ++nt){
    int col = nt*16 + colb;
    if (col >= DDIM) continue;
    float bb0 = bias0[col], bb1 = bias1[col];
    #pragma unroll
    for (int r=0; r<4; ++r){
      int nn = node0 + rbase + r;
      if (nn < N_SUBN){
        out0[(size_t)nn*DDIM + col] = acc0[nt][r] + bb0;
        out1[(size_t)nn*DDIM + col] = acc1[nt][r] + bb1;
      }
    }
  }
}

// ---------------- MFMA edge GEMM: 128 edges/block (2 tiles), reg-built A ----------------
__global__ __launch_bounds__(256, 4) void k_gemm(
    const int* __restrict__ ei, const int* __restrict__ tt,
    const int* __restrict__ lusub, const float* __restrict__ msg,
    const float* __restrict__ wt, const float* __restrict__ bt,
    const unsigned short* __restrict__ Web, unsigned short* __restrict__ evals)
{
  const int tid = threadIdx.x;
  const int lane = tid & 63;
  const int w = tid >> 6;
  const long p0 = (long)blockIdx.x * 128;
  const int arow = w*16 + (lane & 15);
  const int koff = (lane >> 4) << 3;

  long pA = p0 + arow;
  long pB = p0 + 64 + arow;
  long pcA = (pA < NE) ? pA : (NE - 1);
  long pcB = (pB < NE) ? pB : (NE - 1);
  const float relA = (float)(lusub[ei[pcA]] - tt[pcA]);
  const float relB = (float)(lusub[ei[pcB]] - tt[pcB]);
  const float* mrowA = msg + pcA*DDIM;
  const float* mrowB = msg + pcB*DDIM;

  f32x4 accA[7], accB[7];
  #pragma unroll
  for (int nt=0; nt<7; ++nt){ accA[nt] = (f32x4){0,0,0,0}; accB[nt] = (f32x4){0,0,0,0}; }

  #pragma unroll
  for (int kt=0; kt<7; ++kt){
    const int k0 = kt*32 + koff;
    short8 aA = build_attr(relA, mrowA, wt, bt, k0);
    short8 aB = build_attr(relB, mrowB, wt, bt, k0);
    const short8* wb = (const short8*)Web + (size_t)(kt*7)*64 + lane;
    #pragma unroll
    for (int nt=0; nt<7; ++nt){
      short8 b = wb[(size_t)nt*64];
      accA[nt] = __builtin_amdgcn_mfma_f32_16x16x32_bf16(aA, b, accA[nt], 0, 0, 0);
      accB[nt] = __builtin_amdgcn_mfma_f32_16x16x32_bf16(aB, b, accB[nt], 0, 0, 0);
    }
  }

  const int colb = lane & 15;
  const int rbase = w*16 + ((lane >> 4) << 2);
  #pragma unroll
  for (int nt=0; nt<7; ++nt){
    int col = nt*16 + colb;
    if (col >= DDIM) continue;
    #pragma unroll
    for (int r=0; r<4; ++r){
      long ppA = p0 + rbase + r;
      if (ppA < NE) evals[ppA*DDIM + col] = f2bf(accA[nt][r]);
      long ppB = p0 + 64 + rbase + r;
      if (ppB < NE) evals[ppB*DDIM + col] = f2bf(accB[nt][r]);
    }
  }
}

// ---------------- per-dst aggregation, 4-edge unrolled ----------------
__global__ __launch_bounds__(256) void k_agg(
    const int* __restrict__ rowptr, const unsigned long long* __restrict__ sp64,
    const unsigned short* __restrict__ evals,
    const float* __restrict__ qs, const float* __restrict__ ks, const float* __restrict__ vs,
    const float* __restrict__ ssb, float* __restrict__ oute)
{
  const int w = threadIdx.x >> 6;
  const int lane = threadIdx.x & 63;
  const int node = blockIdx.x*4 + w;
  if (node >= N_SUBN) return;

  const int half = lane >> 5;               // 0: head0, 1: head1
  const int lh = lane & 31;
  const bool act = lh < 25;
  const int c = half*50 + lh*2;             // col pair (c, c+1)

  float q0 = 0.f, q1 = 0.f;
  if (act){
    float2 qq = *(const float2*)(qs + (size_t)node*DDIM + c);
    q0 = qq.x; q1 = qq.y;
  }
  const int b0 = rowptr[node], b1 = rowptr[node+1];
  float num0 = 0.f, num1 = 0.f, den = 0.f;
  const float INV = 0.14142135623730951f;   // 1/sqrt(50)

  int p = b0;
  for (; p+3 < b1; p += 4){
    float ph[4], ev0[4], ev1[4], vv0[4], vv1[4];
    #pragma unroll
    for (int j=0;j<4;++j){
      uint2 se = ((const uint2*)sp64)[p+j];
      int s = (int)se.x;
      int e = (int)se.y;
      float e0=0.f,e1=0.f,k0_=0.f,k1_=0.f,v0_=0.f,v1_=0.f;
      if (act){
        unsigned ea = *(const unsigned*)(evals + (size_t)e*DDIM + c);
        float2 ka = *(const float2*)(ks + (size_t)s*DDIM + c);
        float2 va = *(const float2*)(vs + (size_t)s*DDIM + c);
        e0 = bf2f((unsigned short)(ea & 0xffff)); e1 = bf2f((unsigned short)(ea >> 16));
        k0_ = ka.x; k1_ = ka.y; v0_ = va.x; v1_ = va.y;
      }
      ph[j] = fmaf(q0, k0_+e0, q1*(k1_+e1));
      ev0[j]=e0; ev1[j]=e1; vv0[j]=v0_; vv1[j]=v1_;
    }
    #pragma unroll
    for (int m=1; m<32; m<<=1){
      #pragma unroll
      for (int j=0;j<4;++j) ph[j] += __shfl_xor(ph[j], m);
    }
    #pragma unroll
    for (int j=0;j<4;++j){
      float a = __expf(ph[j]*INV);
      den += a;
      num0 = fmaf(a, vv0[j]+ev0[j], num0);
      num1 = fmaf(a, vv1[j]+ev1[j], num1);
    }
  }
  for (; p < b1; ++p){
    uint2 se = ((const uint2*)sp64)[p];
    int s = (int)se.x, e = (int)se.y;
    float e0=0.f,e1=0.f,k0_=0.f,k1_=0.f,v0_=0.f,v1_=0.f;
    if (act){
      unsigned ea = *(const unsigned*)(evals + (size_t)e*DDIM + c);
      float2 ka = *(const float2*)(ks + (size_t)s*DDIM + c);
      float2 va = *(const float2*)(vs + (size_t)s*DDIM + c);
      e0 = bf2f((unsigned short)(ea & 0xffff)); e1 = bf2f((unsigned short)(ea >> 16));
      k0_ = ka.x; k1_ = ka.y; v0_ = va.x; v1_ = va.y;
    }
    float ph = fmaf(q0, k0_+e0, q1*(k1_+e1));
    #pragma unroll
    for (int m=1; m<32; m<<=1) ph += __shfl_xor(ph, m);
    float a = __expf(ph*INV);
    den += a;
    num0 = fmaf(a, v0_+e0, num0);
    num1 = fmaf(a, v1_+e1, num1);
  }

  if (act){
    float inv_d = 1.f / (den + 1e-16f);
    const float* sp = ssb + (size_t)node*DDIM + c;
    float* op = oute + (size_t)node*DDIM + c;
    op[0] = num0*inv_d + sp[0];
    op[1] = num1*inv_d + sp[1];
  }
}

// ---------------- fused predictor ----------------
__global__ __launch_bounds__(256) void k_pred(
    const float* __restrict__ oute, const int* __restrict__ srci, const int* __restrict__ dsti,
    const float* __restrict__ Wps, const float* __restrict__ bps,
    const float* __restrict__ Wpd, const float* __restrict__ bpd,
    const float* __restrict__ Wpf, const float* __restrict__ bpf,
    float* __restrict__ outp)
{
  __shared__ float hs[2][DDIM];
  const int tid = threadIdx.x;
  const int r = tid / DDIM;
  const int c = tid - r*DDIM;
  const int b = blockIdx.x*2 + r;
  const bool on = (r < 2) && (b < NB);

  if (on){
    const float* r1 = oute + (size_t)srci[b]*DDIM;
    const float* r2 = oute + (size_t)dsti[b]*DDIM;
    float a = bps[c] + bpd[c];
    for (int k=0;k<DDIM;k++){
      a = fmaf(r1[k], Wps[k*DDIM+c], a);
      a = fmaf(r2[k], Wpd[k*DDIM+c], a);
    }
    hs[r][c] = fmaxf(a, 0.f);
  }
  __syncthreads();
  if (on){
    float a = bpf[c];
    for (int k=0;k<DDIM;k++) a = fmaf(hs[r][k], Wpf[k*DDIM+c], a);
    outp[(size_t)b*DDIM + c] = a;
  }
}

extern "C" void kernel_launch(void* const* d_in, const int* in_sizes, int n_in,
                              void* d_out, int out_size, void* d_ws, size_t ws_size,
                              hipStream_t stream)
{
  const float* mem   = (const float*)d_in[0];
  const int*   lastu = (const int*)  d_in[1];
  const int*   nid   = (const int*)  d_in[2];
  const int*   ei    = (const int*)  d_in[3];
  const int*   tt    = (const int*)  d_in[4];
  const float* msg   = (const float*)d_in[5];
  const int*   srci  = (const int*)  d_in[6];
  const int*   dsti  = (const int*)  d_in[7];
  const float* wtime = (const float*)d_in[8];
  const float* btime = (const float*)d_in[9];
  const float* Wq = (const float*)d_in[10]; const float* bq = (const float*)d_in[11];
  const float* Wk = (const float*)d_in[12]; const float* bk = (const float*)d_in[13];
  const float* Wv = (const float*)d_in[14]; const float* bv = (const float*)d_in[15];
  const float* We = (const float*)d_in[16];
  const float* Ws = (const float*)d_in[17]; const float* bs = (const float*)d_in[18];
  const float* Wps= (const float*)d_in[19]; const float* bps= (const float*)d_in[20];
  const float* Wpd= (const float*)d_in[21]; const float* bpd= (const float*)d_in[22];
  const float* Wpf= (const float*)d_in[23]; const float* bpf= (const float*)d_in[24];

  char* wsp = (char*)d_ws;
  auto alloc = [&](size_t bytes)->void*{
    void* p = (void*)wsp;
    wsp += (bytes + 255) & ~(size_t)255;
    return p;
  };
  unsigned short* evals = (unsigned short*)alloc((size_t)NE*DDIM*2);   // 100 MB
  float* qs   = (float*)alloc((size_t)N_SUBN*DDIM*4);
  float* ks   = (float*)alloc((size_t)N_SUBN*DDIM*4);
  float* vs   = (float*)alloc((size_t)N_SUBN*DDIM*4);
  float* ssb  = (float*)alloc((size_t)N_SUBN*DDIM*4);
  float* oute = (float*)alloc((size_t)N_SUBN*DDIM*4);
  int* cnt    = (int*)alloc((size_t)N_SUBN*4);
  int* rowptr = (int*)alloc((size_t)(N_SUBN+1)*4);
  int* ofs    = (int*)alloc((size_t)N_SUBN*4);
  int* bsum   = (int*)alloc((size_t)NCHUNK*4);
  int* bbase  = (int*)alloc((size_t)NCHUNK*4);
  unsigned long long* sp64 = (unsigned long long*)alloc((size_t)NE*8);
  int* lusub  = (int*)alloc((size_t)N_SUBN*4);
  unsigned short* Web = (unsigned short*)alloc((size_t)49*64*8*2);
  unsigned short* Wnb = (unsigned short*)alloc((size_t)4*28*64*8*2);

  k_misc<<<(N_SUBN+255)/256, 256, 0, stream>>>(lastu, nid, cnt, lusub, We, Web,
                                               Wq, Wk, Wv, Ws, Wnb);
  k_hist<<<(NE+255)/256, 256, 0, stream>>>(ei, cnt);
  k_bsum<<<NCHUNK, 256, 0, stream>>>(cnt, bsum);
  k_bscan<<<1, 64, 0, stream>>>(bsum, bbase);
  k_off<<<NCHUNK, 1024, 0, stream>>>(cnt, bbase, rowptr, ofs);
  k_perm<<<(NE+255)/256, 256, 0, stream>>>(ei, ofs, sp64);

  dim3 gn((N_SUBN+63)/64, 2);
  k_node<<<gn, 256, 0, stream>>>(mem, nid, Wnb, bq, bk, bv, bs, qs, ks, vs, ssb);

  k_gemm<<<(NE+127)/128, 256, 0, stream>>>(ei, tt, lusub, msg, wtime, btime, Web, evals);

  k_agg<<<(N_SUBN+3)/4, 256, 0, stream>>>(rowptr, sp64, evals, qs, ks, vs, ssb, oute);

  k_pred<<<(NB+1)/2, 256, 0, stream>>>(oute, srci, dsti, Wps,bps, Wpd,bpd, Wpf,bpf,
                                       (float*)d_out);
}

// Round 7
// 376.326 us; speedup vs baseline: 7.8038x; 1.0432x over previous
//
#include <hip/hip_runtime.h>
#include <math.h>

#define N_SUBN  50000
#define NE      500000
#define NB      5000
#define DDIM    100
#define TDIM    100
#define KATTR   200
#define NCHUNK  49        // ceil(N_SUBN/1024)

typedef __attribute__((ext_vector_type(8))) short short8;
typedef __attribute__((ext_vector_type(4))) float f32x4;

__device__ inline unsigned short f2bf(float f){
  union{float f; unsigned int u;} v; v.f = f;
  unsigned int r = (v.u + 0x7fffu + ((v.u >> 16) & 1u)) >> 16;   // RNE
  return (unsigned short)r;
}
__device__ inline float bf2f(unsigned short u){
  union{unsigned int u; float f;} v; v.u = ((unsigned int)u) << 16;
  return v.f;
}

// fast cos for |x| up to ~1e6: Cody-Waite 2-term reduction (fma-exact) + v_cos.
__device__ inline float fast_cos(float x){
  constexpr double TWO_PI_D = 6.2831853071795864769252867665590;
  constexpr float I2PI = (float)(1.0/TWO_PI_D);
  constexpr float C1 = (float)TWO_PI_D;
  constexpr float C2 = (float)(TWO_PI_D - (double)((float)TWO_PI_D));
  float k = rintf(x * I2PI);
  float r = fmaf(k, -C1, x);
  r = fmaf(k, -C2, r);
  return __cosf(r);
}

// A-fragment build for edge GEMM: 8 bf16 at k0..k0+7 of [cos_enc | msg | 0pad]
__device__ inline short8 build_attr(float rel, const float* __restrict__ mrow,
                                    const float* __restrict__ wt,
                                    const float* __restrict__ bt, int k0){
  short8 a;
  if (k0 + 7 < TDIM){
    float4 w0 = *(const float4*)(wt + k0);
    float4 w1 = *(const float4*)(wt + k0 + 4);
    float4 b0 = *(const float4*)(bt + k0);
    float4 b1 = *(const float4*)(bt + k0 + 4);
    // __fmul_rn/__fadd_rn: must match XLA's non-contracted mul-then-add rounding
    a[0] = (short)f2bf(fast_cos(__fadd_rn(__fmul_rn(rel, w0.x), b0.x)));
    a[1] = (short)f2bf(fast_cos(__fadd_rn(__fmul_rn(rel, w0.y), b0.y)));
    a[2] = (short)f2bf(fast_cos(__fadd_rn(__fmul_rn(rel, w0.z), b0.z)));
    a[3] = (short)f2bf(fast_cos(__fadd_rn(__fmul_rn(rel, w0.w), b0.w)));
    a[4] = (short)f2bf(fast_cos(__fadd_rn(__fmul_rn(rel, w1.x), b1.x)));
    a[5] = (short)f2bf(fast_cos(__fadd_rn(__fmul_rn(rel, w1.y), b1.y)));
    a[6] = (short)f2bf(fast_cos(__fadd_rn(__fmul_rn(rel, w1.z), b1.z)));
    a[7] = (short)f2bf(fast_cos(__fadd_rn(__fmul_rn(rel, w1.w), b1.w)));
  } else if (k0 >= KATTR){
    #pragma unroll
    for (int j=0;j<8;++j) a[j] = 0;
  } else if (k0 >= TDIM){
    float4 m0 = *(const float4*)(mrow + (k0 - TDIM));
    float4 m1 = *(const float4*)(mrow + (k0 - TDIM) + 4);
    a[0] = (short)f2bf(m0.x); a[1] = (short)f2bf(m0.y);
    a[2] = (short)f2bf(m0.z); a[3] = (short)f2bf(m0.w);
    a[4] = (short)f2bf(m1.x); a[5] = (short)f2bf(m1.y);
    a[6] = (short)f2bf(m1.z); a[7] = (short)f2bf(m1.w);
  } else {
    #pragma unroll
    for (int j=0;j<8;++j){
      int k = k0 + j;
      float x = (k < TDIM)
                ? fast_cos(__fadd_rn(__fmul_rn(rel, wt[k]), bt[k]))
                : mrow[k - TDIM];
      a[j] = (short)f2bf(x);
    }
  }
  return a;
}

// ---------------- fused: zero cnt + lusub gather + pack Web (edge) + Wnb (node) ----------------
__global__ __launch_bounds__(256) void k_misc(
    const int* __restrict__ lastu, const int* __restrict__ nid,
    int* __restrict__ cnt, int* __restrict__ lusub,
    const float* __restrict__ We, unsigned short* __restrict__ Web,
    const float* __restrict__ Wq, const float* __restrict__ Wk,
    const float* __restrict__ Wv, const float* __restrict__ Ws,
    unsigned short* __restrict__ Wnb)
{
  int i = blockIdx.x*256 + threadIdx.x;
  if (i < N_SUBN){
    cnt[i] = 0;
    lusub[i] = lastu[nid[i]];
  }
  if (i < 49*64){
    int l = i & 63; int t = i >> 6; int kt = t / 7; int nt = t - kt*7;
    int col = nt*16 + (l & 15);
    int kbase = kt*32 + ((l >> 4) << 3);
    short8 pack;
    #pragma unroll
    for (int j = 0; j < 8; ++j){
      int k = kbase + j;
      float v = (k < KATTR && col < DDIM) ? We[k*DDIM + col] : 0.f;
      pack[j] = (short)f2bf(v);
    }
    *((short8*)Web + i) = pack;
  }
  if (i < 4*28*64){
    int l = i & 63; int t = i >> 6;              // 0..111
    int which = t / 28; int t2 = t - which*28;
    int kt = t2 / 7; int nt = t2 - kt*7;
    const float* W = (which==0)?Wq:(which==1)?Wk:(which==2)?Wv:Ws;
    int col = nt*16 + (l & 15);
    int kbase = kt*32 + ((l >> 4) << 3);
    short8 pack;
    #pragma unroll
    for (int j = 0; j < 8; ++j){
      int k = kbase + j;
      float v = (k < DDIM && col < DDIM) ? W[k*DDIM + col] : 0.f;
      pack[j] = (short)f2bf(v);
    }
    *((short8*)Wnb + i) = pack;
  }
}

// ---------------- CSR: histogram over dst ----------------
__global__ void k_hist(const int* __restrict__ ei, int* __restrict__ cnt){
  int i = blockIdx.x*blockDim.x + threadIdx.x;
  if (i < NE) atomicAdd(&cnt[ei[NE + i]], 1);
}

// ---------------- CSR scan phase 1 ----------------
__global__ __launch_bounds__(256) void k_bsum(const int* __restrict__ cnt, int* __restrict__ bsum){
  __shared__ int wsum[4];
  int b = blockIdx.x, tid = threadIdx.x;
  int base = b*1024 + tid*4;
  int s = 0;
  #pragma unroll
  for (int i=0;i<4;i++){ int idx = base+i; if (idx < N_SUBN) s += cnt[idx]; }
  #pragma unroll
  for (int m=1;m<64;m<<=1) s += __shfl_xor(s, m);
  if ((tid&63)==0) wsum[tid>>6] = s;
  __syncthreads();
  if (tid==0) bsum[b] = wsum[0]+wsum[1]+wsum[2]+wsum[3];
}

// ---------------- CSR scan phase 2 ----------------
__global__ void k_bscan(const int* __restrict__ bsum, int* __restrict__ bbase){
  int l = threadIdx.x;
  int v = (l < NCHUNK) ? bsum[l] : 0;
  int orig = v;
  for (int off=1; off<64; off<<=1){
    int t = __shfl_up(v, off);
    if (l >= off) v += t;
  }
  if (l < NCHUNK) bbase[l] = v - orig;
}

// ---------------- CSR scan phase 3 ----------------
__global__ __launch_bounds__(1024) void k_off(const int* __restrict__ cnt, const int* __restrict__ bbase,
                                              int* __restrict__ rowptr, int* __restrict__ ofs){
  __shared__ int sd[1024];
  int b = blockIdx.x, tid = threadIdx.x;
  int i = b*1024 + tid;
  int v = (i < N_SUBN) ? cnt[i] : 0;
  sd[tid] = v; __syncthreads();
  for (int off=1; off<1024; off<<=1){
    int t = (tid >= off) ? sd[tid-off] : 0;
    __syncthreads();
    sd[tid] += t;
    __syncthreads();
  }
  int incl = sd[tid] + bbase[b];
  if (i < N_SUBN){ rowptr[i+1] = incl; ofs[i] = incl - v; }
  if (i == 0) rowptr[0] = 0;
}

// ---------------- CSR: bucket edges by dst, packed (perm<<32 | src) ----------------
__global__ void k_perm(const int* __restrict__ ei, int* __restrict__ ofs,
                       unsigned long long* __restrict__ sp64){
  int i = blockIdx.x*blockDim.x + threadIdx.x;
  if (i < NE){
    int d = ei[NE + i];
    int pos = atomicAdd(&ofs[d], 1);
    sp64[pos] = ((unsigned long long)(unsigned)i << 32) | (unsigned)ei[i];
  }
}

// ---------------- node GEMMs via MFMA: pair 0 -> k,v (packed bf16) ; pair 1 -> q,skip (f32) ----------------
__global__ __launch_bounds__(256, 4) void k_node(
    const float* __restrict__ mem, const int* __restrict__ nid,
    const unsigned short* __restrict__ Wnb,
    const float* __restrict__ bq, const float* __restrict__ bk,
    const float* __restrict__ bv, const float* __restrict__ bs,
    float* __restrict__ qs, unsigned short* __restrict__ kvb,
    float* __restrict__ ss)
{
  const int tid = threadIdx.x;
  const int lane = tid & 63;
  const int w = tid >> 6;
  const int pair = blockIdx.y;
  const int node0 = blockIdx.x*64;
  const int arow = w*16 + (lane & 15);
  const int koff = (lane >> 4) << 3;

  int node = node0 + arow;
  int nc = (node < N_SUBN) ? node : (N_SUBN-1);
  const float* zrow = mem + (size_t)nid[nc]*DDIM;

  f32x4 acc0[7], acc1[7];
  #pragma unroll
  for (int nt=0; nt<7; ++nt){ acc0[nt] = (f32x4){0,0,0,0}; acc1[nt] = (f32x4){0,0,0,0}; }

  // pair0: (Wk, Wv) -> packed kv bf16 ; pair1: (Wq, Ws) -> qs, ss f32
  const int wm0 = pair ? 0 : 1;
  const int wm1 = pair ? 3 : 2;
  #pragma unroll
  for (int kt=0; kt<4; ++kt){
    const int k0 = kt*32 + koff;
    short8 a;
    if (k0 + 7 < DDIM){
      float4 m0 = *(const float4*)(zrow + k0);
      float4 m1 = *(const float4*)(zrow + k0 + 4);
      a[0] = (short)f2bf(m0.x); a[1] = (short)f2bf(m0.y);
      a[2] = (short)f2bf(m0.z); a[3] = (short)f2bf(m0.w);
      a[4] = (short)f2bf(m1.x); a[5] = (short)f2bf(m1.y);
      a[6] = (short)f2bf(m1.z); a[7] = (short)f2bf(m1.w);
    } else if (k0 >= DDIM){
      #pragma unroll
      for (int j=0;j<8;++j) a[j] = 0;
    } else {  // k0 == 96
      float4 m0 = *(const float4*)(zrow + 96);
      a[0] = (short)f2bf(m0.x); a[1] = (short)f2bf(m0.y);
      a[2] = (short)f2bf(m0.z); a[3] = (short)f2bf(m0.w);
      a[4] = 0; a[5] = 0; a[6] = 0; a[7] = 0;
    }
    const short8* wb0 = (const short8*)Wnb + (size_t)((wm0*4 + kt)*7)*64 + lane;
    const short8* wb1 = (const short8*)Wnb + (size_t)((wm1*4 + kt)*7)*64 + lane;
    #pragma unroll
    for (int nt=0; nt<7; ++nt){
      short8 b0 = wb0[(size_t)nt*64];
      short8 b1 = wb1[(size_t)nt*64];
      acc0[nt] = __builtin_amdgcn_mfma_f32_16x16x32_bf16(a, b0, acc0[nt], 0, 0, 0);
      acc1[nt] = __builtin_amdgcn_mfma_f32_16x16x32_bf16(a, b1, acc1[nt], 0, 0, 0);
    }
  }

  const int colb = lane & 15;
  const int rbase = w*16 + ((lane >> 4) << 2);
  if (pair == 0){
    #pragma unroll
    for (int nt=0; nt<7; ++nt){
      int col = nt*16 + colb;
      if (col >= DDIM) continue;
      float bb0 = bk[col], bb1 = bv[col];
      #pragma unroll
      for (int r=0; r<4; ++r){
        int nn = node0 + rbase + r;
        if (nn < N_SUBN){
          unsigned pk = (unsigned)f2bf(acc0[nt][r] + bb0)
                      | ((unsigned)f2bf(acc1[nt][r] + bb1) << 16);
          *(unsigned*)(kvb + (size_t)nn*(2*DDIM) + col*2) = pk;
        }
      }
    }
  } else {
    #pragma unroll
    for (int nt=0; nt<7; ++nt){
      int col = nt*16 + colb;
      if (col >= DDIM) continue;
      float bb0 = bq[col], bb1 = bs[col];
      #pragma unroll
      for (int r=0; r<4; ++r){
        int nn = node0 + rbase + r;
        if (nn < N_SUBN){
          qs[(size_t)nn*DDIM + col] = acc0[nt][r] + bb0;
          ss[(size_t)nn*DDIM + col] = acc1[nt][r] + bb1;
        }
      }
    }
  }
}

// ---------------- MFMA edge GEMM: 128 edges/block, ALL A-fragments hoisted for ILP ----------------
__global__ __launch_bounds__(256, 3) void k_gemm(
    const int* __restrict__ ei, const int* __restrict__ tt,
    const int* __restrict__ lusub, const float* __restrict__ msg,
    const float* __restrict__ wt, const float* __restrict__ bt,
    const unsigned short* __restrict__ Web, unsigned short* __restrict__ evals)
{
  const int tid = threadIdx.x;
  const int lane = tid & 63;
  const int w = tid >> 6;
  const long p0 = (long)blockIdx.x * 128;
  const int arow = w*16 + (lane & 15);
  const int koff = (lane >> 4) << 3;

  long pA = p0 + arow;
  long pB = p0 + 64 + arow;
  long pcA = (pA < NE) ? pA : (NE - 1);
  long pcB = (pB < NE) ? pB : (NE - 1);
  const float relA = (float)(lusub[ei[pcA]] - tt[pcA]);
  const float relB = (float)(lusub[ei[pcB]] - tt[pcB]);
  const float* mrowA = msg + pcA*DDIM;
  const float* mrowB = msg + pcB*DDIM;

  // build ALL fragments up front: 24 independent loads + 112 independent cos chains
  short8 aA[7], aB[7];
  #pragma unroll
  for (int kt=0; kt<7; ++kt){
    aA[kt] = build_attr(relA, mrowA, wt, bt, kt*32 + koff);
    aB[kt] = build_attr(relB, mrowB, wt, bt, kt*32 + koff);
  }

  f32x4 accA[7], accB[7];
  #pragma unroll
  for (int nt=0; nt<7; ++nt){ accA[nt] = (f32x4){0,0,0,0}; accB[nt] = (f32x4){0,0,0,0}; }

  // pure Web-load + MFMA loop
  #pragma unroll
  for (int kt=0; kt<7; ++kt){
    const short8* wb = (const short8*)Web + (size_t)(kt*7)*64 + lane;
    #pragma unroll
    for (int nt=0; nt<7; ++nt){
      short8 b = wb[(size_t)nt*64];
      accA[nt] = __builtin_amdgcn_mfma_f32_16x16x32_bf16(aA[kt], b, accA[nt], 0, 0, 0);
      accB[nt] = __builtin_amdgcn_mfma_f32_16x16x32_bf16(aB[kt], b, accB[nt], 0, 0, 0);
    }
  }

  const int colb = lane & 15;
  const int rbase = w*16 + ((lane >> 4) << 2);
  #pragma unroll
  for (int nt=0; nt<7; ++nt){
    int col = nt*16 + colb;
    if (col >= DDIM) continue;
    #pragma unroll
    for (int r=0; r<4; ++r){
      long ppA = p0 + rbase + r;
      if (ppA < NE) evals[ppA*DDIM + col] = f2bf(accA[nt][r]);
      long ppB = p0 + 64 + rbase + r;
      if (ppB < NE) evals[ppB*DDIM + col] = f2bf(accB[nt][r]);
    }
  }
}

// ---------------- per-dst aggregation, 4-edge unrolled, packed bf16 kv ----------------
__global__ __launch_bounds__(256) void k_agg(
    const int* __restrict__ rowptr, const unsigned long long* __restrict__ sp64,
    const unsigned short* __restrict__ evals,
    const float* __restrict__ qs, const unsigned short* __restrict__ kvb,
    const float* __restrict__ ssb, float* __restrict__ oute)
{
  const int w = threadIdx.x >> 6;
  const int lane = threadIdx.x & 63;
  const int node = blockIdx.x*4 + w;
  if (node >= N_SUBN) return;

  const int half = lane >> 5;               // 0: head0, 1: head1
  const int lh = lane & 31;
  const bool act = lh < 25;
  const int c = half*50 + lh*2;             // col pair (c, c+1)

  float q0 = 0.f, q1 = 0.f;
  if (act){
    float2 qq = *(const float2*)(qs + (size_t)node*DDIM + c);
    q0 = qq.x; q1 = qq.y;
  }
  const int b0 = rowptr[node], b1 = rowptr[node+1];
  float num0 = 0.f, num1 = 0.f, den = 0.f;
  const float INV = 0.14142135623730951f;   // 1/sqrt(50)

  int p = b0;
  for (; p+3 < b1; p += 4){
    float ph[4], ev0[4], ev1[4], vv0[4], vv1[4];
    #pragma unroll
    for (int j=0;j<4;++j){
      uint2 se = ((const uint2*)sp64)[p+j];
      int s = (int)se.x;
      int e = (int)se.y;
      float e0=0.f,e1=0.f,k0_=0.f,k1_=0.f,v0_=0.f,v1_=0.f;
      if (act){
        unsigned ea = *(const unsigned*)(evals + (size_t)e*DDIM + c);
        uint2 kv = *(const uint2*)(kvb + (size_t)s*(2*DDIM) + c*2);
        e0 = bf2f((unsigned short)(ea & 0xffff)); e1 = bf2f((unsigned short)(ea >> 16));
        k0_ = bf2f((unsigned short)(kv.x & 0xffff)); v0_ = bf2f((unsigned short)(kv.x >> 16));
        k1_ = bf2f((unsigned short)(kv.y & 0xffff)); v1_ = bf2f((unsigned short)(kv.y >> 16));
      }
      ph[j] = fmaf(q0, k0_+e0, q1*(k1_+e1));
      ev0[j]=e0; ev1[j]=e1; vv0[j]=v0_; vv1[j]=v1_;
    }
    #pragma unroll
    for (int m=1; m<32; m<<=1){
      #pragma unroll
      for (int j=0;j<4;++j) ph[j] += __shfl_xor(ph[j], m);
    }
    #pragma unroll
    for (int j=0;j<4;++j){
      float a = __expf(ph[j]*INV);
      den += a;
      num0 = fmaf(a, vv0[j]+ev0[j], num0);
      num1 = fmaf(a, vv1[j]+ev1[j], num1);
    }
  }
  for (; p < b1; ++p){
    uint2 se = ((const uint2*)sp64)[p];
    int s = (int)se.x, e = (int)se.y;
    float e0=0.f,e1=0.f,k0_=0.f,k1_=0.f,v0_=0.f,v1_=0.f;
    if (act){
      unsigned ea = *(const unsigned*)(evals + (size_t)e*DDIM + c);
      uint2 kv = *(const uint2*)(kvb + (size_t)s*(2*DDIM) + c*2);
      e0 = bf2f((unsigned short)(ea & 0xffff)); e1 = bf2f((unsigned short)(ea >> 16));
      k0_ = bf2f((unsigned short)(kv.x & 0xffff)); v0_ = bf2f((unsigned short)(kv.x >> 16));
      k1_ = bf2f((unsigned short)(kv.y & 0xffff)); v1_ = bf2f((unsigned short)(kv.y >> 16));
    }
    float ph = fmaf(q0, k0_+e0, q1*(k1_+e1));
    #pragma unroll
    for (int m=1; m<32; m<<=1) ph += __shfl_xor(ph, m);
    float a = __expf(ph*INV);
    den += a;
    num0 = fmaf(a, v0_+e0, num0);
    num1 = fmaf(a, v1_+e1, num1);
  }

  if (act){
    float inv_d = 1.f / (den + 1e-16f);
    const float* sp = ssb + (size_t)node*DDIM + c;
    float* op = oute + (size_t)node*DDIM + c;
    op[0] = num0*inv_d + sp[0];
    op[1] = num1*inv_d + sp[1];
  }
}

// ---------------- fused predictor ----------------
__global__ __launch_bounds__(256) void k_pred(
    const float* __restrict__ oute, const int* __restrict__ srci, const int* __restrict__ dsti,
    const float* __restrict__ Wps, const float* __restrict__ bps,
    const float* __restrict__ Wpd, const float* __restrict__ bpd,
    const float* __restrict__ Wpf, const float* __restrict__ bpf,
    float* __restrict__ outp)
{
  __shared__ float hs[2][DDIM];
  const int tid = threadIdx.x;
  const int r = tid / DDIM;
  const int c = tid - r*DDIM;
  const int b = blockIdx.x*2 + r;
  const bool on = (r < 2) && (b < NB);

  if (on){
    const float* r1 = oute + (size_t)srci[b]*DDIM;
    const float* r2 = oute + (size_t)dsti[b]*DDIM;
    float a = bps[c] + bpd[c];
    for (int k=0;k<DDIM;k++){
      a = fmaf(r1[k], Wps[k*DDIM+c], a);
      a = fmaf(r2[k], Wpd[k*DDIM+c], a);
    }
    hs[r][c] = fmaxf(a, 0.f);
  }
  __syncthreads();
  if (on){
    float a = bpf[c];
    for (int k=0;k<DDIM;k++) a = fmaf(hs[r][k], Wpf[k*DDIM+c], a);
    outp[(size_t)b*DDIM + c] = a;
  }
}

extern "C" void kernel_launch(void* const* d_in, const int* in_sizes, int n_in,
                              void* d_out, int out_size, void* d_ws, size_t ws_size,
                              hipStream_t stream)
{
  const float* mem   = (const float*)d_in[0];
  const int*   lastu = (const int*)  d_in[1];
  const int*   nid   = (const int*)  d_in[2];
  const int*   ei    = (const int*)  d_in[3];
  const int*   tt    = (const int*)  d_in[4];
  const float* msg   = (const float*)d_in[5];
  const int*   srci  = (const int*)  d_in[6];
  const int*   dsti  = (const int*)  d_in[7];
  const float* wtime = (const float*)d_in[8];
  const float* btime = (const float*)d_in[9];
  const float* Wq = (const float*)d_in[10]; const float* bq = (const float*)d_in[11];
  const float* Wk = (const float*)d_in[12]; const float* bk = (const float*)d_in[13];
  const float* Wv = (const float*)d_in[14]; const float* bv = (const float*)d_in[15];
  const float* We = (const float*)d_in[16];
  const float* Ws = (const float*)d_in[17]; const float* bs = (const float*)d_in[18];
  const float* Wps= (const float*)d_in[19]; const float* bps= (const float*)d_in[20];
  const float* Wpd= (const float*)d_in[21]; const float* bpd= (const float*)d_in[22];
  const float* Wpf= (const float*)d_in[23]; const float* bpf= (const float*)d_in[24];

  char* wsp = (char*)d_ws;
  auto alloc = [&](size_t bytes)->void*{
    void* p = (void*)wsp;
    wsp += (bytes + 255) & ~(size_t)255;
    return p;
  };
  unsigned short* evals = (unsigned short*)alloc((size_t)NE*DDIM*2);     // 100 MB
  float* qs   = (float*)alloc((size_t)N_SUBN*DDIM*4);
  unsigned short* kvb = (unsigned short*)alloc((size_t)N_SUBN*DDIM*2*2); // 20 MB packed (k,v) bf16
  float* ssb  = (float*)alloc((size_t)N_SUBN*DDIM*4);
  float* oute = (float*)alloc((size_t)N_SUBN*DDIM*4);
  int* cnt    = (int*)alloc((size_t)N_SUBN*4);
  int* rowptr = (int*)alloc((size_t)(N_SUBN+1)*4);
  int* ofs    = (int*)alloc((size_t)N_SUBN*4);
  int* bsum   = (int*)alloc((size_t)NCHUNK*4);
  int* bbase  = (int*)alloc((size_t)NCHUNK*4);
  unsigned long long* sp64 = (unsigned long long*)alloc((size_t)NE*8);
  int* lusub  = (int*)alloc((size_t)N_SUBN*4);
  unsigned short* Web = (unsigned short*)alloc((size_t)49*64*8*2);
  unsigned short* Wnb = (unsigned short*)alloc((size_t)4*28*64*8*2);

  k_misc<<<(N_SUBN+255)/256, 256, 0, stream>>>(lastu, nid, cnt, lusub, We, Web,
                                               Wq, Wk, Wv, Ws, Wnb);
  k_hist<<<(NE+255)/256, 256, 0, stream>>>(ei, cnt);
  k_bsum<<<NCHUNK, 256, 0, stream>>>(cnt, bsum);
  k_bscan<<<1, 64, 0, stream>>>(bsum, bbase);
  k_off<<<NCHUNK, 1024, 0, stream>>>(cnt, bbase, rowptr, ofs);
  k_perm<<<(NE+255)/256, 256, 0, stream>>>(ei, ofs, sp64);

  dim3 gn((N_SUBN+63)/64, 2);
  k_node<<<gn, 256, 0, stream>>>(mem, nid, Wnb, bq, bk, bv, bs, qs, kvb, ssb);

  k_gemm<<<(NE+127)/128, 256, 0, stream>>>(ei, tt, lusub, msg, wtime, btime, Web, evals);

  k_agg<<<(N_SUBN+3)/4, 256, 0, stream>>>(rowptr, sp64, evals, qs, kvb, ssb, oute);

  k_pred<<<(NB+1)/2, 256, 0, stream>>>(oute, srci, dsti, Wps,bps, Wpd,bpd, Wpf,bpf,
                                       (float*)d_out);
}

// Round 8
// 374.850 us; speedup vs baseline: 7.8345x; 1.0039x over previous
//
#include <hip/hip_runtime.h>
#include <math.h>

#define N_SUBN  50000
#define NE      500000
#define NB      5000
#define DDIM    100
#define TDIM    100
#define KATTR   200
#define NCHUNK  49        // ceil(N_SUBN/1024)

typedef __attribute__((ext_vector_type(8))) short short8;
typedef __attribute__((ext_vector_type(4))) float f32x4;

__device__ inline unsigned short f2bf(float f){
  union{float f; unsigned int u;} v; v.f = f;
  unsigned int r = (v.u + 0x7fffu + ((v.u >> 16) & 1u)) >> 16;   // RNE
  return (unsigned short)r;
}
__device__ inline float bf2f(unsigned short u){
  union{unsigned int u; float f;} v; v.u = ((unsigned int)u) << 16;
  return v.f;
}

// fast cos for |x| up to ~1e6: Cody-Waite 2-term reduction (fma-exact) + v_cos.
__device__ inline float fast_cos(float x){
  constexpr double TWO_PI_D = 6.2831853071795864769252867665590;
  constexpr float I2PI = (float)(1.0/TWO_PI_D);
  constexpr float C1 = (float)TWO_PI_D;
  constexpr float C2 = (float)(TWO_PI_D - (double)((float)TWO_PI_D));
  float k = rintf(x * I2PI);
  float r = fmaf(k, -C1, x);
  r = fmaf(k, -C2, r);
  return __cosf(r);
}

// ---------------- fused: zero cnt + lusub gather + pack Web (edge) + Wnb (node) ----------------
__global__ __launch_bounds__(256) void k_misc(
    const int* __restrict__ lastu, const int* __restrict__ nid,
    int* __restrict__ cnt, int* __restrict__ lusub,
    const float* __restrict__ We, unsigned short* __restrict__ Web,
    const float* __restrict__ Wq, const float* __restrict__ Wk,
    const float* __restrict__ Wv, const float* __restrict__ Ws,
    unsigned short* __restrict__ Wnb)
{
  int i = blockIdx.x*256 + threadIdx.x;
  if (i < N_SUBN){
    cnt[i] = 0;
    lusub[i] = lastu[nid[i]];
  }
  if (i < 49*64){
    int l = i & 63; int t = i >> 6; int kt = t / 7; int nt = t - kt*7;
    int col = nt*16 + (l & 15);
    int kbase = kt*32 + ((l >> 4) << 3);
    short8 pack;
    #pragma unroll
    for (int j = 0; j < 8; ++j){
      int k = kbase + j;
      float v = (k < KATTR && col < DDIM) ? We[k*DDIM + col] : 0.f;
      pack[j] = (short)f2bf(v);
    }
    *((short8*)Web + i) = pack;
  }
  if (i < 4*28*64){
    int l = i & 63; int t = i >> 6;              // 0..111
    int which = t / 28; int t2 = t - which*28;
    int kt = t2 / 7; int nt = t2 - kt*7;
    const float* W = (which==0)?Wq:(which==1)?Wk:(which==2)?Wv:Ws;
    int col = nt*16 + (l & 15);
    int kbase = kt*32 + ((l >> 4) << 3);
    short8 pack;
    #pragma unroll
    for (int j = 0; j < 8; ++j){
      int k = kbase + j;
      float v = (k < DDIM && col < DDIM) ? W[k*DDIM + col] : 0.f;
      pack[j] = (short)f2bf(v);
    }
    *((short8*)Wnb + i) = pack;
  }
}

// ---------------- CSR: histogram over dst ----------------
__global__ void k_hist(const int* __restrict__ ei, int* __restrict__ cnt){
  int i = blockIdx.x*blockDim.x + threadIdx.x;
  if (i < NE) atomicAdd(&cnt[ei[NE + i]], 1);
}

// ---------------- CSR scan phase 1 ----------------
__global__ __launch_bounds__(256) void k_bsum(const int* __restrict__ cnt, int* __restrict__ bsum){
  __shared__ int wsum[4];
  int b = blockIdx.x, tid = threadIdx.x;
  int base = b*1024 + tid*4;
  int s = 0;
  #pragma unroll
  for (int i=0;i<4;i++){ int idx = base+i; if (idx < N_SUBN) s += cnt[idx]; }
  #pragma unroll
  for (int m=1;m<64;m<<=1) s += __shfl_xor(s, m);
  if ((tid&63)==0) wsum[tid>>6] = s;
  __syncthreads();
  if (tid==0) bsum[b] = wsum[0]+wsum[1]+wsum[2]+wsum[3];
}

// ---------------- CSR scan phase 2 ----------------
__global__ void k_bscan(const int* __restrict__ bsum, int* __restrict__ bbase){
  int l = threadIdx.x;
  int v = (l < NCHUNK) ? bsum[l] : 0;
  int orig = v;
  for (int off=1; off<64; off<<=1){
    int t = __shfl_up(v, off);
    if (l >= off) v += t;
  }
  if (l < NCHUNK) bbase[l] = v - orig;
}

// ---------------- CSR scan phase 3 ----------------
__global__ __launch_bounds__(1024) void k_off(const int* __restrict__ cnt, const int* __restrict__ bbase,
                                              int* __restrict__ rowptr, int* __restrict__ ofs){
  __shared__ int sd[1024];
  int b = blockIdx.x, tid = threadIdx.x;
  int i = b*1024 + tid;
  int v = (i < N_SUBN) ? cnt[i] : 0;
  sd[tid] = v; __syncthreads();
  for (int off=1; off<1024; off<<=1){
    int t = (tid >= off) ? sd[tid-off] : 0;
    __syncthreads();
    sd[tid] += t;
    __syncthreads();
  }
  int incl = sd[tid] + bbase[b];
  if (i < N_SUBN){ rowptr[i+1] = incl; ofs[i] = incl - v; }
  if (i == 0) rowptr[0] = 0;
}

// ---------------- CSR: bucket edges by dst, packed (perm<<32 | src) ----------------
__global__ void k_perm(const int* __restrict__ ei, int* __restrict__ ofs,
                       unsigned long long* __restrict__ sp64){
  int i = blockIdx.x*blockDim.x + threadIdx.x;
  if (i < NE){
    int d = ei[NE + i];
    int pos = atomicAdd(&ofs[d], 1);
    sp64[pos] = ((unsigned long long)(unsigned)i << 32) | (unsigned)ei[i];
  }
}

// ---------------- node GEMMs via MFMA: pair 0 -> k,v (packed bf16) ; pair 1 -> q,skip (f32) ----------------
__global__ __launch_bounds__(256, 4) void k_node(
    const float* __restrict__ mem, const int* __restrict__ nid,
    const unsigned short* __restrict__ Wnb,
    const float* __restrict__ bq, const float* __restrict__ bk,
    const float* __restrict__ bv, const float* __restrict__ bs,
    float* __restrict__ qs, unsigned short* __restrict__ kvb,
    float* __restrict__ ss)
{
  const int tid = threadIdx.x;
  const int lane = tid & 63;
  const int w = tid >> 6;
  const int pair = blockIdx.y;
  const int node0 = blockIdx.x*64;
  const int arow = w*16 + (lane & 15);
  const int koff = (lane >> 4) << 3;

  int node = node0 + arow;
  int nc = (node < N_SUBN) ? node : (N_SUBN-1);
  const float* zrow = mem + (size_t)nid[nc]*DDIM;

  f32x4 acc0[7], acc1[7];
  #pragma unroll
  for (int nt=0; nt<7; ++nt){ acc0[nt] = (f32x4){0,0,0,0}; acc1[nt] = (f32x4){0,0,0,0}; }

  // pair0: (Wk, Wv) -> packed kv bf16 ; pair1: (Wq, Ws) -> qs, ss f32
  const int wm0 = pair ? 0 : 1;
  const int wm1 = pair ? 3 : 2;
  #pragma unroll
  for (int kt=0; kt<4; ++kt){
    const int k0 = kt*32 + koff;
    short8 a;
    if (k0 + 7 < DDIM){
      float4 m0 = *(const float4*)(zrow + k0);
      float4 m1 = *(const float4*)(zrow + k0 + 4);
      a[0] = (short)f2bf(m0.x); a[1] = (short)f2bf(m0.y);
      a[2] = (short)f2bf(m0.z); a[3] = (short)f2bf(m0.w);
      a[4] = (short)f2bf(m1.x); a[5] = (short)f2bf(m1.y);
      a[6] = (short)f2bf(m1.z); a[7] = (short)f2bf(m1.w);
    } else if (k0 >= DDIM){
      #pragma unroll
      for (int j=0;j<8;++j) a[j] = 0;
    } else {  // k0 == 96
      float4 m0 = *(const float4*)(zrow + 96);
      a[0] = (short)f2bf(m0.x); a[1] = (short)f2bf(m0.y);
      a[2] = (short)f2bf(m0.z); a[3] = (short)f2bf(m0.w);
      a[4] = 0; a[5] = 0; a[6] = 0; a[7] = 0;
    }
    const short8* wb0 = (const short8*)Wnb + (size_t)((wm0*4 + kt)*7)*64 + lane;
    const short8* wb1 = (const short8*)Wnb + (size_t)((wm1*4 + kt)*7)*64 + lane;
    #pragma unroll
    for (int nt=0; nt<7; ++nt){
      short8 b0 = wb0[(size_t)nt*64];
      short8 b1 = wb1[(size_t)nt*64];
      acc0[nt] = __builtin_amdgcn_mfma_f32_16x16x32_bf16(a, b0, acc0[nt], 0, 0, 0);
      acc1[nt] = __builtin_amdgcn_mfma_f32_16x16x32_bf16(a, b1, acc1[nt], 0, 0, 0);
    }
  }

  const int colb = lane & 15;
  const int rbase = w*16 + ((lane >> 4) << 2);
  if (pair == 0){
    #pragma unroll
    for (int nt=0; nt<7; ++nt){
      int col = nt*16 + colb;
      if (col >= DDIM) continue;
      float bb0 = bk[col], bb1 = bv[col];
      #pragma unroll
      for (int r=0; r<4; ++r){
        int nn = node0 + rbase + r;
        if (nn < N_SUBN){
          unsigned pk = (unsigned)f2bf(acc0[nt][r] + bb0)
                      | ((unsigned)f2bf(acc1[nt][r] + bb1) << 16);
          *(unsigned*)(kvb + (size_t)nn*(2*DDIM) + col*2) = pk;
        }
      }
    }
  } else {
    #pragma unroll
    for (int nt=0; nt<7; ++nt){
      int col = nt*16 + colb;
      if (col >= DDIM) continue;
      float bb0 = bq[col], bb1 = bs[col];
      #pragma unroll
      for (int r=0; r<4; ++r){
        int nn = node0 + rbase + r;
        if (nn < N_SUBN){
          qs[(size_t)nn*DDIM + col] = acc0[nt][r] + bb0;
          ss[(size_t)nn*DDIM + col] = acc1[nt][r] + bb1;
        }
      }
    }
  }
}

// ---------------- MFMA edge GEMM: 64 edges/block, msg prefetched, msg-tiles-first kt order ----------------
// Phase 0: issue ALL global loads (coalesced ei/tt, msg float4s into static mld[7][2], lusub gather).
// Phase 1: kt order {4,5,6,3,0,1,2} -- pure-msg tiles' MFMAs issue while the rel->cos chain resolves.
__global__ __launch_bounds__(256, 3) void k_gemm(
    const int* __restrict__ ei, const int* __restrict__ tt,
    const int* __restrict__ lusub, const float* __restrict__ msg,
    const float* __restrict__ wt, const float* __restrict__ bt,
    const unsigned short* __restrict__ Web, unsigned short* __restrict__ evals)
{
  const int tid = threadIdx.x;
  const int lane = tid & 63;
  const int w = tid >> 6;
  const long p0 = (long)blockIdx.x * 64;
  const int arow = w*16 + (lane & 15);
  const int koff = (lane >> 4) << 3;           // 0,8,16,24

  long p = p0 + arow;
  long pc = (p < NE) ? p : (NE - 1);

  // ---- phase 0: all loads in flight ----
  const int srcn = ei[pc];                     // coalesced
  const int tv   = tt[pc];                     // coalesced
  const float* mrow = msg + pc*DDIM;

  float4 mld[7][2];
  #pragma unroll
  for (int kt=0; kt<7; ++kt){
    const int k0 = kt*32 + koff;
    if (k0 >= TDIM && k0 < KATTR){
      // full-msg tile (k0+7 <= 199 guaranteed: max k0 = 192)
      mld[kt][0] = *(const float4*)(mrow + (k0 - TDIM));
      mld[kt][1] = *(const float4*)(mrow + (k0 - TDIM) + 4);
    } else if (k0 < TDIM && k0 + 7 >= TDIM){
      // mixed tile (k0 == 96): msg dims 100..103
      mld[kt][0] = *(const float4*)(mrow);
      mld[kt][1] = make_float4(0.f,0.f,0.f,0.f);
    } else {
      mld[kt][0] = make_float4(0.f,0.f,0.f,0.f);
      mld[kt][1] = make_float4(0.f,0.f,0.f,0.f);
    }
  }
  const float rel = (float)(lusub[srcn] - tv);   // dependent gather chain

  f32x4 acc[7];
  #pragma unroll
  for (int nt=0; nt<7; ++nt) acc[nt] = (f32x4){0.f,0.f,0.f,0.f};

  // ---- phase 1: fragments + MFMA, msg tiles first ----
  constexpr int KORD[7] = {4,5,6,3,0,1,2};
  #pragma unroll
  for (int ki=0; ki<7; ++ki){
    const int kt = KORD[ki];
    const int k0 = kt*32 + koff;
    short8 a;
    if (k0 + 7 < TDIM){
      // pure cos tile: wt/bt are L1-hot broadcasts
      float4 w0 = *(const float4*)(wt + k0);
      float4 w1 = *(const float4*)(wt + k0 + 4);
      float4 b0 = *(const float4*)(bt + k0);
      float4 b1 = *(const float4*)(bt + k0 + 4);
      // __fmul_rn/__fadd_rn: must match XLA's non-contracted mul-then-add rounding
      a[0] = (short)f2bf(fast_cos(__fadd_rn(__fmul_rn(rel, w0.x), b0.x)));
      a[1] = (short)f2bf(fast_cos(__fadd_rn(__fmul_rn(rel, w0.y), b0.y)));
      a[2] = (short)f2bf(fast_cos(__fadd_rn(__fmul_rn(rel, w0.z), b0.z)));
      a[3] = (short)f2bf(fast_cos(__fadd_rn(__fmul_rn(rel, w0.w), b0.w)));
      a[4] = (short)f2bf(fast_cos(__fadd_rn(__fmul_rn(rel, w1.x), b1.x)));
      a[5] = (short)f2bf(fast_cos(__fadd_rn(__fmul_rn(rel, w1.y), b1.y)));
      a[6] = (short)f2bf(fast_cos(__fadd_rn(__fmul_rn(rel, w1.z), b1.z)));
      a[7] = (short)f2bf(fast_cos(__fadd_rn(__fmul_rn(rel, w1.w), b1.w)));
    } else if (k0 >= KATTR){
      #pragma unroll
      for (int j=0;j<8;++j) a[j] = 0;
    } else if (k0 >= TDIM){
      float4 m0 = mld[kt][0];
      float4 m1 = mld[kt][1];
      a[0] = (short)f2bf(m0.x); a[1] = (short)f2bf(m0.y);
      a[2] = (short)f2bf(m0.z); a[3] = (short)f2bf(m0.w);
      a[4] = (short)f2bf(m1.x); a[5] = (short)f2bf(m1.y);
      a[6] = (short)f2bf(m1.z); a[7] = (short)f2bf(m1.w);
    } else {
      // mixed tile (k0==96): j<4 cos at dims 96..99, j>=4 msg dims 100..103
      float4 w0 = *(const float4*)(wt + k0);
      float4 b0 = *(const float4*)(bt + k0);
      float4 m0 = mld[kt][0];
      a[0] = (short)f2bf(fast_cos(__fadd_rn(__fmul_rn(rel, w0.x), b0.x)));
      a[1] = (short)f2bf(fast_cos(__fadd_rn(__fmul_rn(rel, w0.y), b0.y)));
      a[2] = (short)f2bf(fast_cos(__fadd_rn(__fmul_rn(rel, w0.z), b0.z)));
      a[3] = (short)f2bf(fast_cos(__fadd_rn(__fmul_rn(rel, w0.w), b0.w)));
      a[4] = (short)f2bf(m0.x); a[5] = (short)f2bf(m0.y);
      a[6] = (short)f2bf(m0.z); a[7] = (short)f2bf(m0.w);
    }
    const short8* wb = (const short8*)Web + (size_t)(kt*7)*64 + lane;
    #pragma unroll
    for (int nt=0; nt<7; ++nt){
      short8 b = wb[(size_t)nt*64];
      acc[nt] = __builtin_amdgcn_mfma_f32_16x16x32_bf16(a, b, acc[nt], 0, 0, 0);
    }
  }

  const int colb = lane & 15;
  const int rbase = w*16 + ((lane >> 4) << 2);
  #pragma unroll
  for (int nt=0; nt<7; ++nt){
    int col = nt*16 + colb;
    if (col >= DDIM) continue;
    #pragma unroll
    for (int r=0; r<4; ++r){
      long pp = p0 + rbase + r;
      if (pp < NE) evals[pp*DDIM + col] = f2bf(acc[nt][r]);
    }
  }
}

// ---------------- per-dst aggregation, 4-edge unrolled, packed bf16 kv ----------------
__global__ __launch_bounds__(256) void k_agg(
    const int* __restrict__ rowptr, const unsigned long long* __restrict__ sp64,
    const unsigned short* __restrict__ evals,
    const float* __restrict__ qs, const unsigned short* __restrict__ kvb,
    const float* __restrict__ ssb, float* __restrict__ oute)
{
  const int w = threadIdx.x >> 6;
  const int lane = threadIdx.x & 63;
  const int node = blockIdx.x*4 + w;
  if (node >= N_SUBN) return;

  const int half = lane >> 5;               // 0: head0, 1: head1
  const int lh = lane & 31;
  const bool act = lh < 25;
  const int c = half*50 + lh*2;             // col pair (c, c+1)

  float q0 = 0.f, q1 = 0.f;
  if (act){
    float2 qq = *(const float2*)(qs + (size_t)node*DDIM + c);
    q0 = qq.x; q1 = qq.y;
  }
  const int b0 = rowptr[node], b1 = rowptr[node+1];
  float num0 = 0.f, num1 = 0.f, den = 0.f;
  const float INV = 0.14142135623730951f;   // 1/sqrt(50)

  int p = b0;
  for (; p+3 < b1; p += 4){
    float ph[4], ev0[4], ev1[4], vv0[4], vv1[4];
    #pragma unroll
    for (int j=0;j<4;++j){
      uint2 se = ((const uint2*)sp64)[p+j];
      int s = (int)se.x;
      int e = (int)se.y;
      float e0=0.f,e1=0.f,k0_=0.f,k1_=0.f,v0_=0.f,v1_=0.f;
      if (act){
        unsigned ea = *(const unsigned*)(evals + (size_t)e*DDIM + c);
        uint2 kv = *(const uint2*)(kvb + (size_t)s*(2*DDIM) + c*2);
        e0 = bf2f((unsigned short)(ea & 0xffff)); e1 = bf2f((unsigned short)(ea >> 16));
        k0_ = bf2f((unsigned short)(kv.x & 0xffff)); v0_ = bf2f((unsigned short)(kv.x >> 16));
        k1_ = bf2f((unsigned short)(kv.y & 0xffff)); v1_ = bf2f((unsigned short)(kv.y >> 16));
      }
      ph[j] = fmaf(q0, k0_+e0, q1*(k1_+e1));
      ev0[j]=e0; ev1[j]=e1; vv0[j]=v0_; vv1[j]=v1_;
    }
    #pragma unroll
    for (int m=1; m<32; m<<=1){
      #pragma unroll
      for (int j=0;j<4;++j) ph[j] += __shfl_xor(ph[j], m);
    }
    #pragma unroll
    for (int j=0;j<4;++j){
      float a = __expf(ph[j]*INV);
      den += a;
      num0 = fmaf(a, vv0[j]+ev0[j], num0);
      num1 = fmaf(a, vv1[j]+ev1[j], num1);
    }
  }
  for (; p < b1; ++p){
    uint2 se = ((const uint2*)sp64)[p];
    int s = (int)se.x, e = (int)se.y;
    float e0=0.f,e1=0.f,k0_=0.f,k1_=0.f,v0_=0.f,v1_=0.f;
    if (act){
      unsigned ea = *(const unsigned*)(evals + (size_t)e*DDIM + c);
      uint2 kv = *(const uint2*)(kvb + (size_t)s*(2*DDIM) + c*2);
      e0 = bf2f((unsigned short)(ea & 0xffff)); e1 = bf2f((unsigned short)(ea >> 16));
      k0_ = bf2f((unsigned short)(kv.x & 0xffff)); v0_ = bf2f((unsigned short)(kv.x >> 16));
      k1_ = bf2f((unsigned short)(kv.y & 0xffff)); v1_ = bf2f((unsigned short)(kv.y >> 16));
    }
    float ph = fmaf(q0, k0_+e0, q1*(k1_+e1));
    #pragma unroll
    for (int m=1; m<32; m<<=1) ph += __shfl_xor(ph, m);
    float a = __expf(ph*INV);
    den += a;
    num0 = fmaf(a, v0_+e0, num0);
    num1 = fmaf(a, v1_+e1, num1);
  }

  if (act){
    float inv_d = 1.f / (den + 1e-16f);
    const float* sp = ssb + (size_t)node*DDIM + c;
    float* op = oute + (size_t)node*DDIM + c;
    op[0] = num0*inv_d + sp[0];
    op[1] = num1*inv_d + sp[1];
  }
}

// ---------------- fused predictor ----------------
__global__ __launch_bounds__(256) void k_pred(
    const float* __restrict__ oute, const int* __restrict__ srci, const int* __restrict__ dsti,
    const float* __restrict__ Wps, const float* __restrict__ bps,
    const float* __restrict__ Wpd, const float* __restrict__ bpd,
    const float* __restrict__ Wpf, const float* __restrict__ bpf,
    float* __restrict__ outp)
{
  __shared__ float hs[2][DDIM];
  const int tid = threadIdx.x;
  const int r = tid / DDIM;
  const int c = tid - r*DDIM;
  const int b = blockIdx.x*2 + r;
  const bool on = (r < 2) && (b < NB);

  if (on){
    const float* r1 = oute + (size_t)srci[b]*DDIM;
    const float* r2 = oute + (size_t)dsti[b]*DDIM;
    float a = bps[c] + bpd[c];
    for (int k=0;k<DDIM;k++){
      a = fmaf(r1[k], Wps[k*DDIM+c], a);
      a = fmaf(r2[k], Wpd[k*DDIM+c], a);
    }
    hs[r][c] = fmaxf(a, 0.f);
  }
  __syncthreads();
  if (on){
    float a = bpf[c];
    for (int k=0;k<DDIM;k++) a = fmaf(hs[r][k], Wpf[k*DDIM+c], a);
    outp[(size_t)b*DDIM + c] = a;
  }
}

extern "C" void kernel_launch(void* const* d_in, const int* in_sizes, int n_in,
                              void* d_out, int out_size, void* d_ws, size_t ws_size,
                              hipStream_t stream)
{
  const float* mem   = (const float*)d_in[0];
  const int*   lastu = (const int*)  d_in[1];
  const int*   nid   = (const int*)  d_in[2];
  const int*   ei    = (const int*)  d_in[3];
  const int*   tt    = (const int*)  d_in[4];
  const float* msg   = (const float*)d_in[5];
  const int*   srci  = (const int*)  d_in[6];
  const int*   dsti  = (const int*)  d_in[7];
  const float* wtime = (const float*)d_in[8];
  const float* btime = (const float*)d_in[9];
  const float* Wq = (const float*)d_in[10]; const float* bq = (const float*)d_in[11];
  const float* Wk = (const float*)d_in[12]; const float* bk = (const float*)d_in[13];
  const float* Wv = (const float*)d_in[14]; const float* bv = (const float*)d_in[15];
  const float* We = (const float*)d_in[16];
  const float* Ws = (const float*)d_in[17]; const float* bs = (const float*)d_in[18];
  const float* Wps= (const float*)d_in[19]; const float* bps= (const float*)d_in[20];
  const float* Wpd= (const float*)d_in[21]; const float* bpd= (const float*)d_in[22];
  const float* Wpf= (const float*)d_in[23]; const float* bpf= (const float*)d_in[24];

  char* wsp = (char*)d_ws;
  auto alloc = [&](size_t bytes)->void*{
    void* p = (void*)wsp;
    wsp += (bytes + 255) & ~(size_t)255;
    return p;
  };
  unsigned short* evals = (unsigned short*)alloc((size_t)NE*DDIM*2);     // 100 MB
  float* qs   = (float*)alloc((size_t)N_SUBN*DDIM*4);
  unsigned short* kvb = (unsigned short*)alloc((size_t)N_SUBN*DDIM*2*2); // 20 MB packed (k,v) bf16
  float* ssb  = (float*)alloc((size_t)N_SUBN*DDIM*4);
  float* oute = (float*)alloc((size_t)N_SUBN*DDIM*4);
  int* cnt    = (int*)alloc((size_t)N_SUBN*4);
  int* rowptr = (int*)alloc((size_t)(N_SUBN+1)*4);
  int* ofs    = (int*)alloc((size_t)N_SUBN*4);
  int* bsum   = (int*)alloc((size_t)NCHUNK*4);
  int* bbase  = (int*)alloc((size_t)NCHUNK*4);
  unsigned long long* sp64 = (unsigned long long*)alloc((size_t)NE*8);
  int* lusub  = (int*)alloc((size_t)N_SUBN*4);
  unsigned short* Web = (unsigned short*)alloc((size_t)49*64*8*2);
  unsigned short* Wnb = (unsigned short*)alloc((size_t)4*28*64*8*2);

  k_misc<<<(N_SUBN+255)/256, 256, 0, stream>>>(lastu, nid, cnt, lusub, We, Web,
                                               Wq, Wk, Wv, Ws, Wnb);
  k_hist<<<(NE+255)/256, 256, 0, stream>>>(ei, cnt);
  k_bsum<<<NCHUNK, 256, 0, stream>>>(cnt, bsum);
  k_bscan<<<1, 64, 0, stream>>>(bsum, bbase);
  k_off<<<NCHUNK, 1024, 0, stream>>>(cnt, bbase, rowptr, ofs);
  k_perm<<<(NE+255)/256, 256, 0, stream>>>(ei, ofs, sp64);

  dim3 gn((N_SUBN+63)/64, 2);
  k_node<<<gn, 256, 0, stream>>>(mem, nid, Wnb, bq, bk, bv, bs, qs, kvb, ssb);

  k_gemm<<<(NE+63)/64, 256, 0, stream>>>(ei, tt, lusub, msg, wtime, btime, Web, evals);

  k_agg<<<(N_SUBN+3)/4, 256, 0, stream>>>(rowptr, sp64, evals, qs, kvb, ssb, oute);

  k_pred<<<(NB+1)/2, 256, 0, stream>>>(oute, srci, dsti, Wps,bps, Wpd,bpd, Wpf,bpf,
                                       (float*)d_out);
}

// Round 9
// 340.021 us; speedup vs baseline: 8.6370x; 1.1024x over previous
//
#include <hip/hip_runtime.h>
#include <math.h>

#define N_SUBN  50000
#define NE      500000
#define NB      5000
#define DDIM    100
#define TDIM    100
#define KATTR   200
#define NCHUNK  49        // ceil(N_SUBN/1024)

typedef __attribute__((ext_vector_type(8))) short short8;
typedef __attribute__((ext_vector_type(4))) float f32x4;

__device__ inline unsigned short f2bf(float f){
  union{float f; unsigned int u;} v; v.f = f;
  unsigned int r = (v.u + 0x7fffu + ((v.u >> 16) & 1u)) >> 16;   // RNE
  return (unsigned short)r;
}
__device__ inline float bf2f(unsigned short u){
  union{unsigned int u; float f;} v; v.u = ((unsigned int)u) << 16;
  return v.f;
}

// fast cos for |x| up to ~1e6: Cody-Waite 2-term reduction (fma-exact) + v_cos.
__device__ inline float fast_cos(float x){
  constexpr double TWO_PI_D = 6.2831853071795864769252867665590;
  constexpr float I2PI = (float)(1.0/TWO_PI_D);
  constexpr float C1 = (float)TWO_PI_D;
  constexpr float C2 = (float)(TWO_PI_D - (double)((float)TWO_PI_D));
  float k = rintf(x * I2PI);
  float r = fmaf(k, -C1, x);
  r = fmaf(k, -C2, r);
  return __cosf(r);
}

// ---- fused setup: zero cnt + lusub gather + pack Wnb (node GEMM), Wqxb (qex GEMM), Wfb (final GEMM) ----
__global__ __launch_bounds__(256) void k_misc(
    const int* __restrict__ lastu, const int* __restrict__ nid,
    int* __restrict__ cnt, int* __restrict__ lusub,
    const float* __restrict__ We,
    const float* __restrict__ Wq, const float* __restrict__ Wk,
    const float* __restrict__ Wv, const float* __restrict__ Ws,
    unsigned short* __restrict__ Wnb, unsigned short* __restrict__ Wqxb,
    unsigned short* __restrict__ Wfb)
{
  int i = blockIdx.x*256 + threadIdx.x;
  if (i < N_SUBN){
    cnt[i] = 0;
    lusub[i] = lastu[nid[i]];
  }
  if (i < 4*28*64){           // node GEMM weights (4 matrices, K=100->128, N=100->112)
    int l = i & 63; int t = i >> 6;
    int which = t / 28; int t2 = t - which*28;
    int kt = t2 / 7; int nt = t2 - kt*7;
    const float* W = (which==0)?Wq:(which==1)?Wk:(which==2)?Wv:Ws;
    int col = nt*16 + (l & 15);
    int kbase = kt*32 + ((l >> 4) << 3);
    short8 pack;
    #pragma unroll
    for (int j = 0; j < 8; ++j){
      int k = kbase + j;
      float v = (k < DDIM && col < DDIM) ? W[k*DDIM + col] : 0.f;
      pack[j] = (short)f2bf(v);
    }
    *((short8*)Wnb + i) = pack;
  }
  if (i < 4*25*64){           // qex GEMM: B[k][col] = (h*50<=k<h*50+50)?We[d][k]:0, h=col/200, d=col%200
    int l = i & 63; int t = i >> 6;
    int kt = t / 25; int nt = t - kt*25;
    int col = nt*16 + (l & 15);          // 0..399
    int h = col / 200; int d = col - h*200;
    int kbase = kt*32 + ((l >> 4) << 3);
    short8 pack;
    #pragma unroll
    for (int j = 0; j < 8; ++j){
      int k = kbase + j;
      float v = (k >= h*50 && k < h*50 + 50) ? We[d*DDIM + k] : 0.f;
      pack[j] = (short)f2bf(v);
    }
    *((short8*)Wqxb + i) = pack;
  }
  if (i < 13*7*64){           // final GEMM: B[k][col] = (k/200==col/50)?We[k%200][col]:0
    int l = i & 63; int t = i >> 6;
    int kt = t / 7; int nt = t - kt*7;
    int col = nt*16 + (l & 15);
    int kbase = kt*32 + ((l >> 4) << 3);
    short8 pack;
    #pragma unroll
    for (int j = 0; j < 8; ++j){
      int k = kbase + j;
      float v = 0.f;
      if (col < DDIM && k < 2*KATTR){
        int h = col / 50; int blk = k / KATTR; int d = k - blk*KATTR;
        v = (blk == h) ? We[d*DDIM + col] : 0.f;
      }
      pack[j] = (short)f2bf(v);
    }
    *((short8*)Wfb + i) = pack;
  }
}

// ---------------- CSR: histogram over dst ----------------
__global__ void k_hist(const int* __restrict__ ei, int* __restrict__ cnt){
  int i = blockIdx.x*blockDim.x + threadIdx.x;
  if (i < NE) atomicAdd(&cnt[ei[NE + i]], 1);
}

// ---------------- CSR scan phase 1 ----------------
__global__ __launch_bounds__(256) void k_bsum(const int* __restrict__ cnt, int* __restrict__ bsum){
  __shared__ int wsum[4];
  int b = blockIdx.x, tid = threadIdx.x;
  int base = b*1024 + tid*4;
  int s = 0;
  #pragma unroll
  for (int i=0;i<4;i++){ int idx = base+i; if (idx < N_SUBN) s += cnt[idx]; }
  #pragma unroll
  for (int m=1;m<64;m<<=1) s += __shfl_xor(s, m);
  if ((tid&63)==0) wsum[tid>>6] = s;
  __syncthreads();
  if (tid==0) bsum[b] = wsum[0]+wsum[1]+wsum[2]+wsum[3];
}

// ---------------- CSR scan phase 2 ----------------
__global__ void k_bscan(const int* __restrict__ bsum, int* __restrict__ bbase){
  int l = threadIdx.x;
  int v = (l < NCHUNK) ? bsum[l] : 0;
  int orig = v;
  for (int off=1; off<64; off<<=1){
    int t = __shfl_up(v, off);
    if (l >= off) v += t;
  }
  if (l < NCHUNK) bbase[l] = v - orig;
}

// ---------------- CSR scan phase 3 ----------------
__global__ __launch_bounds__(1024) void k_off(const int* __restrict__ cnt, const int* __restrict__ bbase,
                                              int* __restrict__ rowptr, int* __restrict__ ofs){
  __shared__ int sd[1024];
  int b = blockIdx.x, tid = threadIdx.x;
  int i = b*1024 + tid;
  int v = (i < N_SUBN) ? cnt[i] : 0;
  sd[tid] = v; __syncthreads();
  for (int off=1; off<1024; off<<=1){
    int t = (tid >= off) ? sd[tid-off] : 0;
    __syncthreads();
    sd[tid] += t;
    __syncthreads();
  }
  int incl = sd[tid] + bbase[b];
  if (i < N_SUBN){ rowptr[i+1] = incl; ofs[i] = incl - v; }
  if (i == 0) rowptr[0] = 0;
}

// ---------------- CSR: bucket edges by dst, packed (edge<<32 | src) + t ----------------
__global__ void k_perm(const int* __restrict__ ei, const int* __restrict__ tt,
                       int* __restrict__ ofs, unsigned long long* __restrict__ sp64,
                       int* __restrict__ tsort){
  int i = blockIdx.x*blockDim.x + threadIdx.x;
  if (i < NE){
    int d = ei[NE + i];
    int pos = atomicAdd(&ofs[d], 1);
    sp64[pos] = ((unsigned long long)(unsigned)i << 32) | (unsigned)ei[i];
    tsort[pos] = tt[i];
  }
}

// ---------------- node GEMMs via MFMA: pair 0 -> k,v (packed bf16) ; pair 1 -> q,skip (f32) ----------------
__global__ __launch_bounds__(256, 4) void k_node(
    const float* __restrict__ mem, const int* __restrict__ nid,
    const unsigned short* __restrict__ Wnb,
    const float* __restrict__ bq, const float* __restrict__ bk,
    const float* __restrict__ bv, const float* __restrict__ bs,
    float* __restrict__ qs, unsigned short* __restrict__ kvb,
    float* __restrict__ ss)
{
  const int tid = threadIdx.x;
  const int lane = tid & 63;
  const int w = tid >> 6;
  const int pair = blockIdx.y;
  const int node0 = blockIdx.x*64;
  const int arow = w*16 + (lane & 15);
  const int koff = (lane >> 4) << 3;

  int node = node0 + arow;
  int nc = (node < N_SUBN) ? node : (N_SUBN-1);
  const float* zrow = mem + (size_t)nid[nc]*DDIM;

  f32x4 acc0[7], acc1[7];
  #pragma unroll
  for (int nt=0; nt<7; ++nt){ acc0[nt] = (f32x4){0,0,0,0}; acc1[nt] = (f32x4){0,0,0,0}; }

  const int wm0 = pair ? 0 : 1;
  const int wm1 = pair ? 3 : 2;
  #pragma unroll
  for (int kt=0; kt<4; ++kt){
    const int k0 = kt*32 + koff;
    short8 a;
    if (k0 + 7 < DDIM){
      float4 m0 = *(const float4*)(zrow + k0);
      float4 m1 = *(const float4*)(zrow + k0 + 4);
      a[0] = (short)f2bf(m0.x); a[1] = (short)f2bf(m0.y);
      a[2] = (short)f2bf(m0.z); a[3] = (short)f2bf(m0.w);
      a[4] = (short)f2bf(m1.x); a[5] = (short)f2bf(m1.y);
      a[6] = (short)f2bf(m1.z); a[7] = (short)f2bf(m1.w);
    } else if (k0 >= DDIM){
      #pragma unroll
      for (int j=0;j<8;++j) a[j] = 0;
    } else {  // k0 == 96
      float4 m0 = *(const float4*)(zrow + 96);
      a[0] = (short)f2bf(m0.x); a[1] = (short)f2bf(m0.y);
      a[2] = (short)f2bf(m0.z); a[3] = (short)f2bf(m0.w);
      a[4] = 0; a[5] = 0; a[6] = 0; a[7] = 0;
    }
    const short8* wb0 = (const short8*)Wnb + (size_t)((wm0*4 + kt)*7)*64 + lane;
    const short8* wb1 = (const short8*)Wnb + (size_t)((wm1*4 + kt)*7)*64 + lane;
    #pragma unroll
    for (int nt=0; nt<7; ++nt){
      short8 b0 = wb0[(size_t)nt*64];
      short8 b1 = wb1[(size_t)nt*64];
      acc0[nt] = __builtin_amdgcn_mfma_f32_16x16x32_bf16(a, b0, acc0[nt], 0, 0, 0);
      acc1[nt] = __builtin_amdgcn_mfma_f32_16x16x32_bf16(a, b1, acc1[nt], 0, 0, 0);
    }
  }

  const int colb = lane & 15;
  const int rbase = w*16 + ((lane >> 4) << 2);
  if (pair == 0){
    #pragma unroll
    for (int nt=0; nt<7; ++nt){
      int col = nt*16 + colb;
      if (col >= DDIM) continue;
      float bb0 = bk[col], bb1 = bv[col];
      #pragma unroll
      for (int r=0; r<4; ++r){
        int nn = node0 + rbase + r;
        if (nn < N_SUBN){
          unsigned pk = (unsigned)f2bf(acc0[nt][r] + bb0)
                      | ((unsigned)f2bf(acc1[nt][r] + bb1) << 16);
          *(unsigned*)(kvb + (size_t)nn*(2*DDIM) + col*2) = pk;
        }
      }
    }
  } else {
    #pragma unroll
    for (int nt=0; nt<7; ++nt){
      int col = nt*16 + colb;
      if (col >= DDIM) continue;
      float bb0 = bq[col], bb1 = bs[col];
      #pragma unroll
      for (int r=0; r<4; ++r){
        int nn = node0 + rbase + r;
        if (nn < N_SUBN){
          qs[(size_t)nn*DDIM + col] = acc0[nt][r] + bb0;
          ss[(size_t)nn*DDIM + col] = acc1[nt][r] + bb1;
        }
      }
    }
  }
}

// ---------------- qex GEMM: qex[node][0:200]=We_h0@q_h0, [200:400]=We_h1@q_h1 (bf16 out) ----------------
__global__ __launch_bounds__(256) void k_qex(
    const float* __restrict__ qs, const unsigned short* __restrict__ Wqxb,
    unsigned short* __restrict__ qexb)
{
  const int tid = threadIdx.x;
  const int lane = tid & 63;
  const int w = tid >> 6;
  const int node0 = blockIdx.x*64;
  const int arow = w*16 + (lane & 15);
  const int koff = (lane >> 4) << 3;

  int node = node0 + arow;
  int nc = (node < N_SUBN) ? node : (N_SUBN-1);
  const float* qrow = qs + (size_t)nc*DDIM;

  f32x4 acc[25];
  #pragma unroll
  for (int nt=0; nt<25; ++nt) acc[nt] = (f32x4){0,0,0,0};

  #pragma unroll
  for (int kt=0; kt<4; ++kt){
    const int k0 = kt*32 + koff;
    short8 a;
    if (k0 + 7 < DDIM){
      float4 m0 = *(const float4*)(qrow + k0);
      float4 m1 = *(const float4*)(qrow + k0 + 4);
      a[0] = (short)f2bf(m0.x); a[1] = (short)f2bf(m0.y);
      a[2] = (short)f2bf(m0.z); a[3] = (short)f2bf(m0.w);
      a[4] = (short)f2bf(m1.x); a[5] = (short)f2bf(m1.y);
      a[6] = (short)f2bf(m1.z); a[7] = (short)f2bf(m1.w);
    } else if (k0 >= DDIM){
      #pragma unroll
      for (int j=0;j<8;++j) a[j] = 0;
    } else {
      float4 m0 = *(const float4*)(qrow + 96);
      a[0] = (short)f2bf(m0.x); a[1] = (short)f2bf(m0.y);
      a[2] = (short)f2bf(m0.z); a[3] = (short)f2bf(m0.w);
      a[4] = 0; a[5] = 0; a[6] = 0; a[7] = 0;
    }
    const short8* wb = (const short8*)Wqxb + (size_t)(kt*25)*64 + lane;
    #pragma unroll
    for (int nt=0; nt<25; ++nt){
      short8 b = wb[(size_t)nt*64];
      acc[nt] = __builtin_amdgcn_mfma_f32_16x16x32_bf16(a, b, acc[nt], 0, 0, 0);
    }
  }

  const int colb = lane & 15;
  const int rbase = w*16 + ((lane >> 4) << 2);
  #pragma unroll
  for (int nt=0; nt<25; ++nt){
    int col = nt*16 + colb;   // 0..399, all valid
    #pragma unroll
    for (int r=0; r<4; ++r){
      int nn = node0 + rbase + r;
      if (nn < N_SUBN) qexb[(size_t)nn*400 + col] = f2bf(acc[nt][r]);
    }
  }
}

// ---------------- fused aggregation: alpha via qex.attr, accumulate den/numv/sbar (no evals!) --------
// lane l<50 owns attr dims {l, 50+l, 100+l, 150+l} and cols l (head0), 50+l (head1).
__global__ __launch_bounds__(256) void k_agg(
    const int* __restrict__ rowptr, const unsigned long long* __restrict__ sp64,
    const int* __restrict__ tsort, const int* __restrict__ lusub,
    const float* __restrict__ msg, const float* __restrict__ qs,
    const unsigned short* __restrict__ qexb, const unsigned short* __restrict__ kvb,
    const float* __restrict__ wt, const float* __restrict__ bt,
    unsigned short* __restrict__ sbarb, float* __restrict__ numvb,
    float* __restrict__ denb)
{
  const int w = __builtin_amdgcn_readfirstlane(threadIdx.x >> 6);
  const int lane = threadIdx.x & 63;
  const int node = blockIdx.x*4 + w;
  if (node >= N_SUBN) return;
  const bool act = lane < 50;
  const int l = lane;
  const float INV = 0.14142135623730951f;   // 1/sqrt(50)

  float wtA=0,wtB=0,btA=0,btB=0,q0=0,q1=0;
  float qx0=0,qx1=0,qx2=0,qx3=0,qx4=0,qx5=0,qx6=0,qx7=0;
  if (act){
    wtA = wt[l]; wtB = wt[50+l]; btA = bt[l]; btB = bt[50+l];
    q0 = qs[(size_t)node*DDIM + l]; q1 = qs[(size_t)node*DDIM + 50 + l];
    const unsigned short* qe = qexb + (size_t)node*400;
    qx0 = bf2f(qe[l]);      qx1 = bf2f(qe[50+l]);
    qx2 = bf2f(qe[100+l]);  qx3 = bf2f(qe[150+l]);
    qx4 = bf2f(qe[200+l]);  qx5 = bf2f(qe[250+l]);
    qx6 = bf2f(qe[300+l]);  qx7 = bf2f(qe[350+l]);
  }
  const int b0 = rowptr[node], b1 = rowptr[node+1];
  float den0=0.f, den1=0.f, nv0=0.f, nv1=0.f;
  float sb0=0.f,sb1=0.f,sb2=0.f,sb3=0.f,sb4=0.f,sb5=0.f,sb6=0.f,sb7=0.f;

  int p = b0;
  for (; p+1 < b1; p += 2){
    uint2 seA = ((const uint2*)sp64)[p];
    uint2 seB = ((const uint2*)sp64)[p+1];
    int tA = tsort[p], tB = tsort[p+1];
    float relA = (float)(lusub[(int)seA.x] - tA);
    float relB = (float)(lusub[(int)seB.x] - tB);
    float cAA=0,cBA=0,mAA=0,mBA=0,kA0=0,vA0=0,kA1=0,vA1=0;
    float cAB=0,cBB=0,mAB=0,mBB=0,kB0=0,vB0=0,kB1=0,vB1=0;
    if (act){
      mAA = msg[(size_t)seA.y*DDIM + l];       mBA = msg[(size_t)seA.y*DDIM + 50 + l];
      mAB = msg[(size_t)seB.y*DDIM + l];       mBB = msg[(size_t)seB.y*DDIM + 50 + l];
      unsigned pA0 = *(const unsigned*)(kvb + (size_t)seA.x*(2*DDIM) + 2*l);
      unsigned pA1 = *(const unsigned*)(kvb + (size_t)seA.x*(2*DDIM) + 100 + 2*l);
      unsigned pB0 = *(const unsigned*)(kvb + (size_t)seB.x*(2*DDIM) + 2*l);
      unsigned pB1 = *(const unsigned*)(kvb + (size_t)seB.x*(2*DDIM) + 100 + 2*l);
      kA0 = bf2f((unsigned short)(pA0 & 0xffff)); vA0 = bf2f((unsigned short)(pA0 >> 16));
      kA1 = bf2f((unsigned short)(pA1 & 0xffff)); vA1 = bf2f((unsigned short)(pA1 >> 16));
      kB0 = bf2f((unsigned short)(pB0 & 0xffff)); vB0 = bf2f((unsigned short)(pB0 >> 16));
      kB1 = bf2f((unsigned short)(pB1 & 0xffff)); vB1 = bf2f((unsigned short)(pB1 >> 16));
      cAA = fast_cos(__fadd_rn(__fmul_rn(relA, wtA), btA));
      cBA = fast_cos(__fadd_rn(__fmul_rn(relA, wtB), btB));
      cAB = fast_cos(__fadd_rn(__fmul_rn(relB, wtA), btA));
      cBB = fast_cos(__fadd_rn(__fmul_rn(relB, wtB), btB));
    }
    float pA_0 = fmaf(q0,kA0, fmaf(qx0,cAA, fmaf(qx1,cBA, fmaf(qx2,mAA, qx3*mBA))));
    float pA_1 = fmaf(q1,kA1, fmaf(qx4,cAA, fmaf(qx5,cBA, fmaf(qx6,mAA, qx7*mBA))));
    float pB_0 = fmaf(q0,kB0, fmaf(qx0,cAB, fmaf(qx1,cBB, fmaf(qx2,mAB, qx3*mBB))));
    float pB_1 = fmaf(q1,kB1, fmaf(qx4,cAB, fmaf(qx5,cBB, fmaf(qx6,mAB, qx7*mBB))));
    #pragma unroll
    for (int m=1; m<64; m<<=1){
      pA_0 += __shfl_xor(pA_0, m);
      pA_1 += __shfl_xor(pA_1, m);
      pB_0 += __shfl_xor(pB_0, m);
      pB_1 += __shfl_xor(pB_1, m);
    }
    float aA0 = __expf(pA_0*INV), aA1 = __expf(pA_1*INV);
    float aB0 = __expf(pB_0*INV), aB1 = __expf(pB_1*INV);
    den0 += aA0 + aB0; den1 += aA1 + aB1;
    nv0 = fmaf(aA0, vA0, nv0); nv0 = fmaf(aB0, vB0, nv0);
    nv1 = fmaf(aA1, vA1, nv1); nv1 = fmaf(aB1, vB1, nv1);
    sb0 = fmaf(aA0, cAA, sb0); sb0 = fmaf(aB0, cAB, sb0);
    sb1 = fmaf(aA0, cBA, sb1); sb1 = fmaf(aB0, cBB, sb1);
    sb2 = fmaf(aA0, mAA, sb2); sb2 = fmaf(aB0, mAB, sb2);
    sb3 = fmaf(aA0, mBA, sb3); sb3 = fmaf(aB0, mBB, sb3);
    sb4 = fmaf(aA1, cAA, sb4); sb4 = fmaf(aB1, cAB, sb4);
    sb5 = fmaf(aA1, cBA, sb5); sb5 = fmaf(aB1, cBB, sb5);
    sb6 = fmaf(aA1, mAA, sb6); sb6 = fmaf(aB1, mAB, sb6);
    sb7 = fmaf(aA1, mBA, sb7); sb7 = fmaf(aB1, mBB, sb7);
  }
  if (p < b1){
    uint2 seA = ((const uint2*)sp64)[p];
    int tA = tsort[p];
    float relA = (float)(lusub[(int)seA.x] - tA);
    float cAA=0,cBA=0,mAA=0,mBA=0,kA0=0,vA0=0,kA1=0,vA1=0;
    if (act){
      mAA = msg[(size_t)seA.y*DDIM + l];  mBA = msg[(size_t)seA.y*DDIM + 50 + l];
      unsigned pA0 = *(const unsigned*)(kvb + (size_t)seA.x*(2*DDIM) + 2*l);
      unsigned pA1 = *(const unsigned*)(kvb + (size_t)seA.x*(2*DDIM) + 100 + 2*l);
      kA0 = bf2f((unsigned short)(pA0 & 0xffff)); vA0 = bf2f((unsigned short)(pA0 >> 16));
      kA1 = bf2f((unsigned short)(pA1 & 0xffff)); vA1 = bf2f((unsigned short)(pA1 >> 16));
      cAA = fast_cos(__fadd_rn(__fmul_rn(relA, wtA), btA));
      cBA = fast_cos(__fadd_rn(__fmul_rn(relA, wtB), btB));
    }
    float pA_0 = fmaf(q0,kA0, fmaf(qx0,cAA, fmaf(qx1,cBA, fmaf(qx2,mAA, qx3*mBA))));
    float pA_1 = fmaf(q1,kA1, fmaf(qx4,cAA, fmaf(qx5,cBA, fmaf(qx6,mAA, qx7*mBA))));
    #pragma unroll
    for (int m=1; m<64; m<<=1){
      pA_0 += __shfl_xor(pA_0, m);
      pA_1 += __shfl_xor(pA_1, m);
    }
    float aA0 = __expf(pA_0*INV), aA1 = __expf(pA_1*INV);
    den0 += aA0; den1 += aA1;
    nv0 = fmaf(aA0, vA0, nv0);
    nv1 = fmaf(aA1, vA1, nv1);
    sb0 = fmaf(aA0, cAA, sb0); sb1 = fmaf(aA0, cBA, sb1);
    sb2 = fmaf(aA0, mAA, sb2); sb3 = fmaf(aA0, mBA, sb3);
    sb4 = fmaf(aA1, cAA, sb4); sb5 = fmaf(aA1, cBA, sb5);
    sb6 = fmaf(aA1, mAA, sb6); sb7 = fmaf(aA1, mBA, sb7);
  }

  if (act){
    unsigned short* sr = sbarb + (size_t)node*400;
    sr[l]       = f2bf(sb0); sr[50+l]  = f2bf(sb1);
    sr[100+l]   = f2bf(sb2); sr[150+l] = f2bf(sb3);
    sr[200+l]   = f2bf(sb4); sr[250+l] = f2bf(sb5);
    sr[300+l]   = f2bf(sb6); sr[350+l] = f2bf(sb7);
    numvb[(size_t)node*DDIM + l]      = nv0;
    numvb[(size_t)node*DDIM + 50 + l] = nv1;
  }
  if (lane == 0){
    denb[node*2]   = den0;
    denb[node*2+1] = den1;
  }
}

// ---------------- final: oute = (numv + sbar@We)/den + skip, via MFMA ----------------
__global__ __launch_bounds__(256) void k_final(
    const unsigned short* __restrict__ sbarb, const unsigned short* __restrict__ Wfb,
    const float* __restrict__ numvb, const float* __restrict__ denb,
    const float* __restrict__ ssb, float* __restrict__ oute)
{
  const int tid = threadIdx.x;
  const int lane = tid & 63;
  const int w = tid >> 6;
  const int node0 = blockIdx.x*64;
  const int arow = w*16 + (lane & 15);
  const int koff = (lane >> 4) << 3;

  int node = node0 + arow;
  int nc = (node < N_SUBN) ? node : (N_SUBN-1);
  const unsigned short* srow = sbarb + (size_t)nc*400;

  f32x4 acc[7];
  #pragma unroll
  for (int nt=0; nt<7; ++nt) acc[nt] = (f32x4){0,0,0,0};

  #pragma unroll
  for (int kt=0; kt<13; ++kt){
    const int k0 = kt*32 + koff;
    short8 a;
    if (k0 + 7 < 2*KATTR){
      a = *(const short8*)(srow + k0);
    } else {
      #pragma unroll
      for (int j=0;j<8;++j) a[j] = 0;
    }
    const short8* wb = (const short8*)Wfb + (size_t)(kt*7)*64 + lane;
    #pragma unroll
    for (int nt=0; nt<7; ++nt){
      short8 b = wb[(size_t)nt*64];
      acc[nt] = __builtin_amdgcn_mfma_f32_16x16x32_bf16(a, b, acc[nt], 0, 0, 0);
    }
  }

  const int colb = lane & 15;
  const int rbase = w*16 + ((lane >> 4) << 2);
  #pragma unroll
  for (int nt=0; nt<7; ++nt){
    int col = nt*16 + colb;
    if (col >= DDIM) continue;
    int h = col >= 50 ? 1 : 0;
    #pragma unroll
    for (int r=0; r<4; ++r){
      int nn = node0 + rbase + r;
      if (nn < N_SUBN){
        float den = denb[nn*2 + h];
        float nv  = numvb[(size_t)nn*DDIM + col];
        oute[(size_t)nn*DDIM + col] =
          (nv + acc[nt][r]) / (den + 1e-16f) + ssb[(size_t)nn*DDIM + col];
      }
    }
  }
}

// ---------------- fused predictor ----------------
__global__ __launch_bounds__(256) void k_pred(
    const float* __restrict__ oute, const int* __restrict__ srci, const int* __restrict__ dsti,
    const float* __restrict__ Wps, const float* __restrict__ bps,
    const float* __restrict__ Wpd, const float* __restrict__ bpd,
    const float* __restrict__ Wpf, const float* __restrict__ bpf,
    float* __restrict__ outp)
{
  __shared__ float hs[2][DDIM];
  const int tid = threadIdx.x;
  const int r = tid / DDIM;
  const int c = tid - r*DDIM;
  const int b = blockIdx.x*2 + r;
  const bool on = (r < 2) && (b < NB);

  if (on){
    const float* r1 = oute + (size_t)srci[b]*DDIM;
    const float* r2 = oute + (size_t)dsti[b]*DDIM;
    float a = bps[c] + bpd[c];
    for (int k=0;k<DDIM;k++){
      a = fmaf(r1[k], Wps[k*DDIM+c], a);
      a = fmaf(r2[k], Wpd[k*DDIM+c], a);
    }
    hs[r][c] = fmaxf(a, 0.f);
  }
  __syncthreads();
  if (on){
    float a = bpf[c];
    for (int k=0;k<DDIM;k++) a = fmaf(hs[r][k], Wpf[k*DDIM+c], a);
    outp[(size_t)b*DDIM + c] = a;
  }
}

extern "C" void kernel_launch(void* const* d_in, const int* in_sizes, int n_in,
                              void* d_out, int out_size, void* d_ws, size_t ws_size,
                              hipStream_t stream)
{
  const float* mem   = (const float*)d_in[0];
  const int*   lastu = (const int*)  d_in[1];
  const int*   nid   = (const int*)  d_in[2];
  const int*   ei    = (const int*)  d_in[3];
  const int*   tt    = (const int*)  d_in[4];
  const float* msg   = (const float*)d_in[5];
  const int*   srci  = (const int*)  d_in[6];
  const int*   dsti  = (const int*)  d_in[7];
  const float* wtime = (const float*)d_in[8];
  const float* btime = (const float*)d_in[9];
  const float* Wq = (const float*)d_in[10]; const float* bq = (const float*)d_in[11];
  const float* Wk = (const float*)d_in[12]; const float* bk = (const float*)d_in[13];
  const float* Wv = (const float*)d_in[14]; const float* bv = (const float*)d_in[15];
  const float* We = (const float*)d_in[16];
  const float* Ws = (const float*)d_in[17]; const float* bs = (const float*)d_in[18];
  const float* Wps= (const float*)d_in[19]; const float* bps= (const float*)d_in[20];
  const float* Wpd= (const float*)d_in[21]; const float* bpd= (const float*)d_in[22];
  const float* Wpf= (const float*)d_in[23]; const float* bpf= (const float*)d_in[24];

  char* wsp = (char*)d_ws;
  auto alloc = [&](size_t bytes)->void*{
    void* p = (void*)wsp;
    wsp += (bytes + 255) & ~(size_t)255;
    return p;
  };
  float* qs   = (float*)alloc((size_t)N_SUBN*DDIM*4);
  unsigned short* kvb  = (unsigned short*)alloc((size_t)N_SUBN*DDIM*2*2);
  float* ssb  = (float*)alloc((size_t)N_SUBN*DDIM*4);
  float* oute = (float*)alloc((size_t)N_SUBN*DDIM*4);
  unsigned short* qexb = (unsigned short*)alloc((size_t)N_SUBN*400*2);   // 40 MB
  unsigned short* sbarb= (unsigned short*)alloc((size_t)N_SUBN*400*2);   // 40 MB
  float* numvb= (float*)alloc((size_t)N_SUBN*DDIM*4);                    // 20 MB
  float* denb = (float*)alloc((size_t)N_SUBN*2*4);
  int* cnt    = (int*)alloc((size_t)N_SUBN*4);
  int* rowptr = (int*)alloc((size_t)(N_SUBN+1)*4);
  int* ofs    = (int*)alloc((size_t)N_SUBN*4);
  int* bsum   = (int*)alloc((size_t)NCHUNK*4);
  int* bbase  = (int*)alloc((size_t)NCHUNK*4);
  unsigned long long* sp64 = (unsigned long long*)alloc((size_t)NE*8);
  int* tsort  = (int*)alloc((size_t)NE*4);
  int* lusub  = (int*)alloc((size_t)N_SUBN*4);
  unsigned short* Wnb  = (unsigned short*)alloc((size_t)4*28*64*8*2);
  unsigned short* Wqxb = (unsigned short*)alloc((size_t)4*25*64*8*2);
  unsigned short* Wfb  = (unsigned short*)alloc((size_t)13*7*64*8*2);

  k_misc<<<(N_SUBN+255)/256, 256, 0, stream>>>(lastu, nid, cnt, lusub, We,
                                               Wq, Wk, Wv, Ws, Wnb, Wqxb, Wfb);
  k_hist<<<(NE+255)/256, 256, 0, stream>>>(ei, cnt);
  k_bsum<<<NCHUNK, 256, 0, stream>>>(cnt, bsum);
  k_bscan<<<1, 64, 0, stream>>>(bsum, bbase);
  k_off<<<NCHUNK, 1024, 0, stream>>>(cnt, bbase, rowptr, ofs);
  k_perm<<<(NE+255)/256, 256, 0, stream>>>(ei, tt, ofs, sp64, tsort);

  dim3 gn((N_SUBN+63)/64, 2);
  k_node<<<gn, 256, 0, stream>>>(mem, nid, Wnb, bq, bk, bv, bs, qs, kvb, ssb);

  k_qex<<<(N_SUBN+63)/64, 256, 0, stream>>>(qs, Wqxb, qexb);

  k_agg<<<(N_SUBN+3)/4, 256, 0, stream>>>(rowptr, sp64, tsort, lusub, msg, qs,
                                          qexb, kvb, wtime, btime,
                                          sbarb, numvb, denb);

  k_final<<<(N_SUBN+63)/64, 256, 0, stream>>>(sbarb, Wfb, numvb, denb, ssb, oute);

  k_pred<<<(NB+1)/2, 256, 0, stream>>>(oute, srci, dsti, Wps,bps, Wpd,bpd, Wpf,bpf,
                                       (float*)d_out);
}